// Round 1
// baseline (25979.504 us; speedup 1.0000x reference)
//
#include <hip/hip_runtime.h>
#include <hip/hip_bf16.h>
#include <math.h>

// ---------------- problem constants ----------------
#define B 2
#define S 1024
#define D 1024
#define H 16
#define DH 64
#define NL 6
#define GH 64
#define NP 16
#define V 32000
#define FF 2730
#define M (B*S)   // 2048 rows

typedef float fv4 __attribute__((ext_vector_type(4)));

// ======================================================================
// embed: x[m][:] = tok_emb[ids[m]][:] + w_init[:]
// ======================================================================
__global__ __launch_bounds__(256) void k_embed(const int* __restrict__ ids,
                                               const float* __restrict__ emb,
                                               const float* __restrict__ winit,
                                               float* __restrict__ x) {
  int m = blockIdx.x, t = threadIdx.x;
  int id = ids[m];
  fv4 a = *(const fv4*)(emb + (size_t)id * D + 4*t);
  fv4 w = *(const fv4*)(winit + 4*t);
  *(fv4*)(x + (size_t)m * D + 4*t) = a + w;
}

// ======================================================================
// rope tables: cos/sin (S x 32), inv_freq = 10000^(-2f/DH)
// ======================================================================
__global__ void k_rope_tables(float* __restrict__ cosT, float* __restrict__ sinT) {
  int idx = blockIdx.x * blockDim.x + threadIdx.x;
  if (idx >= S * 32) return;
  int s = idx >> 5, f = idx & 31;
  float inv = powf(10000.0f, -2.0f * (float)f / (float)DH);
  float ang = (float)s * inv;
  cosT[idx] = cosf(ang);
  sinT[idx] = sinf(ang);
}

// ======================================================================
// Mp[h][d][e] = sum_n p[n][h][d] * p[n][h][e],  p[n][h][dh]=persistent[n][h*DH+dh]
// ======================================================================
__global__ __launch_bounds__(256) void k_mp(const float* __restrict__ pers,
                                            float* __restrict__ Mp) {
  int h = blockIdx.x, t = threadIdx.x;
  __shared__ float p[NP][DH];
  for (int i = t; i < NP * DH; i += 256) {
    int n = i / DH, dh = i % DH;
    p[n][dh] = pers[(size_t)n * D + h * DH + dh];
  }
  __syncthreads();
  for (int i = t; i < DH * DH; i += 256) {
    int d = i / DH, e = i % DH;
    float s = 0.f;
#pragma unroll
    for (int n = 0; n < NP; n++) s += p[n][d] * p[n][e];
    Mp[(size_t)h * DH * DH + i] = s;
  }
}

// ======================================================================
// rmsnorm over rows of D
// ======================================================================
__global__ __launch_bounds__(256) void k_rms(const float* __restrict__ in,
                                             const float* __restrict__ w,
                                             float* __restrict__ out) {
  int m = blockIdx.x, t = threadIdx.x;
  fv4 v = *(const fv4*)(in + (size_t)m * D + 4*t);
  float ss = v[0]*v[0] + v[1]*v[1] + v[2]*v[2] + v[3]*v[3];
#pragma unroll
  for (int off = 32; off > 0; off >>= 1) ss += __shfl_down(ss, off);
  __shared__ float buf[4];
  if ((t & 63) == 0) buf[t >> 6] = ss;
  __syncthreads();
  float tot = buf[0] + buf[1] + buf[2] + buf[3];
  float r = rsqrtf(tot * (1.0f / (float)D) + 1e-6f);
  fv4 wv = *(const fv4*)(w + 4*t);
  *(fv4*)(out + (size_t)m * D + 4*t) = v * r * wv;
}

// ======================================================================
// generic f32 GEMM: C[m][n] (op)= act( sum_k A[m][k] * W[n][k] )
// EPI: 0 store, 1 silu-store, 2 add-to-C, 3 mul-into-C
// 64x64 tile, BK=32, 256 threads, 4x4 micro. Scalar global loads (handles
// any K/N, incl. FF=2730 misalignment); fv4 LDS reads in inner loop.
// ======================================================================
template<int EPI>
__global__ __launch_bounds__(256) void k_gemm(const float* __restrict__ A,
                                              const float* __restrict__ W,
                                              float* __restrict__ C,
                                              int Mm, int Nn, int Kk) {
  int bn = blockIdx.x, bm = blockIdx.y;
  int t = threadIdx.x, tc = t & 15, tr = t >> 4;
  __shared__ float As[64][36], Ws[64][36];
  int m0 = bm * 64, n0 = bn * 64;
  float acc[4][4] = {};
  for (int k0 = 0; k0 < Kk; k0 += 32) {
    for (int i = t; i < 2048; i += 256) {
      int r = i >> 5, c = i & 31;
      int gm = m0 + r, gn = n0 + r, gk = k0 + c;
      bool kin = gk < Kk;
      As[r][c] = (kin && gm < Mm) ? A[(size_t)gm * Kk + gk] : 0.f;
      Ws[r][c] = (kin && gn < Nn) ? W[(size_t)gn * Kk + gk] : 0.f;
    }
    __syncthreads();
#pragma unroll
    for (int d4 = 0; d4 < 32; d4 += 4) {
      fv4 a[4], bv[4];
#pragma unroll
      for (int i = 0; i < 4; i++) a[i] = *(const fv4*)&As[tr*4 + i][d4];
#pragma unroll
      for (int j = 0; j < 4; j++) bv[j] = *(const fv4*)&Ws[tc*4 + j][d4];
#pragma unroll
      for (int i = 0; i < 4; i++)
#pragma unroll
        for (int j = 0; j < 4; j++)
          acc[i][j] += a[i][0]*bv[j][0] + a[i][1]*bv[j][1] + a[i][2]*bv[j][2] + a[i][3]*bv[j][3];
    }
    __syncthreads();
  }
#pragma unroll
  for (int i = 0; i < 4; i++)
#pragma unroll
    for (int j = 0; j < 4; j++) {
      int gm = m0 + tr*4 + i, gn = n0 + tc*4 + j;
      if (gm < Mm && gn < Nn) {
        size_t idx = (size_t)gm * Nn + gn;
        float r = acc[i][j];
        if (EPI == 0) C[idx] = r;
        else if (EPI == 1) C[idx] = r / (1.f + expf(-r));
        else if (EPI == 2) C[idx] += r;
        else C[idx] *= r;
      }
    }
}

// ======================================================================
// qkv post: per (b,s) row — split heads, qk rmsnorm(DH), rope, write q/k/v
// in [b][h][s][dh] layout. v is a plain relayout.
// ======================================================================
__global__ __launch_bounds__(256) void k_qkvpost(const float* __restrict__ qkv,
                                                 const float* __restrict__ qnw,
                                                 const float* __restrict__ knw,
                                                 const float* __restrict__ cosT,
                                                 const float* __restrict__ sinT,
                                                 float* __restrict__ q,
                                                 float* __restrict__ k,
                                                 float* __restrict__ v) {
  int m = blockIdx.x;
  int b = m / S, s = m % S;
  int t = threadIdx.x;
  __shared__ float buf[D];
  __shared__ float cs[32], sn[32];
  if (t < 32) { cs[t] = cosT[s*32 + t]; sn[t] = sinT[s*32 + t]; }
  const float* row = qkv + (size_t)m * 3 * D;
  int lane16 = t & 15;
  int e = 4 * t, eh = e >> 6, rdh = e & 63;

  for (int part = 0; part < 2; part++) {
    fv4 val = *(const fv4*)(row + part * D + 4*t);
    float ss = val[0]*val[0] + val[1]*val[1] + val[2]*val[2] + val[3]*val[3];
    ss += __shfl_xor(ss, 8); ss += __shfl_xor(ss, 4);
    ss += __shfl_xor(ss, 2); ss += __shfl_xor(ss, 1);
    float r = rsqrtf(ss * (1.0f / (float)DH) + 1e-6f);
    fv4 w4 = *(const fv4*)((part == 0 ? qnw : knw) + 4*lane16);
    *(fv4*)&buf[4*t] = val * r * w4;
    __syncthreads();
    fv4 out;
#pragma unroll
    for (int j = 0; j < 4; j++) {
      int rr = rdh + j;
      if (rr < 32) {
        float x1 = buf[eh*64 + rr], x2 = buf[eh*64 + rr + 32];
        out[j] = x1 * cs[rr] - x2 * sn[rr];
      } else {
        int f = rr - 32;
        float x1 = buf[eh*64 + f], x2 = buf[eh*64 + rr];
        out[j] = x2 * cs[f] + x1 * sn[f];
      }
    }
    float* dst = (part == 0 ? q : k);
    *(fv4*)&dst[(((size_t)(b*H + eh)) * S + s) * DH + rdh] = out;
    __syncthreads();
  }
  fv4 vv = *(const fv4*)(row + 2 * D + 4*t);
  *(fv4*)&v[(((size_t)(b*H + eh)) * S + s) * DH + rdh] = vv;
}

// ======================================================================
// gamma gate, fused: gk[m] = sigmoid( w2 . silu(w1 @ h[m]) )
// ======================================================================
__global__ __launch_bounds__(256) void k_gamma(const float* __restrict__ h,
                                               const float* __restrict__ w1,
                                               const float* __restrict__ w2,
                                               float* __restrict__ gk) {
  int m = blockIdx.x, t = threadIdx.x;
  __shared__ float hrow[D];
  *(fv4*)&hrow[4*t] = *(const fv4*)(h + (size_t)m * D + 4*t);
  __syncthreads();
  int o = t & 63, seg = t >> 6;
  const float* wr = w1 + (size_t)o * D + seg * 256;
  const float* hr = hrow + seg * 256;
  float acc = 0.f;
  for (int j = 0; j < 256; j += 4) {
    fv4 wv = *(const fv4*)(wr + j);
    acc += wv[0]*hr[j] + wv[1]*hr[j+1] + wv[2]*hr[j+2] + wv[3]*hr[j+3];
  }
  __shared__ float part[4][64];
  part[seg][o] = acc;
  __syncthreads();
  if (t < 64) {
    float dot = part[0][t] + part[1][t] + part[2][t] + part[3][t];
    float sv = dot / (1.f + expf(-dot));      // silu
    float val = sv * w2[t];
#pragma unroll
    for (int off = 32; off > 0; off >>= 1) val += __shfl_down(val, off);
    if (t == 0) gk[m] = 1.f / (1.f + expf(-val));
  }
}

// ======================================================================
// per-batch inclusive cumsum: norm[b][s] = NP + sum_{i<=s} gk[b][i]
// ======================================================================
__global__ __launch_bounds__(1024) void k_cumsum(const float* __restrict__ gk,
                                                 float* __restrict__ nrm) {
  int b = blockIdx.x, t = threadIdx.x;
  __shared__ float buf[S];
  buf[t] = gk[b*S + t];
  __syncthreads();
  for (int off = 1; off < S; off <<= 1) {
    float add = (t >= off) ? buf[t - off] : 0.f;
    __syncthreads();
    buf[t] += add;
    __syncthreads();
  }
  nrm[b*S + t] = (float)NP + buf[t];
}

// ----- shared 64x64 micro-GEMM helpers (LDS stride 68, fv4-aligned) -----
__device__ __forceinline__ void gemm_nt_16(const float (*A)[68], const float (*Bm)[68],
                                           int tr, int tc, float acc[4][4]) {
  for (int d4 = 0; d4 < 64; d4 += 4) {
    fv4 a[4], b[4];
#pragma unroll
    for (int i = 0; i < 4; i++) a[i] = *(const fv4*)&A[tr*4 + i][d4];
#pragma unroll
    for (int j = 0; j < 4; j++) b[j] = *(const fv4*)&Bm[tc*4 + j][d4];
#pragma unroll
    for (int i = 0; i < 4; i++)
#pragma unroll
      for (int j = 0; j < 4; j++)
        acc[i][j] += a[i][0]*b[j][0] + a[i][1]*b[j][1] + a[i][2]*b[j][2] + a[i][3]*b[j][3];
  }
}
__device__ __forceinline__ void gemm_nn_16(const float (*A)[68], const float (*Bm)[68],
                                           int tr, int tc, float acc[4][4]) {
  for (int k4 = 0; k4 < 64; k4 += 4) {
    fv4 a[4], b[4];
#pragma unroll
    for (int i = 0; i < 4; i++) a[i] = *(const fv4*)&A[tr*4 + i][k4];
#pragma unroll
    for (int kk = 0; kk < 4; kk++) b[kk] = *(const fv4*)&Bm[k4 + kk][tc*4];
#pragma unroll
    for (int i = 0; i < 4; i++)
#pragma unroll
      for (int j = 0; j < 4; j++)
        acc[i][j] += a[i][0]*b[0][j] + a[i][1]*b[1][j] + a[i][2]*b[2][j] + a[i][3]*b[3][j];
  }
}
__device__ __forceinline__ void load_tile64(const float* __restrict__ g,
                                            float (*dst)[68], int t) {
  for (int i = t; i < 64 * 16; i += 256) {
    int r = i >> 4, c4 = (i & 15) * 4;
    *(fv4*)&dst[r][c4] = *(const fv4*)(g + r * 64 + c4);
  }
}

// ======================================================================
// pass 1 — omega-rule memory update of q (in place), per (b,h,64-row q tile)
// acc[qi][d] = (Mp q)[qi][d] + sum_{k<=q} gk[k] (K_k . Q_qi) K_k[d]
// q_new = (1-gate)*q + gate*acc/norm[q]
// ======================================================================
__global__ __launch_bounds__(256) void k_mem(const float* __restrict__ qb,
                                             const float* __restrict__ kb,
                                             const float* __restrict__ MpB,
                                             const float* __restrict__ gk,
                                             const float* __restrict__ normc,
                                             const float* __restrict__ mg, int layer,
                                             float* __restrict__ qout) {
  int qt = blockIdx.x, bh = blockIdx.y;
  int b = bh / H, hh = bh % H;
  int t = threadIdx.x, tc = t & 15, tr = t >> 4;
  __shared__ float Qs[64][68], Ks[64][68], Ss[64][68];
  __shared__ float gks[64];
  load_tile64(qb + ((size_t)bh * S + qt*64) * DH, Qs, t);
  load_tile64(MpB + (size_t)hh * DH * DH, Ks, t);   // Mp staged in Ks
  __syncthreads();
  float acc[4][4] = {};
  gemm_nt_16(Qs, Ks, tr, tc, acc);                  // mpq
  __syncthreads();
  for (int kt = 0; kt <= qt; kt++) {
    load_tile64(kb + ((size_t)bh * S + kt*64) * DH, Ks, t);
    if (t < 64) gks[t] = gk[b*S + kt*64 + t];
    __syncthreads();
    float sc[4][4] = {};
    gemm_nt_16(Qs, Ks, tr, tc, sc);
#pragma unroll
    for (int i = 0; i < 4; i++)
#pragma unroll
      for (int j = 0; j < 4; j++) {
        int qi = tr*4 + i, kj = tc*4 + j;
        float val = sc[i][j] * gks[kj];
        if (kt == qt && kj > qi) val = 0.f;
        Ss[qi][kj] = val;
      }
    __syncthreads();
    gemm_nn_16(Ss, Ks, tr, tc, acc);
    __syncthreads();
  }
  float gate = 1.f / (1.f + expf(-mg[layer]));
#pragma unroll
  for (int i = 0; i < 4; i++)
#pragma unroll
    for (int j = 0; j < 4; j++) {
      int qi = tr*4 + i, dj = tc*4 + j;
      int sg = qt*64 + qi;
      float nq = normc[b*S + sg];
      float qold = Qs[qi][dj];
      qout[((size_t)bh * S + sg) * DH + dj] = (1.f - gate) * qold + gate * (acc[i][j] / nq);
    }
}

// ======================================================================
// pass 2 — causal flash attention, per (b,h,64-row q tile); writes o in
// (b,s,h,dh) == (M,D) layout for the w_o GEMM.
// ======================================================================
__global__ __launch_bounds__(256) void k_attn(const float* __restrict__ qb,
                                              const float* __restrict__ kb,
                                              const float* __restrict__ vb,
                                              float* __restrict__ ob) {
  int qt = blockIdx.x, bh = blockIdx.y;
  int b = bh / H, hh = bh % H;
  int t = threadIdx.x, tc = t & 15, tr = t >> 4;
  __shared__ float Qs[64][68], Ks[64][68], Vs[64][68], Ss[64][68];
  __shared__ float mrow[64], lrow[64], rscale[64], red[64][4];
  load_tile64(qb + ((size_t)bh * S + qt*64) * DH, Qs, t);
  if (t < 64) { mrow[t] = -1e30f; lrow[t] = 0.f; }
  float acc[4][4] = {};
  __syncthreads();
  int row = t >> 2, seg = t & 3;
  for (int kt = 0; kt <= qt; kt++) {
    load_tile64(kb + ((size_t)bh * S + kt*64) * DH, Ks, t);
    load_tile64(vb + ((size_t)bh * S + kt*64) * DH, Vs, t);
    __syncthreads();
    float sc[4][4] = {};
    gemm_nt_16(Qs, Ks, tr, tc, sc);
#pragma unroll
    for (int i = 0; i < 4; i++)
#pragma unroll
      for (int j = 0; j < 4; j++) {
        int qi = tr*4 + i, kj = tc*4 + j;
        float val = sc[i][j] * 0.125f;        // DH^-0.5
        if (kt == qt && kj > qi) val = -1e30f;
        Ss[qi][kj] = val;
      }
    __syncthreads();
    float pm = -1e30f;
#pragma unroll
    for (int c = 0; c < 16; c++) pm = fmaxf(pm, Ss[row][seg*16 + c]);
    red[row][seg] = pm;
    __syncthreads();
    if (t < 64) {
      float mold = mrow[t];
      float mnew = fmaxf(fmaxf(red[t][0], red[t][1]), fmaxf(red[t][2], red[t][3]));
      mnew = fmaxf(mold, mnew);
      float al = expf(mold - mnew);
      rscale[t] = al;
      mrow[t] = mnew;
      lrow[t] *= al;
    }
    __syncthreads();
    float ps = 0.f;
    float mn = mrow[row];
#pragma unroll
    for (int c = 0; c < 16; c++) {
      float p = expf(Ss[row][seg*16 + c] - mn);
      Ss[row][seg*16 + c] = p;
      ps += p;
    }
    red[row][seg] = ps;
    __syncthreads();
    if (t < 64) lrow[t] += red[t][0] + red[t][1] + red[t][2] + red[t][3];
#pragma unroll
    for (int i = 0; i < 4; i++) {
      float al = rscale[tr*4 + i];
#pragma unroll
      for (int j = 0; j < 4; j++) acc[i][j] *= al;
    }
    gemm_nn_16(Ss, Vs, tr, tc, acc);
    __syncthreads();
  }
#pragma unroll
  for (int i = 0; i < 4; i++)
#pragma unroll
    for (int j = 0; j < 4; j++) {
      int qi = tr*4 + i, dj = tc*4 + j;
      int sg = qt*64 + qi;
      ob[((size_t)b * S + sg) * D + hh * DH + dj] = acc[i][j] / lrow[qi];
    }
}

// ======================================================================
// launcher
// ======================================================================
extern "C" void kernel_launch(void* const* d_in, const int* in_sizes, int n_in,
                              void* d_out, int out_size, void* d_ws, size_t ws_size,
                              hipStream_t stream) {
  const int*   ids      = (const int*)d_in[0];
  const float* tok_emb  = (const float*)d_in[1];
  const float* w_init   = (const float*)d_in[2];
  const float* persist  = (const float*)d_in[3];
  const float* norm1_w  = (const float*)d_in[4];
  const float* norm2_w  = (const float*)d_in[5];
  const float* norm_f_w = (const float*)d_in[6];
  const float* qkv_w    = (const float*)d_in[7];
  const float* q_norm_w = (const float*)d_in[8];
  const float* k_norm_w = (const float*)d_in[9];
  const float* gamma_w1 = (const float*)d_in[10];
  const float* gamma_w2 = (const float*)d_in[11];
  const float* mem_gate = (const float*)d_in[12];
  const float* w_o      = (const float*)d_in[13];
  const float* ffn_w1   = (const float*)d_in[14];
  const float* ffn_w2   = (const float*)d_in[15];
  const float* ffn_w3   = (const float*)d_in[16];
  float* out = (float*)d_out;

  // ---- workspace layout (floats). ffn1 aliases qkv (disjoint lifetimes). ----
  float* ws   = (float*)d_ws;
  float* x    = ws;                       // M*D
  float* h    = x    + (size_t)M * D;     // M*D
  float* qkv  = h    + (size_t)M * D;     // M*3D  (also ffn1: M*FF <= M*3D)
  float* qb   = qkv  + (size_t)M * 3 * D; // M*D
  float* kb   = qb   + (size_t)M * D;     // M*D
  float* vb   = kb   + (size_t)M * D;     // M*D
  float* ob   = vb   + (size_t)M * D;     // M*D
  float* gk   = ob   + (size_t)M * D;     // M
  float* nrm  = gk   + M;                 // M
  float* cosT = nrm  + M;                 // S*32
  float* sinT = cosT + S * 32;            // S*32
  float* MpB  = sinT + S * 32;            // H*DH*DH
  float* ffn1 = qkv;                      // alias

  k_embed<<<M, 256, 0, stream>>>(ids, tok_emb, w_init, x);
  k_rope_tables<<<(S*32 + 255)/256, 256, 0, stream>>>(cosT, sinT);
  k_mp<<<H, 256, 0, stream>>>(persist, MpB);

  for (int l = 0; l < NL; l++) {
    k_rms<<<M, 256, 0, stream>>>(x, norm1_w + (size_t)l * D, h);
    k_gemm<0><<<dim3(3*D/64, M/64), 256, 0, stream>>>(h, qkv_w + (size_t)l*3*D*D, qkv, M, 3*D, D);
    k_qkvpost<<<M, 256, 0, stream>>>(qkv, q_norm_w + (size_t)l*DH, k_norm_w + (size_t)l*DH,
                                     cosT, sinT, qb, kb, vb);
    k_gamma<<<M, 256, 0, stream>>>(h, gamma_w1 + (size_t)l*GH*D, gamma_w2 + (size_t)l*GH, gk);
    k_cumsum<<<B, S, 0, stream>>>(gk, nrm);
    k_mem<<<dim3(S/64, B*H), 256, 0, stream>>>(qb, kb, MpB, gk, nrm, mem_gate, l, qb);
    k_attn<<<dim3(S/64, B*H), 256, 0, stream>>>(qb, kb, vb, ob);
    k_gemm<2><<<dim3(D/64, M/64), 256, 0, stream>>>(ob, w_o + (size_t)l*D*D, x, M, D, D);
    k_rms<<<M, 256, 0, stream>>>(x, norm2_w + (size_t)l * D, h);
    k_gemm<1><<<dim3((FF+63)/64, M/64), 256, 0, stream>>>(h, ffn_w1 + (size_t)l*FF*D, ffn1, M, FF, D);
    k_gemm<3><<<dim3((FF+63)/64, M/64), 256, 0, stream>>>(h, ffn_w2 + (size_t)l*FF*D, ffn1, M, FF, D);
    k_gemm<2><<<dim3(D/64, M/64), 256, 0, stream>>>(ffn1, ffn_w3 + (size_t)l*D*FF, x, M, D, FF);
  }

  k_rms<<<M, 256, 0, stream>>>(x, norm_f_w, h);
  k_gemm<0><<<dim3(V/64, M/64), 256, 0, stream>>>(h, tok_emb, out, M, V, D);
}

// Round 2
// 7216.814 us; speedup vs baseline: 3.5999x; 3.5999x over previous
//
#include <hip/hip_runtime.h>
#include <hip/hip_bf16.h>
#include <math.h>

// ---------------- problem constants ----------------
#define B 2
#define S 1024
#define D 1024
#define H 16
#define DH 64
#define NL 6
#define GH 64
#define NP 16
#define V 32000
#define FF 2730
#define M (B*S)   // 2048 rows

typedef float fv4 __attribute__((ext_vector_type(4)));
typedef short bf16x8 __attribute__((ext_vector_type(8)));       // 8 bf16 = 4 VGPRs
typedef unsigned short us4 __attribute__((ext_vector_type(4))); // 4 bf16 = 8 bytes

__device__ __forceinline__ unsigned short f2bf(float f) {
  union { float f; unsigned u; } v; v.f = f;
  unsigned r = v.u + 0x7FFFu + ((v.u >> 16) & 1u);   // RNE
  return (unsigned short)(r >> 16);
}

// ======================================================================
// embed: x[m][:] = tok_emb[ids[m]][:] + w_init[:]
// ======================================================================
__global__ __launch_bounds__(256) void k_embed(const int* __restrict__ ids,
                                               const float* __restrict__ emb,
                                               const float* __restrict__ winit,
                                               float* __restrict__ x) {
  int m = blockIdx.x, t = threadIdx.x;
  int id = ids[m];
  fv4 a = *(const fv4*)(emb + (size_t)id * D + 4*t);
  fv4 w = *(const fv4*)(winit + 4*t);
  *(fv4*)(x + (size_t)m * D + 4*t) = a + w;
}

// ======================================================================
// rope tables: cos/sin (S x 32), inv_freq = 10000^(-2f/DH)
// ======================================================================
__global__ void k_rope_tables(float* __restrict__ cosT, float* __restrict__ sinT) {
  int idx = blockIdx.x * blockDim.x + threadIdx.x;
  if (idx >= S * 32) return;
  int s = idx >> 5, f = idx & 31;
  float inv = powf(10000.0f, -2.0f * (float)f / (float)DH);
  float ang = (float)s * inv;
  cosT[idx] = cosf(ang);
  sinT[idx] = sinf(ang);
}

// ======================================================================
// Mp[h][d][e] = sum_n p[n][h][d] * p[n][h][e]
// ======================================================================
__global__ __launch_bounds__(256) void k_mp(const float* __restrict__ pers,
                                            float* __restrict__ Mp) {
  int h = blockIdx.x, t = threadIdx.x;
  __shared__ float p[NP][DH];
  for (int i = t; i < NP * DH; i += 256) {
    int n = i / DH, dh = i % DH;
    p[n][dh] = pers[(size_t)n * D + h * DH + dh];
  }
  __syncthreads();
  for (int i = t; i < DH * DH; i += 256) {
    int d = i / DH, e = i % DH;
    float s = 0.f;
#pragma unroll
    for (int n = 0; n < NP; n++) s += p[n][d] * p[n][e];
    Mp[(size_t)h * DH * DH + i] = s;
  }
}

// ======================================================================
// rmsnorm over rows of D
// ======================================================================
__global__ __launch_bounds__(256) void k_rms(const float* __restrict__ in,
                                             const float* __restrict__ w,
                                             float* __restrict__ out) {
  int m = blockIdx.x, t = threadIdx.x;
  fv4 v = *(const fv4*)(in + (size_t)m * D + 4*t);
  float ss = v[0]*v[0] + v[1]*v[1] + v[2]*v[2] + v[3]*v[3];
#pragma unroll
  for (int off = 32; off > 0; off >>= 1) ss += __shfl_down(ss, off);
  __shared__ float buf[4];
  if ((t & 63) == 0) buf[t >> 6] = ss;
  __syncthreads();
  float tot = buf[0] + buf[1] + buf[2] + buf[3];
  float r = rsqrtf(tot * (1.0f / (float)D) + 1e-6f);
  fv4 wv = *(const fv4*)(w + 4*t);
  *(fv4*)(out + (size_t)m * D + 4*t) = v * r * wv;
}

// ======================================================================
// bf16 MFMA GEMM: C[m][n] (op)= act( sum_k A[m][k] * W[n][k] )  (A,W f32 in HBM)
// Tile BM x 128, BK=32, 256 threads = 4 waves (2x2), mfma_f32_16x16x32_bf16.
// MFR = m-fragments per wave (4 -> BM=128, 2 -> BM=64).
// Reg-staged f32->bf16 conversion into LDS (RNE).
// EPI: 0 store, 1 silu-store, 2 add-to-C, 3 mul-into-C
// Requires Mm % BM == 0 (true here: M=2048).
// ======================================================================
template<int EPI, int MFR>
__global__ __launch_bounds__(256) void k_mgemm(const float* __restrict__ A,
                                               const float* __restrict__ W,
                                               float* __restrict__ C,
                                               int Mm, int Nn, int Kk) {
  constexpr int BM = MFR * 32;
  __shared__ __attribute__((aligned(16))) unsigned short As[BM * 32];
  __shared__ __attribute__((aligned(16))) unsigned short Ws[128 * 32];
  int t = threadIdx.x;
  int lane = t & 63, wave = t >> 6;
  int wr = wave >> 1, wc = wave & 1;
  int l16 = lane & 15, lkb = lane >> 4;
  int m0 = blockIdx.y * BM, n0 = blockIdx.x * 128;
  fv4 acc[MFR][4] = {};

  for (int k0 = 0; k0 < Kk; k0 += 32) {
    if (k0 + 32 <= Kk) {
      // ---- fast path: fv4 loads, full K-slab ----
#pragma unroll
      for (int p = 0; p < MFR; p++) {
        int i = t + p * 256;
        int r = i >> 3, c4 = (i & 7) * 4;
        fv4 v = *(const fv4*)(A + (size_t)(m0 + r) * Kk + k0 + c4);
        us4 o; o[0] = f2bf(v[0]); o[1] = f2bf(v[1]); o[2] = f2bf(v[2]); o[3] = f2bf(v[3]);
        *(us4*)&As[r * 32 + c4] = o;
      }
#pragma unroll
      for (int p = 0; p < 4; p++) {
        int i = t + p * 256;
        int r = i >> 3, c4 = (i & 7) * 4;
        int gn = n0 + r;
        fv4 v = {};
        if (gn < Nn) v = *(const fv4*)(W + (size_t)gn * Kk + k0 + c4);
        us4 o; o[0] = f2bf(v[0]); o[1] = f2bf(v[1]); o[2] = f2bf(v[2]); o[3] = f2bf(v[3]);
        *(us4*)&Ws[r * 32 + c4] = o;
      }
    } else {
      // ---- K tail (K=2730 case): per-element guards ----
#pragma unroll
      for (int p = 0; p < MFR; p++) {
        int i = t + p * 256;
        int r = i >> 3, c4 = (i & 7) * 4;
        us4 o;
#pragma unroll
        for (int q = 0; q < 4; q++) {
          int gk = k0 + c4 + q;
          o[q] = (gk < Kk) ? f2bf(A[(size_t)(m0 + r) * Kk + gk]) : (unsigned short)0;
        }
        *(us4*)&As[r * 32 + c4] = o;
      }
#pragma unroll
      for (int p = 0; p < 4; p++) {
        int i = t + p * 256;
        int r = i >> 3, c4 = (i & 7) * 4;
        int gn = n0 + r;
        us4 o;
#pragma unroll
        for (int q = 0; q < 4; q++) {
          int gk = k0 + c4 + q;
          o[q] = (gk < Kk && gn < Nn) ? f2bf(W[(size_t)gn * Kk + gk]) : (unsigned short)0;
        }
        *(us4*)&Ws[r * 32 + c4] = o;
      }
    }
    __syncthreads();
    bf16x8 af[MFR], bfr[4];
#pragma unroll
    for (int i = 0; i < MFR; i++)
      af[i] = *(const bf16x8*)&As[((wr * MFR + i) * 16 + l16) * 32 + lkb * 8];
#pragma unroll
    for (int j = 0; j < 4; j++)
      bfr[j] = *(const bf16x8*)&Ws[((wc * 4 + j) * 16 + l16) * 32 + lkb * 8];
#pragma unroll
    for (int i = 0; i < MFR; i++)
#pragma unroll
      for (int j = 0; j < 4; j++)
        acc[i][j] = __builtin_amdgcn_mfma_f32_16x16x32_bf16(af[i], bfr[j], acc[i][j], 0, 0, 0);
    __syncthreads();
  }

  // epilogue: C/D layout col=lane&15, row=(lane>>4)*4+reg  [verified m89]
#pragma unroll
  for (int i = 0; i < MFR; i++) {
    int gr0 = m0 + (wr * MFR + i) * 16 + lkb * 4;
#pragma unroll
    for (int j = 0; j < 4; j++) {
      int gc = n0 + (wc * 4 + j) * 16 + l16;
      if (gc < Nn) {
#pragma unroll
        for (int r = 0; r < 4; r++) {
          size_t idx = (size_t)(gr0 + r) * Nn + gc;
          float val = acc[i][j][r];
          if (EPI == 0) C[idx] = val;
          else if (EPI == 1) C[idx] = val / (1.f + expf(-val));
          else if (EPI == 2) C[idx] += val;
          else C[idx] *= val;
        }
      }
    }
  }
}

// ======================================================================
// qkv post: per (b,s) row — split heads, qk rmsnorm(DH), rope, write q/k/v
// ======================================================================
__global__ __launch_bounds__(256) void k_qkvpost(const float* __restrict__ qkv,
                                                 const float* __restrict__ qnw,
                                                 const float* __restrict__ knw,
                                                 const float* __restrict__ cosT,
                                                 const float* __restrict__ sinT,
                                                 float* __restrict__ q,
                                                 float* __restrict__ k,
                                                 float* __restrict__ v) {
  int m = blockIdx.x;
  int b = m / S, s = m % S;
  int t = threadIdx.x;
  __shared__ float buf[D];
  __shared__ float cs[32], sn[32];
  if (t < 32) { cs[t] = cosT[s*32 + t]; sn[t] = sinT[s*32 + t]; }
  const float* row = qkv + (size_t)m * 3 * D;
  int lane16 = t & 15;
  int e = 4 * t, eh = e >> 6, rdh = e & 63;

  for (int part = 0; part < 2; part++) {
    fv4 val = *(const fv4*)(row + part * D + 4*t);
    float ss = val[0]*val[0] + val[1]*val[1] + val[2]*val[2] + val[3]*val[3];
    ss += __shfl_xor(ss, 8); ss += __shfl_xor(ss, 4);
    ss += __shfl_xor(ss, 2); ss += __shfl_xor(ss, 1);
    float r = rsqrtf(ss * (1.0f / (float)DH) + 1e-6f);
    fv4 w4 = *(const fv4*)((part == 0 ? qnw : knw) + 4*lane16);
    *(fv4*)&buf[4*t] = val * r * w4;
    __syncthreads();
    fv4 out;
#pragma unroll
    for (int j = 0; j < 4; j++) {
      int rr = rdh + j;
      if (rr < 32) {
        float x1 = buf[eh*64 + rr], x2 = buf[eh*64 + rr + 32];
        out[j] = x1 * cs[rr] - x2 * sn[rr];
      } else {
        int f = rr - 32;
        float x1 = buf[eh*64 + f], x2 = buf[eh*64 + rr];
        out[j] = x2 * cs[f] + x1 * sn[f];
      }
    }
    float* dst = (part == 0 ? q : k);
    *(fv4*)&dst[(((size_t)(b*H + eh)) * S + s) * DH + rdh] = out;
    __syncthreads();
  }
  fv4 vv = *(const fv4*)(row + 2 * D + 4*t);
  *(fv4*)&v[(((size_t)(b*H + eh)) * S + s) * DH + rdh] = vv;
}

// ======================================================================
// gamma gate, fused: gk[m] = sigmoid( w2 . silu(w1 @ h[m]) )
// ======================================================================
__global__ __launch_bounds__(256) void k_gamma(const float* __restrict__ h,
                                               const float* __restrict__ w1,
                                               const float* __restrict__ w2,
                                               float* __restrict__ gk) {
  int m = blockIdx.x, t = threadIdx.x;
  __shared__ float hrow[D];
  *(fv4*)&hrow[4*t] = *(const fv4*)(h + (size_t)m * D + 4*t);
  __syncthreads();
  int o = t & 63, seg = t >> 6;
  const float* wr = w1 + (size_t)o * D + seg * 256;
  const float* hr = hrow + seg * 256;
  float acc = 0.f;
  for (int j = 0; j < 256; j += 4) {
    fv4 wv = *(const fv4*)(wr + j);
    acc += wv[0]*hr[j] + wv[1]*hr[j+1] + wv[2]*hr[j+2] + wv[3]*hr[j+3];
  }
  __shared__ float part[4][64];
  part[seg][o] = acc;
  __syncthreads();
  if (t < 64) {
    float dot = part[0][t] + part[1][t] + part[2][t] + part[3][t];
    float sv = dot / (1.f + expf(-dot));      // silu
    float val = sv * w2[t];
#pragma unroll
    for (int off = 32; off > 0; off >>= 1) val += __shfl_down(val, off);
    if (t == 0) gk[m] = 1.f / (1.f + expf(-val));
  }
}

// ======================================================================
// per-batch inclusive cumsum: norm[b][s] = NP + sum_{i<=s} gk[b][i]
// ======================================================================
__global__ __launch_bounds__(1024) void k_cumsum(const float* __restrict__ gk,
                                                 float* __restrict__ nrm) {
  int b = blockIdx.x, t = threadIdx.x;
  __shared__ float buf[S];
  buf[t] = gk[b*S + t];
  __syncthreads();
  for (int off = 1; off < S; off <<= 1) {
    float add = (t >= off) ? buf[t - off] : 0.f;
    __syncthreads();
    buf[t] += add;
    __syncthreads();
  }
  nrm[b*S + t] = (float)NP + buf[t];
}

// ----- shared 64x64 micro-GEMM helpers (LDS stride 68, fv4-aligned) -----
__device__ __forceinline__ void gemm_nt_16(const float (*A)[68], const float (*Bm)[68],
                                           int tr, int tc, float acc[4][4]) {
  for (int d4 = 0; d4 < 64; d4 += 4) {
    fv4 a[4], b[4];
#pragma unroll
    for (int i = 0; i < 4; i++) a[i] = *(const fv4*)&A[tr*4 + i][d4];
#pragma unroll
    for (int j = 0; j < 4; j++) b[j] = *(const fv4*)&Bm[tc*4 + j][d4];
#pragma unroll
    for (int i = 0; i < 4; i++)
#pragma unroll
      for (int j = 0; j < 4; j++)
        acc[i][j] += a[i][0]*b[j][0] + a[i][1]*b[j][1] + a[i][2]*b[j][2] + a[i][3]*b[j][3];
  }
}
__device__ __forceinline__ void gemm_nn_16(const float (*A)[68], const float (*Bm)[68],
                                           int tr, int tc, float acc[4][4]) {
  for (int k4 = 0; k4 < 64; k4 += 4) {
    fv4 a[4], b[4];
#pragma unroll
    for (int i = 0; i < 4; i++) a[i] = *(const fv4*)&A[tr*4 + i][k4];
#pragma unroll
    for (int kk = 0; kk < 4; kk++) b[kk] = *(const fv4*)&Bm[k4 + kk][tc*4];
#pragma unroll
    for (int i = 0; i < 4; i++)
#pragma unroll
      for (int j = 0; j < 4; j++)
        acc[i][j] += a[i][0]*b[0][j] + a[i][1]*b[1][j] + a[i][2]*b[2][j] + a[i][3]*b[3][j];
  }
}
__device__ __forceinline__ void load_tile64(const float* __restrict__ g,
                                            float (*dst)[68], int t) {
  for (int i = t; i < 64 * 16; i += 256) {
    int r = i >> 4, c4 = (i & 15) * 4;
    *(fv4*)&dst[r][c4] = *(const fv4*)(g + r * 64 + c4);
  }
}

// ======================================================================
// pass 1 — omega-rule memory update of q (in place)
// ======================================================================
__global__ __launch_bounds__(256) void k_mem(const float* __restrict__ qb,
                                             const float* __restrict__ kb,
                                             const float* __restrict__ MpB,
                                             const float* __restrict__ gk,
                                             const float* __restrict__ normc,
                                             const float* __restrict__ mg, int layer,
                                             float* __restrict__ qout) {
  int qt = blockIdx.x, bh = blockIdx.y;
  int b = bh / H, hh = bh % H;
  int t = threadIdx.x, tc = t & 15, tr = t >> 4;
  __shared__ float Qs[64][68], Ks[64][68], Ss[64][68];
  __shared__ float gks[64];
  load_tile64(qb + ((size_t)bh * S + qt*64) * DH, Qs, t);
  load_tile64(MpB + (size_t)hh * DH * DH, Ks, t);   // Mp staged in Ks
  __syncthreads();
  float acc[4][4] = {};
  gemm_nt_16(Qs, Ks, tr, tc, acc);                  // mpq
  __syncthreads();
  for (int kt = 0; kt <= qt; kt++) {
    load_tile64(kb + ((size_t)bh * S + kt*64) * DH, Ks, t);
    if (t < 64) gks[t] = gk[b*S + kt*64 + t];
    __syncthreads();
    float sc[4][4] = {};
    gemm_nt_16(Qs, Ks, tr, tc, sc);
#pragma unroll
    for (int i = 0; i < 4; i++)
#pragma unroll
      for (int j = 0; j < 4; j++) {
        int qi = tr*4 + i, kj = tc*4 + j;
        float val = sc[i][j] * gks[kj];
        if (kt == qt && kj > qi) val = 0.f;
        Ss[qi][kj] = val;
      }
    __syncthreads();
    gemm_nn_16(Ss, Ks, tr, tc, acc);
    __syncthreads();
  }
  float gate = 1.f / (1.f + expf(-mg[layer]));
#pragma unroll
  for (int i = 0; i < 4; i++)
#pragma unroll
    for (int j = 0; j < 4; j++) {
      int qi = tr*4 + i, dj = tc*4 + j;
      int sg = qt*64 + qi;
      float nq = normc[b*S + sg];
      float qold = Qs[qi][dj];
      qout[((size_t)bh * S + sg) * DH + dj] = (1.f - gate) * qold + gate * (acc[i][j] / nq);
    }
}

// ======================================================================
// pass 2 — causal flash attention
// ======================================================================
__global__ __launch_bounds__(256) void k_attn(const float* __restrict__ qb,
                                              const float* __restrict__ kb,
                                              const float* __restrict__ vb,
                                              float* __restrict__ ob) {
  int qt = blockIdx.x, bh = blockIdx.y;
  int b = bh / H, hh = bh % H;
  int t = threadIdx.x, tc = t & 15, tr = t >> 4;
  __shared__ float Qs[64][68], Ks[64][68], Vs[64][68], Ss[64][68];
  __shared__ float mrow[64], lrow[64], rscale[64], red[64][4];
  load_tile64(qb + ((size_t)bh * S + qt*64) * DH, Qs, t);
  if (t < 64) { mrow[t] = -1e30f; lrow[t] = 0.f; }
  float acc[4][4] = {};
  __syncthreads();
  int row = t >> 2, seg = t & 3;
  for (int kt = 0; kt <= qt; kt++) {
    load_tile64(kb + ((size_t)bh * S + kt*64) * DH, Ks, t);
    load_tile64(vb + ((size_t)bh * S + kt*64) * DH, Vs, t);
    __syncthreads();
    float sc[4][4] = {};
    gemm_nt_16(Qs, Ks, tr, tc, sc);
#pragma unroll
    for (int i = 0; i < 4; i++)
#pragma unroll
      for (int j = 0; j < 4; j++) {
        int qi = tr*4 + i, kj = tc*4 + j;
        float val = sc[i][j] * 0.125f;        // DH^-0.5
        if (kt == qt && kj > qi) val = -1e30f;
        Ss[qi][kj] = val;
      }
    __syncthreads();
    float pm = -1e30f;
#pragma unroll
    for (int c = 0; c < 16; c++) pm = fmaxf(pm, Ss[row][seg*16 + c]);
    red[row][seg] = pm;
    __syncthreads();
    if (t < 64) {
      float mold = mrow[t];
      float mnew = fmaxf(fmaxf(red[t][0], red[t][1]), fmaxf(red[t][2], red[t][3]));
      mnew = fmaxf(mold, mnew);
      float al = expf(mold - mnew);
      rscale[t] = al;
      mrow[t] = mnew;
      lrow[t] *= al;
    }
    __syncthreads();
    float ps = 0.f;
    float mn = mrow[row];
#pragma unroll
    for (int c = 0; c < 16; c++) {
      float p = expf(Ss[row][seg*16 + c] - mn);
      Ss[row][seg*16 + c] = p;
      ps += p;
    }
    red[row][seg] = ps;
    __syncthreads();
    if (t < 64) lrow[t] += red[t][0] + red[t][1] + red[t][2] + red[t][3];
#pragma unroll
    for (int i = 0; i < 4; i++) {
      float al = rscale[tr*4 + i];
#pragma unroll
      for (int j = 0; j < 4; j++) acc[i][j] *= al;
    }
    gemm_nn_16(Ss, Vs, tr, tc, acc);
    __syncthreads();
  }
#pragma unroll
  for (int i = 0; i < 4; i++)
#pragma unroll
    for (int j = 0; j < 4; j++) {
      int qi = tr*4 + i, dj = tc*4 + j;
      int sg = qt*64 + qi;
      ob[((size_t)b * S + sg) * D + hh * DH + dj] = acc[i][j] / lrow[qi];
    }
}

// ======================================================================
// launcher
// ======================================================================
extern "C" void kernel_launch(void* const* d_in, const int* in_sizes, int n_in,
                              void* d_out, int out_size, void* d_ws, size_t ws_size,
                              hipStream_t stream) {
  const int*   ids      = (const int*)d_in[0];
  const float* tok_emb  = (const float*)d_in[1];
  const float* w_init   = (const float*)d_in[2];
  const float* persist  = (const float*)d_in[3];
  const float* norm1_w  = (const float*)d_in[4];
  const float* norm2_w  = (const float*)d_in[5];
  const float* norm_f_w = (const float*)d_in[6];
  const float* qkv_w    = (const float*)d_in[7];
  const float* q_norm_w = (const float*)d_in[8];
  const float* k_norm_w = (const float*)d_in[9];
  const float* gamma_w1 = (const float*)d_in[10];
  const float* gamma_w2 = (const float*)d_in[11];
  const float* mem_gate = (const float*)d_in[12];
  const float* w_o      = (const float*)d_in[13];
  const float* ffn_w1   = (const float*)d_in[14];
  const float* ffn_w2   = (const float*)d_in[15];
  const float* ffn_w3   = (const float*)d_in[16];
  float* out = (float*)d_out;

  // ---- workspace layout (floats). ffn1 aliases qkv (disjoint lifetimes). ----
  float* ws   = (float*)d_ws;
  float* x    = ws;                       // M*D
  float* h    = x    + (size_t)M * D;     // M*D
  float* qkv  = h    + (size_t)M * D;     // M*3D  (also ffn1: M*FF <= M*3D)
  float* qb   = qkv  + (size_t)M * 3 * D; // M*D
  float* kb   = qb   + (size_t)M * D;     // M*D
  float* vb   = kb   + (size_t)M * D;     // M*D
  float* ob   = vb   + (size_t)M * D;     // M*D
  float* gk   = ob   + (size_t)M * D;     // M
  float* nrm  = gk   + M;                 // M
  float* cosT = nrm  + M;                 // S*32
  float* sinT = cosT + S * 32;            // S*32
  float* MpB  = sinT + S * 32;            // H*DH*DH
  float* ffn1 = qkv;                      // alias

  k_embed<<<M, 256, 0, stream>>>(ids, tok_emb, w_init, x);
  k_rope_tables<<<(S*32 + 255)/256, 256, 0, stream>>>(cosT, sinT);
  k_mp<<<H, 256, 0, stream>>>(persist, MpB);

  for (int l = 0; l < NL; l++) {
    k_rms<<<M, 256, 0, stream>>>(x, norm1_w + (size_t)l * D, h);
    k_mgemm<0,4><<<dim3(3*D/128, M/128), 256, 0, stream>>>(h, qkv_w + (size_t)l*3*D*D, qkv, M, 3*D, D);
    k_qkvpost<<<M, 256, 0, stream>>>(qkv, q_norm_w + (size_t)l*DH, k_norm_w + (size_t)l*DH,
                                     cosT, sinT, qb, kb, vb);
    k_gamma<<<M, 256, 0, stream>>>(h, gamma_w1 + (size_t)l*GH*D, gamma_w2 + (size_t)l*GH, gk);
    k_cumsum<<<B, S, 0, stream>>>(gk, nrm);
    k_mem<<<dim3(S/64, B*H), 256, 0, stream>>>(qb, kb, MpB, gk, nrm, mem_gate, l, qb);
    k_attn<<<dim3(S/64, B*H), 256, 0, stream>>>(qb, kb, vb, ob);
    k_mgemm<2,2><<<dim3(D/128, M/64), 256, 0, stream>>>(ob, w_o + (size_t)l*D*D, x, M, D, D);
    k_rms<<<M, 256, 0, stream>>>(x, norm2_w + (size_t)l * D, h);
    k_mgemm<1,4><<<dim3((FF+127)/128, M/128), 256, 0, stream>>>(h, ffn_w1 + (size_t)l*FF*D, ffn1, M, FF, D);
    k_mgemm<3,4><<<dim3((FF+127)/128, M/128), 256, 0, stream>>>(h, ffn_w2 + (size_t)l*FF*D, ffn1, M, FF, D);
    k_mgemm<2,2><<<dim3(D/128, M/64), 256, 0, stream>>>(ffn1, ffn_w3 + (size_t)l*D*FF, x, M, D, FF);
  }

  k_rms<<<M, 256, 0, stream>>>(x, norm_f_w, h);
  k_mgemm<0,4><<<dim3(V/128, M/128), 256, 0, stream>>>(h, tok_emb, out, M, V, D);
}

// Round 3
// 5162.504 us; speedup vs baseline: 5.0323x; 1.3979x over previous
//
#include <hip/hip_runtime.h>
#include <hip/hip_bf16.h>
#include <math.h>

// ---------------- problem constants ----------------
#define B 2
#define S 1024
#define D 1024
#define H 16
#define DH 64
#define NL 6
#define GH 64
#define NP 16
#define V 32000
#define FF 2730
#define M (B*S)   // 2048 rows

typedef float fv4 __attribute__((ext_vector_type(4)));
typedef short bf16x8 __attribute__((ext_vector_type(8)));       // 8 bf16 = 4 VGPRs
typedef unsigned short us4 __attribute__((ext_vector_type(4))); // 4 bf16 = 8 bytes
typedef unsigned short us;

#define MFMA16 __builtin_amdgcn_mfma_f32_16x16x32_bf16

__device__ __forceinline__ us f2bf(float f) {
  union { float f; unsigned u; } v; v.f = f;
  unsigned r = v.u + 0x7FFFu + ((v.u >> 16) & 1u);   // RNE
  return (us)(r >> 16);
}
__device__ __forceinline__ float bf2f(us h) {
  union { unsigned u; float f; } v; v.u = ((unsigned)h) << 16;
  return v.f;
}

// ======================================================================
// embed
// ======================================================================
__global__ __launch_bounds__(256) void k_embed(const int* __restrict__ ids,
                                               const float* __restrict__ emb,
                                               const float* __restrict__ winit,
                                               float* __restrict__ x) {
  int m = blockIdx.x, t = threadIdx.x;
  int id = ids[m];
  fv4 a = *(const fv4*)(emb + (size_t)id * D + 4*t);
  fv4 w = *(const fv4*)(winit + 4*t);
  *(fv4*)(x + (size_t)m * D + 4*t) = a + w;
}

// ======================================================================
// rope tables
// ======================================================================
__global__ void k_rope_tables(float* __restrict__ cosT, float* __restrict__ sinT) {
  int idx = blockIdx.x * blockDim.x + threadIdx.x;
  if (idx >= S * 32) return;
  int s = idx >> 5, f = idx & 31;
  float inv = powf(10000.0f, -2.0f * (float)f / (float)DH);
  float ang = (float)s * inv;
  cosT[idx] = cosf(ang);
  sinT[idx] = sinf(ang);
}

// ======================================================================
// Mp[h][d][e] = sum_n p[n][h][d] * p[n][h][e]   (symmetric)
// ======================================================================
__global__ __launch_bounds__(256) void k_mp(const float* __restrict__ pers,
                                            float* __restrict__ Mp) {
  int h = blockIdx.x, t = threadIdx.x;
  __shared__ float p[NP][DH];
  for (int i = t; i < NP * DH; i += 256) {
    int n = i / DH, dh = i % DH;
    p[n][dh] = pers[(size_t)n * D + h * DH + dh];
  }
  __syncthreads();
  for (int i = t; i < DH * DH; i += 256) {
    int d = i / DH, e = i % DH;
    float s = 0.f;
#pragma unroll
    for (int n = 0; n < NP; n++) s += p[n][d] * p[n][e];
    Mp[(size_t)h * DH * DH + i] = s;
  }
}

// ======================================================================
// rmsnorm rows of D
// ======================================================================
__global__ __launch_bounds__(256) void k_rms(const float* __restrict__ in,
                                             const float* __restrict__ w,
                                             float* __restrict__ out) {
  int m = blockIdx.x, t = threadIdx.x;
  fv4 v = *(const fv4*)(in + (size_t)m * D + 4*t);
  float ss = v[0]*v[0] + v[1]*v[1] + v[2]*v[2] + v[3]*v[3];
#pragma unroll
  for (int off = 32; off > 0; off >>= 1) ss += __shfl_down(ss, off);
  __shared__ float buf[4];
  if ((t & 63) == 0) buf[t >> 6] = ss;
  __syncthreads();
  float tot = buf[0] + buf[1] + buf[2] + buf[3];
  float r = rsqrtf(tot * (1.0f / (float)D) + 1e-6f);
  fv4 wv = *(const fv4*)(w + 4*t);
  *(fv4*)(out + (size_t)m * D + 4*t) = v * r * wv;
}

// ======================================================================
// bf16 MFMA GEMM (A,W f32 in HBM). Grid: x = M-tiles (fast), y = N-tiles.
// ======================================================================
template<int EPI, int MFR>
__global__ __launch_bounds__(256) void k_mgemm(const float* __restrict__ A,
                                               const float* __restrict__ W,
                                               float* __restrict__ C,
                                               int Mm, int Nn, int Kk) {
  constexpr int BM = MFR * 32;
  __shared__ __attribute__((aligned(16))) us As[BM * 32];
  __shared__ __attribute__((aligned(16))) us Ws[128 * 32];
  int t = threadIdx.x;
  int lane = t & 63, wave = t >> 6;
  int wr = wave >> 1, wc = wave & 1;
  int l16 = lane & 15, lkb = lane >> 4;
  int m0 = blockIdx.x * BM, n0 = blockIdx.y * 128;
  fv4 acc[MFR][4] = {};

  for (int k0 = 0; k0 < Kk; k0 += 32) {
    if (k0 + 32 <= Kk) {
#pragma unroll
      for (int p = 0; p < MFR; p++) {
        int i = t + p * 256;
        int r = i >> 3, c4 = (i & 7) * 4;
        fv4 v = *(const fv4*)(A + (size_t)(m0 + r) * Kk + k0 + c4);
        us4 o; o[0] = f2bf(v[0]); o[1] = f2bf(v[1]); o[2] = f2bf(v[2]); o[3] = f2bf(v[3]);
        *(us4*)&As[r * 32 + c4] = o;
      }
#pragma unroll
      for (int p = 0; p < 4; p++) {
        int i = t + p * 256;
        int r = i >> 3, c4 = (i & 7) * 4;
        int gn = n0 + r;
        fv4 v = {};
        if (gn < Nn) v = *(const fv4*)(W + (size_t)gn * Kk + k0 + c4);
        us4 o; o[0] = f2bf(v[0]); o[1] = f2bf(v[1]); o[2] = f2bf(v[2]); o[3] = f2bf(v[3]);
        *(us4*)&Ws[r * 32 + c4] = o;
      }
    } else {
#pragma unroll
      for (int p = 0; p < MFR; p++) {
        int i = t + p * 256;
        int r = i >> 3, c4 = (i & 7) * 4;
        us4 o;
#pragma unroll
        for (int q = 0; q < 4; q++) {
          int gk = k0 + c4 + q;
          o[q] = (gk < Kk) ? f2bf(A[(size_t)(m0 + r) * Kk + gk]) : (us)0;
        }
        *(us4*)&As[r * 32 + c4] = o;
      }
#pragma unroll
      for (int p = 0; p < 4; p++) {
        int i = t + p * 256;
        int r = i >> 3, c4 = (i & 7) * 4;
        int gn = n0 + r;
        us4 o;
#pragma unroll
        for (int q = 0; q < 4; q++) {
          int gk = k0 + c4 + q;
          o[q] = (gk < Kk && gn < Nn) ? f2bf(W[(size_t)gn * Kk + gk]) : (us)0;
        }
        *(us4*)&Ws[r * 32 + c4] = o;
      }
    }
    __syncthreads();
    bf16x8 af[MFR], bfr[4];
#pragma unroll
    for (int i = 0; i < MFR; i++)
      af[i] = *(const bf16x8*)&As[((wr * MFR + i) * 16 + l16) * 32 + lkb * 8];
#pragma unroll
    for (int j = 0; j < 4; j++)
      bfr[j] = *(const bf16x8*)&Ws[((wc * 4 + j) * 16 + l16) * 32 + lkb * 8];
#pragma unroll
    for (int i = 0; i < MFR; i++)
#pragma unroll
      for (int j = 0; j < 4; j++)
        acc[i][j] = MFMA16(af[i], bfr[j], acc[i][j], 0, 0, 0);
    __syncthreads();
  }

#pragma unroll
  for (int i = 0; i < MFR; i++) {
    int gr0 = m0 + (wr * MFR + i) * 16 + lkb * 4;
#pragma unroll
    for (int j = 0; j < 4; j++) {
      int gc = n0 + (wc * 4 + j) * 16 + l16;
      if (gc < Nn) {
#pragma unroll
        for (int r = 0; r < 4; r++) {
          size_t idx = (size_t)(gr0 + r) * Nn + gc;
          float val = acc[i][j][r];
          if (EPI == 0) C[idx] = val;
          else if (EPI == 1) C[idx] = val / (1.f + expf(-val));
          else if (EPI == 2) C[idx] += val;
          else C[idx] *= val;
        }
      }
    }
  }
}

// ======================================================================
// qkv post: split heads, qk rmsnorm, rope -> q/k/v in (bh, s, dh) BF16
// ======================================================================
__global__ __launch_bounds__(256) void k_qkvpost(const float* __restrict__ qkv,
                                                 const float* __restrict__ qnw,
                                                 const float* __restrict__ knw,
                                                 const float* __restrict__ cosT,
                                                 const float* __restrict__ sinT,
                                                 us* __restrict__ q,
                                                 us* __restrict__ k,
                                                 us* __restrict__ v) {
  int m = blockIdx.x;
  int b = m / S, s = m % S;
  int t = threadIdx.x;
  __shared__ float buf[D];
  __shared__ float cs[32], sn[32];
  if (t < 32) { cs[t] = cosT[s*32 + t]; sn[t] = sinT[s*32 + t]; }
  const float* row = qkv + (size_t)m * 3 * D;
  int lane16 = t & 15;
  int e = 4 * t, eh = e >> 6, rdh = e & 63;

  for (int part = 0; part < 2; part++) {
    fv4 val = *(const fv4*)(row + part * D + 4*t);
    float ss = val[0]*val[0] + val[1]*val[1] + val[2]*val[2] + val[3]*val[3];
    ss += __shfl_xor(ss, 8); ss += __shfl_xor(ss, 4);
    ss += __shfl_xor(ss, 2); ss += __shfl_xor(ss, 1);
    float r = rsqrtf(ss * (1.0f / (float)DH) + 1e-6f);
    fv4 w4 = *(const fv4*)((part == 0 ? qnw : knw) + 4*lane16);
    *(fv4*)&buf[4*t] = val * r * w4;
    __syncthreads();
    fv4 out;
#pragma unroll
    for (int j = 0; j < 4; j++) {
      int rr = rdh + j;
      if (rr < 32) {
        float x1 = buf[eh*64 + rr], x2 = buf[eh*64 + rr + 32];
        out[j] = x1 * cs[rr] - x2 * sn[rr];
      } else {
        int f = rr - 32;
        float x1 = buf[eh*64 + f], x2 = buf[eh*64 + rr];
        out[j] = x2 * cs[f] + x1 * sn[f];
      }
    }
    us* dst = (part == 0 ? q : k);
    us4 o; o[0]=f2bf(out[0]); o[1]=f2bf(out[1]); o[2]=f2bf(out[2]); o[3]=f2bf(out[3]);
    *(us4*)&dst[(((size_t)(b*H + eh)) * S + s) * DH + rdh] = o;
    __syncthreads();
  }
  fv4 vv = *(const fv4*)(row + 2 * D + 4*t);
  us4 o; o[0]=f2bf(vv[0]); o[1]=f2bf(vv[1]); o[2]=f2bf(vv[2]); o[3]=f2bf(vv[3]);
  *(us4*)&v[(((size_t)(b*H + eh)) * S + s) * DH + rdh] = o;
}

// ======================================================================
// 64x64 bf16 transpose: (bh, s, dh) -> (bh, dh, s)
// ======================================================================
__global__ __launch_bounds__(256) void k_tr(const us* __restrict__ src,
                                            us* __restrict__ dst) {
  __shared__ __attribute__((aligned(16))) us tile[64*72];
  int st = blockIdx.x, bh = blockIdx.y, t = threadIdx.x;
  const us* sp = src + ((size_t)bh * S + st*64) * 64;
#pragma unroll
  for (int p = 0; p < 2; p++) {
    int idx = t + p*256;
    int r = idx >> 3, c = (idx & 7)*8;
    *(bf16x8*)&tile[r*72 + c] = *(const bf16x8*)&sp[(size_t)idx*8];
  }
  __syncthreads();
  int d = t >> 2;
#pragma unroll
  for (int cc = 0; cc < 16; cc += 8) {
    int s0 = (t & 3)*16 + cc;
    bf16x8 vv;
#pragma unroll
    for (int j2 = 0; j2 < 8; j2++) vv[j2] = (short)tile[(s0+j2)*72 + d];
    *(bf16x8*)&dst[((size_t)bh*64 + d)*S + st*64 + s0] = vv;
  }
}

// ======================================================================
// gamma gate
// ======================================================================
__global__ __launch_bounds__(256) void k_gamma(const float* __restrict__ h,
                                               const float* __restrict__ w1,
                                               const float* __restrict__ w2,
                                               float* __restrict__ gk) {
  int m = blockIdx.x, t = threadIdx.x;
  __shared__ float hrow[D];
  *(fv4*)&hrow[4*t] = *(const fv4*)(h + (size_t)m * D + 4*t);
  __syncthreads();
  int o = t & 63, seg = t >> 6;
  const float* wr = w1 + (size_t)o * D + seg * 256;
  const float* hr = hrow + seg * 256;
  float acc = 0.f;
  for (int j = 0; j < 256; j += 4) {
    fv4 wv = *(const fv4*)(wr + j);
    acc += wv[0]*hr[j] + wv[1]*hr[j+1] + wv[2]*hr[j+2] + wv[3]*hr[j+3];
  }
  __shared__ float part[4][64];
  part[seg][o] = acc;
  __syncthreads();
  if (t < 64) {
    float dot = part[0][t] + part[1][t] + part[2][t] + part[3][t];
    float sv = dot / (1.f + expf(-dot));
    float val = sv * w2[t];
#pragma unroll
    for (int off = 32; off > 0; off >>= 1) val += __shfl_down(val, off);
    if (t == 0) gk[m] = 1.f / (1.f + expf(-val));
  }
}

// ======================================================================
// cumsum
// ======================================================================
__global__ __launch_bounds__(1024) void k_cumsum(const float* __restrict__ gk,
                                                 float* __restrict__ nrm) {
  int b = blockIdx.x, t = threadIdx.x;
  __shared__ float buf[S];
  buf[t] = gk[b*S + t];
  __syncthreads();
  for (int off = 1; off < S; off <<= 1) {
    float add = (t >= off) ? buf[t - off] : 0.f;
    __syncthreads();
    buf[t] += add;
    __syncthreads();
  }
  nrm[b*S + t] = (float)NP + buf[t];
}

// ======================================================================
// FUSED omega-memory + flash attention, MFMA bf16.
// grid (16, B*H); block 256 = 4 waves, wave w owns output rows [16w,16w+16).
// qt load-balance map: [0,15,1,14,...] so adjacent blocks sum to const work.
// ======================================================================
__global__ __launch_bounds__(256) void k_matt(const us* __restrict__ qb,
                                              const us* __restrict__ kb,
                                              const us* __restrict__ kbT,
                                              const us* __restrict__ vbT,
                                              const float* __restrict__ MpB,
                                              const float* __restrict__ gk,
                                              const float* __restrict__ nrm,
                                              const float* __restrict__ mg, int layer,
                                              float* __restrict__ ob) {
  int xx = blockIdx.x;
  int qt = (xx & 1) ? 15 - (xx >> 1) : (xx >> 1);
  int bh = blockIdx.y, b = bh >> 4, hh = bh & 15;
  int t = threadIdx.x, lane = t & 63, w = t >> 6;
  int l16 = lane & 15, lg = lane >> 4;

  __shared__ __attribute__((aligned(16))) us Qs[64*72];
  __shared__ __attribute__((aligned(16))) us Ks[64*72];
  __shared__ __attribute__((aligned(16))) us Ts[64*72];
  __shared__ __attribute__((aligned(16))) us Ps[64*72];
  __shared__ float gks_[64], nrms[64];

  float gate = 1.f / (1.f + expf(-mg[layer]));

  // ---- stage Q tile + Mp (f32->bf16) ----
  {
    const us* src = qb + ((size_t)bh * S + qt*64) * 64;
#pragma unroll
    for (int p = 0; p < 2; p++) {
      int idx = t + p*256;
      int r = idx >> 3, c = (idx & 7) * 8;
      *(bf16x8*)&Qs[r*72 + c] = *(const bf16x8*)&src[(size_t)idx*8];
    }
    const float* mp = MpB + (size_t)hh * 4096;
#pragma unroll
    for (int p = 0; p < 4; p++) {
      int e = (t + p*256) * 4;
      int r = e >> 6, c = e & 63;
      fv4 v = *(const fv4*)&mp[e];
      us4 o; o[0]=f2bf(v[0]); o[1]=f2bf(v[1]); o[2]=f2bf(v[2]); o[3]=f2bf(v[3]);
      *(us4*)&Ts[r*72 + c] = o;
    }
    if (t < 64) nrms[t] = nrm[b*S + qt*64 + t];
  }
  __syncthreads();

  bf16x8 aq0 = *(const bf16x8*)&Qs[(16*w + l16)*72 + lg*8];
  bf16x8 aq1 = *(const bf16x8*)&Qs[(16*w + l16)*72 + 32 + lg*8];

  // ---- acc_mem init = Mp q (Mp symmetric -> row-major B works) ----
  fv4 am[4];
#pragma unroll
  for (int j = 0; j < 4; j++) {
    bf16x8 b0 = *(const bf16x8*)&Ts[(16*j + l16)*72 + lg*8];
    bf16x8 b1 = *(const bf16x8*)&Ts[(16*j + l16)*72 + 32 + lg*8];
    fv4 z = {};
    z = MFMA16(aq0, b0, z, 0, 0, 0);
    z = MFMA16(aq1, b1, z, 0, 0, 0);
    am[j] = z;
  }

  // ================= phase 1: omega memory =================
  for (int kt = 0; kt <= qt; kt++) {
    __syncthreads();
    {
      const us* ksrc = kb + ((size_t)bh * S + kt*64) * 64;
#pragma unroll
      for (int p = 0; p < 2; p++) {
        int idx = t + p*256;
        int r = idx >> 3, c = (idx & 7) * 8;
        *(bf16x8*)&Ks[r*72 + c] = *(const bf16x8*)&ksrc[(size_t)idx*8];
      }
      int d = t >> 2, c0 = (t & 3) * 16;
      const us* tsrc = kbT + ((size_t)bh*64 + d) * S + kt*64 + c0;
      *(bf16x8*)&Ts[d*72 + c0]     = *(const bf16x8*)&tsrc[0];
      *(bf16x8*)&Ts[d*72 + c0 + 8] = *(const bf16x8*)&tsrc[8];
      if (t < 64) gks_[t] = gk[b*S + kt*64 + t];
    }
    __syncthreads();
    fv4 sc[4];
#pragma unroll
    for (int j = 0; j < 4; j++) {
      bf16x8 b0 = *(const bf16x8*)&Ks[(16*j + l16)*72 + lg*8];
      bf16x8 b1 = *(const bf16x8*)&Ks[(16*j + l16)*72 + 32 + lg*8];
      fv4 z = {};
      z = MFMA16(aq0, b0, z, 0, 0, 0);
      z = MFMA16(aq1, b1, z, 0, 0, 0);
      sc[j] = z;
    }
#pragma unroll
    for (int j = 0; j < 4; j++) {
      int kj = 16*j + l16;
      float g = gks_[kj];
#pragma unroll
      for (int r = 0; r < 4; r++) {
        int qi = 16*w + lg*4 + r;
        float val = sc[j][r] * g;
        if (kt == qt && kj > qi) val = 0.f;
        Ps[qi*72 + kj] = f2bf(val);
      }
    }
    __syncthreads();
    bf16x8 ap0 = *(const bf16x8*)&Ps[(16*w + l16)*72 + lg*8];
    bf16x8 ap1 = *(const bf16x8*)&Ps[(16*w + l16)*72 + 32 + lg*8];
#pragma unroll
    for (int j = 0; j < 4; j++) {
      bf16x8 b0 = *(const bf16x8*)&Ts[(16*j + l16)*72 + lg*8];
      bf16x8 b1 = *(const bf16x8*)&Ts[(16*j + l16)*72 + 32 + lg*8];
      am[j] = MFMA16(ap0, b0, am[j], 0, 0, 0);
      am[j] = MFMA16(ap1, b1, am[j], 0, 0, 0);
    }
  }

  // ---- q' = (1-gate) q + gate * acc/norm, written back to Qs (bf16) ----
  __syncthreads();
#pragma unroll
  for (int j = 0; j < 4; j++)
#pragma unroll
    for (int r = 0; r < 4; r++) {
      int qi = 16*w + lg*4 + r, dj = 16*j + l16;
      float qold = bf2f(Qs[qi*72 + dj]);
      float qn = (1.f - gate) * qold + gate * (am[j][r] / nrms[qi]);
      Qs[qi*72 + dj] = f2bf(qn);
    }
  __syncthreads();
  aq0 = *(const bf16x8*)&Qs[(16*w + l16)*72 + lg*8];
  aq1 = *(const bf16x8*)&Qs[(16*w + l16)*72 + 32 + lg*8];

  // ================= phase 2: flash attention =================
  float mrow_[4] = {-1e30f, -1e30f, -1e30f, -1e30f};
  float lrow_[4] = {};
  fv4 ao[4] = {};
  for (int kt = 0; kt <= qt; kt++) {
    __syncthreads();
    {
      const us* ksrc = kb + ((size_t)bh * S + kt*64) * 64;
#pragma unroll
      for (int p = 0; p < 2; p++) {
        int idx = t + p*256;
        int r = idx >> 3, c = (idx & 7) * 8;
        *(bf16x8*)&Ks[r*72 + c] = *(const bf16x8*)&ksrc[(size_t)idx*8];
      }
      int d = t >> 2, c0 = (t & 3) * 16;
      const us* tsrc = vbT + ((size_t)bh*64 + d) * S + kt*64 + c0;
      *(bf16x8*)&Ts[d*72 + c0]     = *(const bf16x8*)&tsrc[0];
      *(bf16x8*)&Ts[d*72 + c0 + 8] = *(const bf16x8*)&tsrc[8];
    }
    __syncthreads();
    fv4 sc[4];
#pragma unroll
    for (int j = 0; j < 4; j++) {
      bf16x8 b0 = *(const bf16x8*)&Ks[(16*j + l16)*72 + lg*8];
      bf16x8 b1 = *(const bf16x8*)&Ks[(16*j + l16)*72 + 32 + lg*8];
      fv4 z = {};
      z = MFMA16(aq0, b0, z, 0, 0, 0);
      z = MFMA16(aq1, b1, z, 0, 0, 0);
      sc[j] = z;
    }
#pragma unroll
    for (int r = 0; r < 4; r++) {
      int qi = 16*w + lg*4 + r;
      float pv[4];
      float tm = -1e30f;
#pragma unroll
      for (int j = 0; j < 4; j++) {
        int kj = 16*j + l16;
        float val = sc[j][r] * 0.125f;
        if (kt == qt && kj > qi) val = -1e30f;
        pv[j] = val;
        tm = fmaxf(tm, val);
      }
      tm = fmaxf(tm, __shfl_xor(tm, 1));
      tm = fmaxf(tm, __shfl_xor(tm, 2));
      tm = fmaxf(tm, __shfl_xor(tm, 4));
      tm = fmaxf(tm, __shfl_xor(tm, 8));
      float mnew = fmaxf(mrow_[r], tm);
      float alpha = __expf(mrow_[r] - mnew);
      mrow_[r] = mnew;
      float ps = 0.f;
#pragma unroll
      for (int j = 0; j < 4; j++) {
        float p = __expf(pv[j] - mnew);
        ps += p;
        Ps[qi*72 + 16*j + l16] = f2bf(p);
      }
      ps += __shfl_xor(ps, 1);
      ps += __shfl_xor(ps, 2);
      ps += __shfl_xor(ps, 4);
      ps += __shfl_xor(ps, 8);
      lrow_[r] = lrow_[r] * alpha + ps;
#pragma unroll
      for (int j = 0; j < 4; j++) ao[j][r] *= alpha;
    }
    __syncthreads();
    bf16x8 ap0 = *(const bf16x8*)&Ps[(16*w + l16)*72 + lg*8];
    bf16x8 ap1 = *(const bf16x8*)&Ps[(16*w + l16)*72 + 32 + lg*8];
#pragma unroll
    for (int j = 0; j < 4; j++) {
      bf16x8 b0 = *(const bf16x8*)&Ts[(16*j + l16)*72 + lg*8];
      bf16x8 b1 = *(const bf16x8*)&Ts[(16*j + l16)*72 + 32 + lg*8];
      ao[j] = MFMA16(ap0, b0, ao[j], 0, 0, 0);
      ao[j] = MFMA16(ap1, b1, ao[j], 0, 0, 0);
    }
  }

  // ---- epilogue: o / l -> ob (M, D) f32 ----
#pragma unroll
  for (int j = 0; j < 4; j++)
#pragma unroll
    for (int r = 0; r < 4; r++) {
      int qi = 16*w + lg*4 + r;
      ob[((size_t)b*S + qt*64 + qi) * D + hh*64 + 16*j + l16] = ao[j][r] / lrow_[r];
    }
}

// ======================================================================
// launcher
// ======================================================================
extern "C" void kernel_launch(void* const* d_in, const int* in_sizes, int n_in,
                              void* d_out, int out_size, void* d_ws, size_t ws_size,
                              hipStream_t stream) {
  const int*   ids      = (const int*)d_in[0];
  const float* tok_emb  = (const float*)d_in[1];
  const float* w_init   = (const float*)d_in[2];
  const float* persist  = (const float*)d_in[3];
  const float* norm1_w  = (const float*)d_in[4];
  const float* norm2_w  = (const float*)d_in[5];
  const float* norm_f_w = (const float*)d_in[6];
  const float* qkv_w    = (const float*)d_in[7];
  const float* q_norm_w = (const float*)d_in[8];
  const float* k_norm_w = (const float*)d_in[9];
  const float* gamma_w1 = (const float*)d_in[10];
  const float* gamma_w2 = (const float*)d_in[11];
  const float* mem_gate = (const float*)d_in[12];
  const float* w_o      = (const float*)d_in[13];
  const float* ffn_w1   = (const float*)d_in[14];
  const float* ffn_w2   = (const float*)d_in[15];
  const float* ffn_w3   = (const float*)d_in[16];
  float* out = (float*)d_out;

  // ---- workspace layout ----
  float* ws   = (float*)d_ws;
  float* x    = ws;                       // M*D
  float* h    = x    + (size_t)M * D;     // M*D
  float* qkv  = h    + (size_t)M * D;     // M*3D (ffn1 alias)
  float* ob   = qkv  + (size_t)M * 3 * D; // M*D
  float* gk   = ob   + (size_t)M * D;     // M
  float* nrm  = gk   + M;                 // M
  float* cosT = nrm  + M;                 // S*32
  float* sinT = cosT + S * 32;            // S*32
  float* MpB  = sinT + S * 32;            // H*DH*DH
  us*    qb   = (us*)(MpB + H*DH*DH);     // M*D bf16
  us*    kb   = qb  + (size_t)M * D;
  us*    vb   = kb  + (size_t)M * D;
  us*    kbT  = vb  + (size_t)M * D;
  us*    vbT  = kbT + (size_t)M * D;
  float* ffn1 = qkv;

  k_embed<<<M, 256, 0, stream>>>(ids, tok_emb, w_init, x);
  k_rope_tables<<<(S*32 + 255)/256, 256, 0, stream>>>(cosT, sinT);
  k_mp<<<H, 256, 0, stream>>>(persist, MpB);

  for (int l = 0; l < NL; l++) {
    k_rms<<<M, 256, 0, stream>>>(x, norm1_w + (size_t)l * D, h);
    k_mgemm<0,4><<<dim3(M/128, 3*D/128), 256, 0, stream>>>(h, qkv_w + (size_t)l*3*D*D, qkv, M, 3*D, D);
    k_qkvpost<<<M, 256, 0, stream>>>(qkv, q_norm_w + (size_t)l*DH, k_norm_w + (size_t)l*DH,
                                     cosT, sinT, qb, kb, vb);
    k_tr<<<dim3(S/64, B*H), 256, 0, stream>>>(kb, kbT);
    k_tr<<<dim3(S/64, B*H), 256, 0, stream>>>(vb, vbT);
    k_gamma<<<M, 256, 0, stream>>>(h, gamma_w1 + (size_t)l*GH*D, gamma_w2 + (size_t)l*GH, gk);
    k_cumsum<<<B, S, 0, stream>>>(gk, nrm);
    k_matt<<<dim3(S/64, B*H), 256, 0, stream>>>(qb, kb, kbT, vbT, MpB, gk, nrm, mem_gate, l, ob);
    k_mgemm<2,2><<<dim3(M/64, D/128), 256, 0, stream>>>(ob, w_o + (size_t)l*D*D, x, M, D, D);
    k_rms<<<M, 256, 0, stream>>>(x, norm2_w + (size_t)l * D, h);
    k_mgemm<1,4><<<dim3(M/128, (FF+127)/128), 256, 0, stream>>>(h, ffn_w1 + (size_t)l*FF*D, ffn1, M, FF, D);
    k_mgemm<3,4><<<dim3(M/128, (FF+127)/128), 256, 0, stream>>>(h, ffn_w2 + (size_t)l*FF*D, ffn1, M, FF, D);
    k_mgemm<2,2><<<dim3(M/64, D/128), 256, 0, stream>>>(ffn1, ffn_w3 + (size_t)l*D*FF, x, M, D, FF);
  }

  k_rms<<<M, 256, 0, stream>>>(x, norm_f_w, h);
  k_mgemm<0,4><<<dim3(M/128, V/128), 256, 0, stream>>>(h, tok_emb, out, M, V, D);
}

// Round 4
// 2341.154 us; speedup vs baseline: 11.0969x; 2.2051x over previous
//
#include <hip/hip_runtime.h>
#include <hip/hip_bf16.h>
#include <math.h>

// ---------------- problem constants ----------------
#define B 2
#define S 1024
#define D 1024
#define H 16
#define DH 64
#define NL 6
#define GH 64
#define NP 16
#define V 32000
#define FF 2730
#define FFP 2752   // FF padded to multiple of 64
#define M (B*S)    // 2048 rows

typedef float fv4 __attribute__((ext_vector_type(4)));
typedef short bf16x8 __attribute__((ext_vector_type(8)));       // 8 bf16 = 4 VGPRs
typedef unsigned short us4 __attribute__((ext_vector_type(4))); // 4 bf16 = 8 bytes
typedef unsigned short us;

#define MFMA16 __builtin_amdgcn_mfma_f32_16x16x32_bf16
#define G2L16(g, l) __builtin_amdgcn_global_load_lds( \
    (const __attribute__((address_space(1))) void*)(g), \
    (__attribute__((address_space(3))) void*)(l), 16, 0, 0)

__device__ __forceinline__ us f2bf(float f) {
  union { float f; unsigned u; } v; v.f = f;
  unsigned r = v.u + 0x7FFFu + ((v.u >> 16) & 1u);   // RNE
  return (us)(r >> 16);
}
__device__ __forceinline__ float bf2f(us h) {
  union { unsigned u; float f; } v; v.u = ((unsigned)h) << 16;
  return v.f;
}

// ======================================================================
// embed
// ======================================================================
__global__ __launch_bounds__(256) void k_embed(const int* __restrict__ ids,
                                               const float* __restrict__ emb,
                                               const float* __restrict__ winit,
                                               float* __restrict__ x) {
  int m = blockIdx.x, t = threadIdx.x;
  int id = ids[m];
  fv4 a = *(const fv4*)(emb + (size_t)id * D + 4*t);
  fv4 w = *(const fv4*)(winit + 4*t);
  *(fv4*)(x + (size_t)m * D + 4*t) = a + w;
}

// ======================================================================
// rope tables
// ======================================================================
__global__ void k_rope_tables(float* __restrict__ cosT, float* __restrict__ sinT) {
  int idx = blockIdx.x * blockDim.x + threadIdx.x;
  if (idx >= S * 32) return;
  int s = idx >> 5, f = idx & 31;
  float inv = powf(10000.0f, -2.0f * (float)f / (float)DH);
  float ang = (float)s * inv;
  cosT[idx] = cosf(ang);
  sinT[idx] = sinf(ang);
}

// ======================================================================
// Mp[h][d][e] = sum_n p[n][h][d] * p[n][h][e]   (symmetric)
// ======================================================================
__global__ __launch_bounds__(256) void k_mp(const float* __restrict__ pers,
                                            float* __restrict__ Mp) {
  int h = blockIdx.x, t = threadIdx.x;
  __shared__ float p[NP][DH];
  for (int i = t; i < NP * DH; i += 256) {
    int n = i / DH, dh = i % DH;
    p[n][dh] = pers[(size_t)n * D + h * DH + dh];
  }
  __syncthreads();
  for (int i = t; i < DH * DH; i += 256) {
    int d = i / DH, e = i % DH;
    float s = 0.f;
#pragma unroll
    for (int n = 0; n < NP; n++) s += p[n][d] * p[n][e];
    Mp[(size_t)h * DH * DH + i] = s;
  }
}

// ======================================================================
// rmsnorm rows of D, dual store f32 + bf16
// ======================================================================
__global__ __launch_bounds__(256) void k_rms(const float* __restrict__ in,
                                             const float* __restrict__ w,
                                             float* __restrict__ out,
                                             us* __restrict__ outb) {
  int m = blockIdx.x, t = threadIdx.x;
  fv4 v = *(const fv4*)(in + (size_t)m * D + 4*t);
  float ss = v[0]*v[0] + v[1]*v[1] + v[2]*v[2] + v[3]*v[3];
#pragma unroll
  for (int off = 32; off > 0; off >>= 1) ss += __shfl_down(ss, off);
  __shared__ float buf[4];
  if ((t & 63) == 0) buf[t >> 6] = ss;
  __syncthreads();
  float tot = buf[0] + buf[1] + buf[2] + buf[3];
  float r = rsqrtf(tot * (1.0f / (float)D) + 1e-6f);
  fv4 wv = *(const fv4*)(w + 4*t);
  fv4 res = v * r * wv;
  *(fv4*)(out + (size_t)m * D + 4*t) = res;
  us4 o; o[0]=f2bf(res[0]); o[1]=f2bf(res[1]); o[2]=f2bf(res[2]); o[3]=f2bf(res[3]);
  *(us4*)(outb + (size_t)m * D + 4*t) = o;
}

// ======================================================================
// flat f32 -> bf16 convert (n % 4 == 0)
// ======================================================================
__global__ __launch_bounds__(256) void k_cvt(const float* __restrict__ src,
                                             us* __restrict__ dst, int n) {
  for (size_t i = ((size_t)blockIdx.x * 256 + threadIdx.x) * 4; i < (size_t)n;
       i += (size_t)gridDim.x * 1024) {
    fv4 v = *(const fv4*)(src + i);
    us4 o; o[0]=f2bf(v[0]); o[1]=f2bf(v[1]); o[2]=f2bf(v[2]); o[3]=f2bf(v[3]);
    *(us4*)(dst + i) = o;
  }
}

// ======================================================================
// row-wise f32 (rows x K) -> bf16 (rows x Kp), zero pad. grid = rows.
// scalar reads (K=2730 rows are not 16B aligned).
// ======================================================================
__global__ __launch_bounds__(256) void k_cvt_pad(const float* __restrict__ src,
                                                 us* __restrict__ dst,
                                                 int K, int Kp) {
  int r = blockIdx.x, t = threadIdx.x;
  for (int c = t * 4; c < Kp; c += 1024) {
    us4 o;
#pragma unroll
    for (int q = 0; q < 4; q++) {
      int cc = c + q;
      o[q] = (cc < K) ? f2bf(src[(size_t)r * K + cc]) : (us)0;
    }
    *(us4*)&dst[(size_t)r * Kp + c] = o;
  }
}

// ======================================================================
// bf16 MFMA GEMM, m97 structure: global_load_lds width 16, BK=64,
// 2-barrier loop. A: Mx Kk bf16, W: Nn x Kk bf16 (B^T). C f32.
// grid (M/BM, ceil(Nn/BN)), 256 threads = 4 waves in 2x2.
// EPI: 0 store, 1 silu-store, 2 add-to-C, 3 mul-into-C
// ======================================================================
template<int EPI, int BM, int BN>
__global__ __launch_bounds__(256) void k_bgemm(const us* __restrict__ A,
                                               const us* __restrict__ W,
                                               float* __restrict__ C,
                                               int Nn, int Kk) {
  constexpr int FM = BM / 32;   // m-frags per wave
  constexpr int FN = BN / 32;   // n-frags per wave
  constexpr int ACW = BM / 32;  // A staging chunks (1KB) per wave
  constexpr int BCW = BN / 32;
  __shared__ __attribute__((aligned(16))) us As[BM * 64];
  __shared__ __attribute__((aligned(16))) us Bs[BN * 64];
  int t = threadIdx.x, lane = t & 63, w = t >> 6;
  int l16 = lane & 15, lkb = lane >> 4;
  int lr = lane >> 3, lc = (lane & 7) * 8;
  int m0 = blockIdx.x * BM, n0 = blockIdx.y * BN;
  int wr = w >> 1, wc = w & 1;

  const us* aB[ACW]; us* aL[ACW];
  const us* bB[BCW]; us* bL[BCW];
#pragma unroll
  for (int i = 0; i < ACW; i++) {
    int chunk = w * ACW + i;
    aB[i] = A + (size_t)(m0 + chunk * 8 + lr) * Kk + lc;
    aL[i] = &As[chunk * 512];
  }
#pragma unroll
  for (int i = 0; i < BCW; i++) {
    int chunk = w * BCW + i;
    int wrow = n0 + chunk * 8 + lr;
    if (wrow >= Nn) wrow = Nn - 1;   // clamp: garbage cols never stored
    bB[i] = W + (size_t)wrow * Kk + lc;
    bL[i] = &Bs[chunk * 512];
  }

  fv4 acc[FM][FN] = {};
  for (int k0 = 0; k0 < Kk; k0 += 64) {
#pragma unroll
    for (int i = 0; i < ACW; i++) G2L16(aB[i] + k0, aL[i]);
#pragma unroll
    for (int i = 0; i < BCW; i++) G2L16(bB[i] + k0, bL[i]);
    __syncthreads();
#pragma unroll
    for (int kk = 0; kk < 2; kk++) {
      bf16x8 af[FM], bfh[FN];
#pragma unroll
      for (int i = 0; i < FM; i++)
        af[i] = *(const bf16x8*)&As[(wr*(BM/2) + i*16 + l16)*64 + kk*32 + lkb*8];
#pragma unroll
      for (int j = 0; j < FN; j++)
        bfh[j] = *(const bf16x8*)&Bs[(wc*(BN/2) + j*16 + l16)*64 + kk*32 + lkb*8];
#pragma unroll
      for (int i = 0; i < FM; i++)
#pragma unroll
        for (int j = 0; j < FN; j++)
          acc[i][j] = MFMA16(af[i], bfh[j], acc[i][j], 0, 0, 0);
    }
    __syncthreads();
  }

#pragma unroll
  for (int i = 0; i < FM; i++) {
    int gr0 = m0 + wr*(BM/2) + i*16 + lkb*4;
#pragma unroll
    for (int j = 0; j < FN; j++) {
      int gc = n0 + wc*(BN/2) + j*16 + l16;
      if (gc < Nn) {
#pragma unroll
        for (int r = 0; r < 4; r++) {
          size_t idx = (size_t)(gr0 + r) * Nn + gc;
          float val = acc[i][j][r];
          if (EPI == 0) C[idx] = val;
          else if (EPI == 1) C[idx] = val / (1.f + expf(-val));
          else if (EPI == 2) C[idx] += val;
          else C[idx] *= val;
        }
      }
    }
  }
}

// ======================================================================
// qkv post: split heads, qk rmsnorm, rope -> q/k/v in (bh, s, dh) BF16
// ======================================================================
__global__ __launch_bounds__(256) void k_qkvpost(const float* __restrict__ qkv,
                                                 const float* __restrict__ qnw,
                                                 const float* __restrict__ knw,
                                                 const float* __restrict__ cosT,
                                                 const float* __restrict__ sinT,
                                                 us* __restrict__ q,
                                                 us* __restrict__ k,
                                                 us* __restrict__ v) {
  int m = blockIdx.x;
  int b = m / S, s = m % S;
  int t = threadIdx.x;
  __shared__ float buf[D];
  __shared__ float cs[32], sn[32];
  if (t < 32) { cs[t] = cosT[s*32 + t]; sn[t] = sinT[s*32 + t]; }
  const float* row = qkv + (size_t)m * 3 * D;
  int lane16 = t & 15;
  int e = 4 * t, eh = e >> 6, rdh = e & 63;

  for (int part = 0; part < 2; part++) {
    fv4 val = *(const fv4*)(row + part * D + 4*t);
    float ss = val[0]*val[0] + val[1]*val[1] + val[2]*val[2] + val[3]*val[3];
    ss += __shfl_xor(ss, 8); ss += __shfl_xor(ss, 4);
    ss += __shfl_xor(ss, 2); ss += __shfl_xor(ss, 1);
    float r = rsqrtf(ss * (1.0f / (float)DH) + 1e-6f);
    fv4 w4 = *(const fv4*)((part == 0 ? qnw : knw) + 4*lane16);
    *(fv4*)&buf[4*t] = val * r * w4;
    __syncthreads();
    fv4 out;
#pragma unroll
    for (int j = 0; j < 4; j++) {
      int rr = rdh + j;
      if (rr < 32) {
        float x1 = buf[eh*64 + rr], x2 = buf[eh*64 + rr + 32];
        out[j] = x1 * cs[rr] - x2 * sn[rr];
      } else {
        int f = rr - 32;
        float x1 = buf[eh*64 + f], x2 = buf[eh*64 + rr];
        out[j] = x2 * cs[f] + x1 * sn[f];
      }
    }
    us* dst = (part == 0 ? q : k);
    us4 o; o[0]=f2bf(out[0]); o[1]=f2bf(out[1]); o[2]=f2bf(out[2]); o[3]=f2bf(out[3]);
    *(us4*)&dst[(((size_t)(b*H + eh)) * S + s) * DH + rdh] = o;
    __syncthreads();
  }
  fv4 vv = *(const fv4*)(row + 2 * D + 4*t);
  us4 o; o[0]=f2bf(vv[0]); o[1]=f2bf(vv[1]); o[2]=f2bf(vv[2]); o[3]=f2bf(vv[3]);
  *(us4*)&v[(((size_t)(b*H + eh)) * S + s) * DH + rdh] = o;
}

// ======================================================================
// 64x64 bf16 transpose: (bh, s, dh) -> (bh, dh, s)
// ======================================================================
__global__ __launch_bounds__(256) void k_tr(const us* __restrict__ src,
                                            us* __restrict__ dst) {
  __shared__ __attribute__((aligned(16))) us tile[64*72];
  int st = blockIdx.x, bh = blockIdx.y, t = threadIdx.x;
  const us* sp = src + ((size_t)bh * S + st*64) * 64;
#pragma unroll
  for (int p = 0; p < 2; p++) {
    int idx = t + p*256;
    int r = idx >> 3, c = (idx & 7)*8;
    *(bf16x8*)&tile[r*72 + c] = *(const bf16x8*)&sp[(size_t)idx*8];
  }
  __syncthreads();
  int d = t >> 2;
#pragma unroll
  for (int cc = 0; cc < 16; cc += 8) {
    int s0 = (t & 3)*16 + cc;
    bf16x8 vv;
#pragma unroll
    for (int j2 = 0; j2 < 8; j2++) vv[j2] = (short)tile[(s0+j2)*72 + d];
    *(bf16x8*)&dst[((size_t)bh*64 + d)*S + st*64 + s0] = vv;
  }
}

// ======================================================================
// gamma gate
// ======================================================================
__global__ __launch_bounds__(256) void k_gamma(const float* __restrict__ h,
                                               const float* __restrict__ w1,
                                               const float* __restrict__ w2,
                                               float* __restrict__ gk) {
  int m = blockIdx.x, t = threadIdx.x;
  __shared__ float hrow[D];
  *(fv4*)&hrow[4*t] = *(const fv4*)(h + (size_t)m * D + 4*t);
  __syncthreads();
  int o = t & 63, seg = t >> 6;
  const float* wr = w1 + (size_t)o * D + seg * 256;
  const float* hr = hrow + seg * 256;
  float acc = 0.f;
  for (int j = 0; j < 256; j += 4) {
    fv4 wv = *(const fv4*)(wr + j);
    acc += wv[0]*hr[j] + wv[1]*hr[j+1] + wv[2]*hr[j+2] + wv[3]*hr[j+3];
  }
  __shared__ float part[4][64];
  part[seg][o] = acc;
  __syncthreads();
  if (t < 64) {
    float dot = part[0][t] + part[1][t] + part[2][t] + part[3][t];
    float sv = dot / (1.f + expf(-dot));
    float val = sv * w2[t];
#pragma unroll
    for (int off = 32; off > 0; off >>= 1) val += __shfl_down(val, off);
    if (t == 0) gk[m] = 1.f / (1.f + expf(-val));
  }
}

// ======================================================================
// cumsum
// ======================================================================
__global__ __launch_bounds__(1024) void k_cumsum(const float* __restrict__ gk,
                                                 float* __restrict__ nrm) {
  int b = blockIdx.x, t = threadIdx.x;
  __shared__ float buf[S];
  buf[t] = gk[b*S + t];
  __syncthreads();
  for (int off = 1; off < S; off <<= 1) {
    float add = (t >= off) ? buf[t - off] : 0.f;
    __syncthreads();
    buf[t] += add;
    __syncthreads();
  }
  nrm[b*S + t] = (float)NP + buf[t];
}

// ======================================================================
// FUSED omega-memory + flash attention, MFMA bf16. Output bf16.
// ======================================================================
__global__ __launch_bounds__(256) void k_matt(const us* __restrict__ qb,
                                              const us* __restrict__ kb,
                                              const us* __restrict__ kbT,
                                              const us* __restrict__ vbT,
                                              const float* __restrict__ MpB,
                                              const float* __restrict__ gk,
                                              const float* __restrict__ nrm,
                                              const float* __restrict__ mg, int layer,
                                              us* __restrict__ ob) {
  int xx = blockIdx.x;
  int qt = (xx & 1) ? 15 - (xx >> 1) : (xx >> 1);
  int bh = blockIdx.y, b = bh >> 4, hh = bh & 15;
  int t = threadIdx.x, lane = t & 63, w = t >> 6;
  int l16 = lane & 15, lg = lane >> 4;

  __shared__ __attribute__((aligned(16))) us Qs[64*72];
  __shared__ __attribute__((aligned(16))) us Ks[64*72];
  __shared__ __attribute__((aligned(16))) us Ts[64*72];
  __shared__ __attribute__((aligned(16))) us Ps[64*72];
  __shared__ float gks_[64], nrms[64];

  float gate = 1.f / (1.f + expf(-mg[layer]));

  // ---- stage Q tile + Mp (f32->bf16) ----
  {
    const us* src = qb + ((size_t)bh * S + qt*64) * 64;
#pragma unroll
    for (int p = 0; p < 2; p++) {
      int idx = t + p*256;
      int r = idx >> 3, c = (idx & 7) * 8;
      *(bf16x8*)&Qs[r*72 + c] = *(const bf16x8*)&src[(size_t)idx*8];
    }
    const float* mp = MpB + (size_t)hh * 4096;
#pragma unroll
    for (int p = 0; p < 4; p++) {
      int e = (t + p*256) * 4;
      int r = e >> 6, c = e & 63;
      fv4 v = *(const fv4*)&mp[e];
      us4 o; o[0]=f2bf(v[0]); o[1]=f2bf(v[1]); o[2]=f2bf(v[2]); o[3]=f2bf(v[3]);
      *(us4*)&Ts[r*72 + c] = o;
    }
    if (t < 64) nrms[t] = nrm[b*S + qt*64 + t];
  }
  __syncthreads();

  bf16x8 aq0 = *(const bf16x8*)&Qs[(16*w + l16)*72 + lg*8];
  bf16x8 aq1 = *(const bf16x8*)&Qs[(16*w + l16)*72 + 32 + lg*8];

  // ---- acc_mem init = Mp q (Mp symmetric) ----
  fv4 am[4];
#pragma unroll
  for (int j = 0; j < 4; j++) {
    bf16x8 b0 = *(const bf16x8*)&Ts[(16*j + l16)*72 + lg*8];
    bf16x8 b1 = *(const bf16x8*)&Ts[(16*j + l16)*72 + 32 + lg*8];
    fv4 z = {};
    z = MFMA16(aq0, b0, z, 0, 0, 0);
    z = MFMA16(aq1, b1, z, 0, 0, 0);
    am[j] = z;
  }

  // ================= phase 1: omega memory =================
  for (int kt = 0; kt <= qt; kt++) {
    __syncthreads();
    {
      const us* ksrc = kb + ((size_t)bh * S + kt*64) * 64;
#pragma unroll
      for (int p = 0; p < 2; p++) {
        int idx = t + p*256;
        int r = idx >> 3, c = (idx & 7) * 8;
        *(bf16x8*)&Ks[r*72 + c] = *(const bf16x8*)&ksrc[(size_t)idx*8];
      }
      int d = t >> 2, c0 = (t & 3) * 16;
      const us* tsrc = kbT + ((size_t)bh*64 + d) * S + kt*64 + c0;
      *(bf16x8*)&Ts[d*72 + c0]     = *(const bf16x8*)&tsrc[0];
      *(bf16x8*)&Ts[d*72 + c0 + 8] = *(const bf16x8*)&tsrc[8];
      if (t < 64) gks_[t] = gk[b*S + kt*64 + t];
    }
    __syncthreads();
    fv4 sc[4];
#pragma unroll
    for (int j = 0; j < 4; j++) {
      bf16x8 b0 = *(const bf16x8*)&Ks[(16*j + l16)*72 + lg*8];
      bf16x8 b1 = *(const bf16x8*)&Ks[(16*j + l16)*72 + 32 + lg*8];
      fv4 z = {};
      z = MFMA16(aq0, b0, z, 0, 0, 0);
      z = MFMA16(aq1, b1, z, 0, 0, 0);
      sc[j] = z;
    }
#pragma unroll
    for (int j = 0; j < 4; j++) {
      int kj = 16*j + l16;
      float g = gks_[kj];
#pragma unroll
      for (int r = 0; r < 4; r++) {
        int qi = 16*w + lg*4 + r;
        float val = sc[j][r] * g;
        if (kt == qt && kj > qi) val = 0.f;
        Ps[qi*72 + kj] = f2bf(val);
      }
    }
    __syncthreads();
    bf16x8 ap0 = *(const bf16x8*)&Ps[(16*w + l16)*72 + lg*8];
    bf16x8 ap1 = *(const bf16x8*)&Ps[(16*w + l16)*72 + 32 + lg*8];
#pragma unroll
    for (int j = 0; j < 4; j++) {
      bf16x8 b0 = *(const bf16x8*)&Ts[(16*j + l16)*72 + lg*8];
      bf16x8 b1 = *(const bf16x8*)&Ts[(16*j + l16)*72 + 32 + lg*8];
      am[j] = MFMA16(ap0, b0, am[j], 0, 0, 0);
      am[j] = MFMA16(ap1, b1, am[j], 0, 0, 0);
    }
  }

  // ---- q' = (1-gate) q + gate * acc/norm ----
  __syncthreads();
#pragma unroll
  for (int j = 0; j < 4; j++)
#pragma unroll
    for (int r = 0; r < 4; r++) {
      int qi = 16*w + lg*4 + r, dj = 16*j + l16;
      float qold = bf2f(Qs[qi*72 + dj]);
      float qn = (1.f - gate) * qold + gate * (am[j][r] / nrms[qi]);
      Qs[qi*72 + dj] = f2bf(qn);
    }
  __syncthreads();
  aq0 = *(const bf16x8*)&Qs[(16*w + l16)*72 + lg*8];
  aq1 = *(const bf16x8*)&Qs[(16*w + l16)*72 + 32 + lg*8];

  // ================= phase 2: flash attention =================
  float mrow_[4] = {-1e30f, -1e30f, -1e30f, -1e30f};
  float lrow_[4] = {};
  fv4 ao[4] = {};
  for (int kt = 0; kt <= qt; kt++) {
    __syncthreads();
    {
      const us* ksrc = kb + ((size_t)bh * S + kt*64) * 64;
#pragma unroll
      for (int p = 0; p < 2; p++) {
        int idx = t + p*256;
        int r = idx >> 3, c = (idx & 7) * 8;
        *(bf16x8*)&Ks[r*72 + c] = *(const bf16x8*)&ksrc[(size_t)idx*8];
      }
      int d = t >> 2, c0 = (t & 3) * 16;
      const us* tsrc = vbT + ((size_t)bh*64 + d) * S + kt*64 + c0;
      *(bf16x8*)&Ts[d*72 + c0]     = *(const bf16x8*)&tsrc[0];
      *(bf16x8*)&Ts[d*72 + c0 + 8] = *(const bf16x8*)&tsrc[8];
    }
    __syncthreads();
    fv4 sc[4];
#pragma unroll
    for (int j = 0; j < 4; j++) {
      bf16x8 b0 = *(const bf16x8*)&Ks[(16*j + l16)*72 + lg*8];
      bf16x8 b1 = *(const bf16x8*)&Ks[(16*j + l16)*72 + 32 + lg*8];
      fv4 z = {};
      z = MFMA16(aq0, b0, z, 0, 0, 0);
      z = MFMA16(aq1, b1, z, 0, 0, 0);
      sc[j] = z;
    }
#pragma unroll
    for (int r = 0; r < 4; r++) {
      int qi = 16*w + lg*4 + r;
      float pv[4];
      float tm = -1e30f;
#pragma unroll
      for (int j = 0; j < 4; j++) {
        int kj = 16*j + l16;
        float val = sc[j][r] * 0.125f;
        if (kt == qt && kj > qi) val = -1e30f;
        pv[j] = val;
        tm = fmaxf(tm, val);
      }
      tm = fmaxf(tm, __shfl_xor(tm, 1));
      tm = fmaxf(tm, __shfl_xor(tm, 2));
      tm = fmaxf(tm, __shfl_xor(tm, 4));
      tm = fmaxf(tm, __shfl_xor(tm, 8));
      float mnew = fmaxf(mrow_[r], tm);
      float alpha = __expf(mrow_[r] - mnew);
      mrow_[r] = mnew;
      float ps = 0.f;
#pragma unroll
      for (int j = 0; j < 4; j++) {
        float p = __expf(pv[j] - mnew);
        ps += p;
        Ps[qi*72 + 16*j + l16] = f2bf(p);
      }
      ps += __shfl_xor(ps, 1);
      ps += __shfl_xor(ps, 2);
      ps += __shfl_xor(ps, 4);
      ps += __shfl_xor(ps, 8);
      lrow_[r] = lrow_[r] * alpha + ps;
#pragma unroll
      for (int j = 0; j < 4; j++) ao[j][r] *= alpha;
    }
    __syncthreads();
    bf16x8 ap0 = *(const bf16x8*)&Ps[(16*w + l16)*72 + lg*8];
    bf16x8 ap1 = *(const bf16x8*)&Ps[(16*w + l16)*72 + 32 + lg*8];
#pragma unroll
    for (int j = 0; j < 4; j++) {
      bf16x8 b0 = *(const bf16x8*)&Ts[(16*j + l16)*72 + lg*8];
      bf16x8 b1 = *(const bf16x8*)&Ts[(16*j + l16)*72 + 32 + lg*8];
      ao[j] = MFMA16(ap0, b0, ao[j], 0, 0, 0);
      ao[j] = MFMA16(ap1, b1, ao[j], 0, 0, 0);
    }
  }

  // ---- epilogue: o / l -> ob (M, D) bf16 ----
#pragma unroll
  for (int j = 0; j < 4; j++)
#pragma unroll
    for (int r = 0; r < 4; r++) {
      int qi = 16*w + lg*4 + r;
      ob[((size_t)b*S + qt*64 + qi) * D + hh*64 + 16*j + l16] = f2bf(ao[j][r] / lrow_[r]);
    }
}

// ======================================================================
// launcher
// ======================================================================
extern "C" void kernel_launch(void* const* d_in, const int* in_sizes, int n_in,
                              void* d_out, int out_size, void* d_ws, size_t ws_size,
                              hipStream_t stream) {
  const int*   ids      = (const int*)d_in[0];
  const float* tok_emb  = (const float*)d_in[1];
  const float* w_init   = (const float*)d_in[2];
  const float* persist  = (const float*)d_in[3];
  const float* norm1_w  = (const float*)d_in[4];
  const float* norm2_w  = (const float*)d_in[5];
  const float* norm_f_w = (const float*)d_in[6];
  const float* qkv_w    = (const float*)d_in[7];
  const float* q_norm_w = (const float*)d_in[8];
  const float* k_norm_w = (const float*)d_in[9];
  const float* gamma_w1 = (const float*)d_in[10];
  const float* gamma_w2 = (const float*)d_in[11];
  const float* mem_gate = (const float*)d_in[12];
  const float* w_o      = (const float*)d_in[13];
  const float* ffn_w1   = (const float*)d_in[14];
  const float* ffn_w2   = (const float*)d_in[15];
  const float* ffn_w3   = (const float*)d_in[16];
  float* out = (float*)d_out;

  // ---- workspace layout (f32 units noted) ----
  float* ws   = (float*)d_ws;
  float* x    = ws;                          // 2097152
  us*    hbf  = (us*)(x + 2097152);          // 2097152 us
  float* gk   = x + 2097152 + 1048576;
  float* nrm  = gk + 2048;
  float* cosT = nrm + 2048;
  float* sinT = cosT + 32768;
  float* MpB  = sinT + 32768;                // 65536
  float* h    = MpB + 65536;                 // 2097152
  float* qkv  = h + 2097152;                 // 6291456 (ffn1_f32 alias)
  us*    obf  = (us*)(qkv + 6291456);        // 2097152 us
  us*    qb   = obf + 2097152;
  us*    kb   = qb + 2097152;
  us*    vb   = kb + 2097152;
  us*    kbT  = vb + 2097152;
  us*    vbT  = kbT + 2097152;
  us*    f1bf = vbT + 2097152;               // M*FFP = 5636096 us
  us*    wq   = f1bf + (size_t)M*FFP;        // 3145728
  us*    wo   = wq + 3145728;                // 1048576
  us*    w1c  = wo + 1048576;                // 2795520
  us*    w2c  = w1c + 2795520;               // 2795520
  us*    w3c  = w2c + 2795520;               // 1024*FFP = 2818048
  us*    temb = (us*)h;                      // 32768000 us, aliases dead h..w3c span
  float* ffn1 = qkv;

  k_embed<<<M, 256, 0, stream>>>(ids, tok_emb, w_init, x);
  k_rope_tables<<<(S*32 + 255)/256, 256, 0, stream>>>(cosT, sinT);
  k_mp<<<H, 256, 0, stream>>>(persist, MpB);

  for (int l = 0; l < NL; l++) {
    k_rms<<<M, 256, 0, stream>>>(x, norm1_w + (size_t)l * D, h, hbf);
    k_cvt<<<1024, 256, 0, stream>>>(qkv_w + (size_t)l*3*D*D, wq, 3*D*D);
    k_bgemm<0,128,128><<<dim3(M/128, 3*D/128), 256, 0, stream>>>(hbf, wq, qkv, 3*D, D);
    k_qkvpost<<<M, 256, 0, stream>>>(qkv, q_norm_w + (size_t)l*DH, k_norm_w + (size_t)l*DH,
                                     cosT, sinT, qb, kb, vb);
    k_tr<<<dim3(S/64, B*H), 256, 0, stream>>>(kb, kbT);
    k_tr<<<dim3(S/64, B*H), 256, 0, stream>>>(vb, vbT);
    k_gamma<<<M, 256, 0, stream>>>(h, gamma_w1 + (size_t)l*GH*D, gamma_w2 + (size_t)l*GH, gk);
    k_cumsum<<<B, S, 0, stream>>>(gk, nrm);
    k_matt<<<dim3(S/64, B*H), 256, 0, stream>>>(qb, kb, kbT, vbT, MpB, gk, nrm, mem_gate, l, obf);
    k_cvt<<<1024, 256, 0, stream>>>(w_o + (size_t)l*D*D, wo, D*D);
    k_bgemm<2,64,64><<<dim3(M/64, D/64), 256, 0, stream>>>(obf, wo, x, D, D);
    k_rms<<<M, 256, 0, stream>>>(x, norm2_w + (size_t)l * D, h, hbf);
    k_cvt<<<1024, 256, 0, stream>>>(ffn_w1 + (size_t)l*FF*D, w1c, FF*D);
    k_bgemm<1,128,128><<<dim3(M/128, (FF+127)/128), 256, 0, stream>>>(hbf, w1c, ffn1, FF, D);
    k_cvt<<<1024, 256, 0, stream>>>(ffn_w2 + (size_t)l*FF*D, w2c, FF*D);
    k_bgemm<3,128,128><<<dim3(M/128, (FF+127)/128), 256, 0, stream>>>(hbf, w2c, ffn1, FF, D);
    k_cvt_pad<<<D, 256, 0, stream>>>(ffn_w3 + (size_t)l*D*FF, w3c, FF, FFP);
    k_cvt_pad<<<M, 256, 0, stream>>>(ffn1, f1bf, FF, FFP);
    k_bgemm<2,64,64><<<dim3(M/64, D/64), 256, 0, stream>>>(f1bf, w3c, x, D, FFP);
  }

  k_rms<<<M, 256, 0, stream>>>(x, norm_f_w, h, hbf);
  k_cvt<<<2048, 256, 0, stream>>>(tok_emb, temb, V*D);
  k_bgemm<0,128,128><<<dim3(M/128, V/128), 256, 0, stream>>>(hbf, temb, out, V, D);
}

// Round 5
// 1959.406 us; speedup vs baseline: 13.2589x; 1.1948x over previous
//
#include <hip/hip_runtime.h>
#include <hip/hip_bf16.h>
#include <math.h>

// ---------------- problem constants ----------------
#define B 2
#define S 1024
#define D 1024
#define H 16
#define DH 64
#define NL 6
#define GH 64
#define NP 16
#define V 32000
#define FF 2730
#define FFP 2752   // FF padded to multiple of 64
#define M (B*S)    // 2048 rows

typedef float fv4 __attribute__((ext_vector_type(4)));
typedef short bf16x8 __attribute__((ext_vector_type(8)));       // 8 bf16 = 4 VGPRs
typedef unsigned short us4 __attribute__((ext_vector_type(4))); // 4 bf16 = 8 bytes
typedef unsigned short us;

#define MFMA16 __builtin_amdgcn_mfma_f32_16x16x32_bf16
#define G2L16(g, l) __builtin_amdgcn_global_load_lds( \
    (const __attribute__((address_space(1))) void*)(g), \
    (__attribute__((address_space(3))) void*)(l), 16, 0, 0)

__device__ __forceinline__ us f2bf(float f) {
  union { float f; unsigned u; } v; v.f = f;
  unsigned r = v.u + 0x7FFFu + ((v.u >> 16) & 1u);   // RNE
  return (us)(r >> 16);
}
__device__ __forceinline__ float bf2f(us h) {
  union { unsigned u; float f; } v; v.u = ((unsigned)h) << 16;
  return v.f;
}

// m204 bijective XCD swizzle: consecutive hw ids -> one XCD owns a
// contiguous chunk of the flattened grid.
__device__ __forceinline__ int xcd_remap(int flat, int nwg) {
  int q = nwg >> 3, r = nwg & 7;
  int xcd = flat & 7, idx = flat >> 3;
  return (xcd < r) ? (xcd * (q + 1) + idx) : (r * (q + 1) + (xcd - r) * q + idx);
}

// ======================================================================
// embed
// ======================================================================
__global__ __launch_bounds__(256) void k_embed(const int* __restrict__ ids,
                                               const float* __restrict__ emb,
                                               const float* __restrict__ winit,
                                               float* __restrict__ x) {
  int m = blockIdx.x, t = threadIdx.x;
  int id = ids[m];
  fv4 a = *(const fv4*)(emb + (size_t)id * D + 4*t);
  fv4 w = *(const fv4*)(winit + 4*t);
  *(fv4*)(x + (size_t)m * D + 4*t) = a + w;
}

// ======================================================================
// rope tables
// ======================================================================
__global__ void k_rope_tables(float* __restrict__ cosT, float* __restrict__ sinT) {
  int idx = blockIdx.x * blockDim.x + threadIdx.x;
  if (idx >= S * 32) return;
  int s = idx >> 5, f = idx & 31;
  float inv = powf(10000.0f, -2.0f * (float)f / (float)DH);
  float ang = (float)s * inv;
  cosT[idx] = cosf(ang);
  sinT[idx] = sinf(ang);
}

// ======================================================================
// Mp[h][d][e] = sum_n p[n][h][d] * p[n][h][e]   (symmetric)
// ======================================================================
__global__ __launch_bounds__(256) void k_mp(const float* __restrict__ pers,
                                            float* __restrict__ Mp) {
  int h = blockIdx.x, t = threadIdx.x;
  __shared__ float p[NP][DH];
  for (int i = t; i < NP * DH; i += 256) {
    int n = i / DH, dh = i % DH;
    p[n][dh] = pers[(size_t)n * D + h * DH + dh];
  }
  __syncthreads();
  for (int i = t; i < DH * DH; i += 256) {
    int d = i / DH, e = i % DH;
    float s = 0.f;
#pragma unroll
    for (int n = 0; n < NP; n++) s += p[n][d] * p[n][e];
    Mp[(size_t)h * DH * DH + i] = s;
  }
}

// ======================================================================
// rmsnorm rows of D, dual store f32 + bf16
// ======================================================================
__global__ __launch_bounds__(256) void k_rms(const float* __restrict__ in,
                                             const float* __restrict__ w,
                                             float* __restrict__ out,
                                             us* __restrict__ outb) {
  int m = blockIdx.x, t = threadIdx.x;
  fv4 v = *(const fv4*)(in + (size_t)m * D + 4*t);
  float ss = v[0]*v[0] + v[1]*v[1] + v[2]*v[2] + v[3]*v[3];
#pragma unroll
  for (int off = 32; off > 0; off >>= 1) ss += __shfl_down(ss, off);
  __shared__ float buf[4];
  if ((t & 63) == 0) buf[t >> 6] = ss;
  __syncthreads();
  float tot = buf[0] + buf[1] + buf[2] + buf[3];
  float r = rsqrtf(tot * (1.0f / (float)D) + 1e-6f);
  fv4 wv = *(const fv4*)(w + 4*t);
  fv4 res = v * r * wv;
  *(fv4*)(out + (size_t)m * D + 4*t) = res;
  us4 o; o[0]=f2bf(res[0]); o[1]=f2bf(res[1]); o[2]=f2bf(res[2]); o[3]=f2bf(res[3]);
  *(us4*)(outb + (size_t)m * D + 4*t) = o;
}

// ======================================================================
// flat f32 -> bf16 convert (n % 4 == 0)
// ======================================================================
__global__ __launch_bounds__(256) void k_cvt(const float* __restrict__ src,
                                             us* __restrict__ dst, int n) {
  for (size_t i = ((size_t)blockIdx.x * 256 + threadIdx.x) * 4; i < (size_t)n;
       i += (size_t)gridDim.x * 1024) {
    fv4 v = *(const fv4*)(src + i);
    us4 o; o[0]=f2bf(v[0]); o[1]=f2bf(v[1]); o[2]=f2bf(v[2]); o[3]=f2bf(v[3]);
    *(us4*)(dst + i) = o;
  }
}

// ======================================================================
// per-layer weight conversion, single launch: qkv_w, w_o, ffn_w1, ffn_w2
// flat fv4 converts + ffn_w3 row-pad convert (2730 -> 2752).
// ======================================================================
#define CVT_N1 786432   // 3*D*D/4
#define CVT_N2 262144   // D*D/4
#define CVT_N3 698880   // FF*D/4
#define CVT_N4 698880
#define CVT_N5 704512   // D * FFP/4
__global__ __launch_bounds__(256) void k_cvtw(const float* __restrict__ s1,
                                              const float* __restrict__ s2,
                                              const float* __restrict__ s3,
                                              const float* __restrict__ s4,
                                              const float* __restrict__ s5,
                                              us* __restrict__ d1, us* __restrict__ d2,
                                              us* __restrict__ d3, us* __restrict__ d4,
                                              us* __restrict__ d5) {
  const int TOT = CVT_N1 + CVT_N2 + CVT_N3 + CVT_N4 + CVT_N5;
  for (int i = blockIdx.x * 256 + threadIdx.x; i < TOT; i += gridDim.x * 256) {
    const float* s; us* d; int j = i;
    if (j < CVT_N1) { s = s1; d = d1; }
    else if ((j -= CVT_N1) < CVT_N2) { s = s2; d = d2; }
    else if ((j -= CVT_N2) < CVT_N3) { s = s3; d = d3; }
    else if ((j -= CVT_N3) < CVT_N4) { s = s4; d = d4; }
    else {
      j -= CVT_N4;
      int r = j / (FFP/4), c = (j % (FFP/4)) * 4;
      us4 o;
#pragma unroll
      for (int q = 0; q < 4; q++) {
        int cc = c + q;
        o[q] = (cc < FF) ? f2bf(s5[(size_t)r * FF + cc]) : (us)0;
      }
      *(us4*)&d5[(size_t)r * FFP + c] = o;
      continue;
    }
    fv4 v = *(const fv4*)(s + (size_t)4 * j);
    us4 o; o[0]=f2bf(v[0]); o[1]=f2bf(v[1]); o[2]=f2bf(v[2]); o[3]=f2bf(v[3]);
    *(us4*)&d[(size_t)4 * j] = o;
  }
}

// ======================================================================
// bf16 MFMA GEMM, m97 structure + XCD swizzle. A: M x Kk bf16,
// W: Nn x Kk bf16 (B^T). C f32. EPI: 0 store, 1 silu, 2 add, 3 mul.
// ======================================================================
template<int EPI, int BM, int BN>
__global__ __launch_bounds__(256) void k_bgemm(const us* __restrict__ A,
                                               const us* __restrict__ W,
                                               float* __restrict__ C,
                                               int Nn, int Kk) {
  constexpr int FM = BM / 32;
  constexpr int FN = BN / 32;
  constexpr int ACW = BM / 32;
  constexpr int BCW = BN / 32;
  __shared__ __attribute__((aligned(16))) us As[BM * 64];
  __shared__ __attribute__((aligned(16))) us Bs[BN * 64];
  int t = threadIdx.x, lane = t & 63, w = t >> 6;
  int l16 = lane & 15, lkb = lane >> 4;
  int lr = lane >> 3, lc = (lane & 7) * 8;
  int gx = gridDim.x, nwg = gx * gridDim.y;
  int nf = xcd_remap(blockIdx.y * gx + blockIdx.x, nwg);
  int m0 = (nf % gx) * BM, n0 = (nf / gx) * BN;
  int wr = w >> 1, wc = w & 1;

  const us* aB[ACW]; us* aL[ACW];
  const us* bB[BCW]; us* bL[BCW];
#pragma unroll
  for (int i = 0; i < ACW; i++) {
    int chunk = w * ACW + i;
    aB[i] = A + (size_t)(m0 + chunk * 8 + lr) * Kk + lc;
    aL[i] = &As[chunk * 512];
  }
#pragma unroll
  for (int i = 0; i < BCW; i++) {
    int chunk = w * BCW + i;
    int wrow = n0 + chunk * 8 + lr;
    if (wrow >= Nn) wrow = Nn - 1;
    bB[i] = W + (size_t)wrow * Kk + lc;
    bL[i] = &Bs[chunk * 512];
  }

  fv4 acc[FM][FN] = {};
  for (int k0 = 0; k0 < Kk; k0 += 64) {
#pragma unroll
    for (int i = 0; i < ACW; i++) G2L16(aB[i] + k0, aL[i]);
#pragma unroll
    for (int i = 0; i < BCW; i++) G2L16(bB[i] + k0, bL[i]);
    __syncthreads();
#pragma unroll
    for (int kk = 0; kk < 2; kk++) {
      bf16x8 af[FM], bfh[FN];
#pragma unroll
      for (int i = 0; i < FM; i++)
        af[i] = *(const bf16x8*)&As[(wr*(BM/2) + i*16 + l16)*64 + kk*32 + lkb*8];
#pragma unroll
      for (int j = 0; j < FN; j++)
        bfh[j] = *(const bf16x8*)&Bs[(wc*(BN/2) + j*16 + l16)*64 + kk*32 + lkb*8];
#pragma unroll
      for (int i = 0; i < FM; i++)
#pragma unroll
        for (int j = 0; j < FN; j++)
          acc[i][j] = MFMA16(af[i], bfh[j], acc[i][j], 0, 0, 0);
    }
    __syncthreads();
  }

#pragma unroll
  for (int i = 0; i < FM; i++) {
    int gr0 = m0 + wr*(BM/2) + i*16 + lkb*4;
#pragma unroll
    for (int j = 0; j < FN; j++) {
      int gc = n0 + wc*(BN/2) + j*16 + l16;
      if (gc < Nn) {
#pragma unroll
        for (int r = 0; r < 4; r++) {
          size_t idx = (size_t)(gr0 + r) * Nn + gc;
          float val = acc[i][j][r];
          if (EPI == 0) C[idx] = val;
          else if (EPI == 1) C[idx] = val / (1.f + expf(-val));
          else if (EPI == 2) C[idx] += val;
          else C[idx] *= val;
        }
      }
    }
  }
}

// ======================================================================
// fused FFN w1/w2 GEMM: Cb[m][n] = f2bf( silu(A@W1^T) * (A@W2^T) ),
// bf16 output with row stride FFP (pad cols untouched; W pad rows are 0).
// BM=BN=64.
// ======================================================================
__global__ __launch_bounds__(256) void k_ffn12(const us* __restrict__ A,
                                               const us* __restrict__ W1,
                                               const us* __restrict__ W2,
                                               us* __restrict__ Cb,
                                               int Nn, int Kk) {
  __shared__ __attribute__((aligned(16))) us As[64 * 64];
  __shared__ __attribute__((aligned(16))) us B1s[64 * 64];
  __shared__ __attribute__((aligned(16))) us B2s[64 * 64];
  int t = threadIdx.x, lane = t & 63, w = t >> 6;
  int l16 = lane & 15, lkb = lane >> 4;
  int lr = lane >> 3, lc = (lane & 7) * 8;
  int gx = gridDim.x, nwg = gx * gridDim.y;
  int nf = xcd_remap(blockIdx.y * gx + blockIdx.x, nwg);
  int m0 = (nf % gx) * 64, n0 = (nf / gx) * 64;
  int wr = w >> 1, wc = w & 1;

  const us* aB[2]; us* aL[2];
  const us* b1B[2]; us* b1L[2];
  const us* b2B[2]; us* b2L[2];
#pragma unroll
  for (int i = 0; i < 2; i++) {
    int chunk = w * 2 + i;
    aB[i] = A + (size_t)(m0 + chunk * 8 + lr) * Kk + lc;
    aL[i] = &As[chunk * 512];
    int wrow = n0 + chunk * 8 + lr;
    if (wrow >= Nn) wrow = Nn - 1;
    b1B[i] = W1 + (size_t)wrow * Kk + lc;
    b1L[i] = &B1s[chunk * 512];
    b2B[i] = W2 + (size_t)wrow * Kk + lc;
    b2L[i] = &B2s[chunk * 512];
  }

  fv4 acc1[2][2] = {}, acc2[2][2] = {};
  for (int k0 = 0; k0 < Kk; k0 += 64) {
#pragma unroll
    for (int i = 0; i < 2; i++) {
      G2L16(aB[i] + k0, aL[i]);
      G2L16(b1B[i] + k0, b1L[i]);
      G2L16(b2B[i] + k0, b2L[i]);
    }
    __syncthreads();
#pragma unroll
    for (int kk = 0; kk < 2; kk++) {
      bf16x8 af[2], b1f[2], b2f[2];
#pragma unroll
      for (int i = 0; i < 2; i++)
        af[i] = *(const bf16x8*)&As[(wr*32 + i*16 + l16)*64 + kk*32 + lkb*8];
#pragma unroll
      for (int j = 0; j < 2; j++) {
        b1f[j] = *(const bf16x8*)&B1s[(wc*32 + j*16 + l16)*64 + kk*32 + lkb*8];
        b2f[j] = *(const bf16x8*)&B2s[(wc*32 + j*16 + l16)*64 + kk*32 + lkb*8];
      }
#pragma unroll
      for (int i = 0; i < 2; i++)
#pragma unroll
        for (int j = 0; j < 2; j++) {
          acc1[i][j] = MFMA16(af[i], b1f[j], acc1[i][j], 0, 0, 0);
          acc2[i][j] = MFMA16(af[i], b2f[j], acc2[i][j], 0, 0, 0);
        }
    }
    __syncthreads();
  }

#pragma unroll
  for (int i = 0; i < 2; i++) {
    int gr0 = m0 + wr*32 + i*16 + lkb*4;
#pragma unroll
    for (int j = 0; j < 2; j++) {
      int gc = n0 + wc*32 + j*16 + l16;
      if (gc < Nn) {
#pragma unroll
        for (int r = 0; r < 4; r++) {
          float v1 = acc1[i][j][r], v2 = acc2[i][j][r];
          float sv = v1 / (1.f + expf(-v1));
          Cb[(size_t)(gr0 + r) * FFP + gc] = f2bf(sv * v2);
        }
      }
    }
  }
}

// ======================================================================
// qkv post: split heads, qk rmsnorm, rope -> q/k/v in (bh, s, dh) BF16
// ======================================================================
__global__ __launch_bounds__(256) void k_qkvpost(const float* __restrict__ qkv,
                                                 const float* __restrict__ qnw,
                                                 const float* __restrict__ knw,
                                                 const float* __restrict__ cosT,
                                                 const float* __restrict__ sinT,
                                                 us* __restrict__ q,
                                                 us* __restrict__ k,
                                                 us* __restrict__ v) {
  int m = blockIdx.x;
  int b = m / S, s = m % S;
  int t = threadIdx.x;
  __shared__ float buf[D];
  __shared__ float cs[32], sn[32];
  if (t < 32) { cs[t] = cosT[s*32 + t]; sn[t] = sinT[s*32 + t]; }
  const float* row = qkv + (size_t)m * 3 * D;
  int lane16 = t & 15;
  int e = 4 * t, eh = e >> 6, rdh = e & 63;

  for (int part = 0; part < 2; part++) {
    fv4 val = *(const fv4*)(row + part * D + 4*t);
    float ss = val[0]*val[0] + val[1]*val[1] + val[2]*val[2] + val[3]*val[3];
    ss += __shfl_xor(ss, 8); ss += __shfl_xor(ss, 4);
    ss += __shfl_xor(ss, 2); ss += __shfl_xor(ss, 1);
    float r = rsqrtf(ss * (1.0f / (float)DH) + 1e-6f);
    fv4 w4 = *(const fv4*)((part == 0 ? qnw : knw) + 4*lane16);
    *(fv4*)&buf[4*t] = val * r * w4;
    __syncthreads();
    fv4 out;
#pragma unroll
    for (int j = 0; j < 4; j++) {
      int rr = rdh + j;
      if (rr < 32) {
        float x1 = buf[eh*64 + rr], x2 = buf[eh*64 + rr + 32];
        out[j] = x1 * cs[rr] - x2 * sn[rr];
      } else {
        int f = rr - 32;
        float x1 = buf[eh*64 + f], x2 = buf[eh*64 + rr];
        out[j] = x2 * cs[f] + x1 * sn[f];
      }
    }
    us* dst = (part == 0 ? q : k);
    us4 o; o[0]=f2bf(out[0]); o[1]=f2bf(out[1]); o[2]=f2bf(out[2]); o[3]=f2bf(out[3]);
    *(us4*)&dst[(((size_t)(b*H + eh)) * S + s) * DH + rdh] = o;
    __syncthreads();
  }
  fv4 vv = *(const fv4*)(row + 2 * D + 4*t);
  us4 o; o[0]=f2bf(vv[0]); o[1]=f2bf(vv[1]); o[2]=f2bf(vv[2]); o[3]=f2bf(vv[3]);
  *(us4*)&v[(((size_t)(b*H + eh)) * S + s) * DH + rdh] = o;
}

// ======================================================================
// 64x64 bf16 transpose: (bh, s, dh) -> (bh, dh, s); grid.z selects k or v
// ======================================================================
__global__ __launch_bounds__(256) void k_tr2(const us* __restrict__ ksrc,
                                             const us* __restrict__ vsrc,
                                             us* __restrict__ kdst,
                                             us* __restrict__ vdst) {
  __shared__ __attribute__((aligned(16))) us tile[64*72];
  int st = blockIdx.x, bh = blockIdx.y, t = threadIdx.x;
  const us* src = blockIdx.z ? vsrc : ksrc;
  us* dst = blockIdx.z ? vdst : kdst;
  const us* sp = src + ((size_t)bh * S + st*64) * 64;
#pragma unroll
  for (int p = 0; p < 2; p++) {
    int idx = t + p*256;
    int r = idx >> 3, c = (idx & 7)*8;
    *(bf16x8*)&tile[r*72 + c] = *(const bf16x8*)&sp[(size_t)idx*8];
  }
  __syncthreads();
  int d = t >> 2;
#pragma unroll
  for (int cc = 0; cc < 16; cc += 8) {
    int s0 = (t & 3)*16 + cc;
    bf16x8 vv;
#pragma unroll
    for (int j2 = 0; j2 < 8; j2++) vv[j2] = (short)tile[(s0+j2)*72 + d];
    *(bf16x8*)&dst[((size_t)bh*64 + d)*S + st*64 + s0] = vv;
  }
}

// ======================================================================
// gamma gate
// ======================================================================
__global__ __launch_bounds__(256) void k_gamma(const float* __restrict__ h,
                                               const float* __restrict__ w1,
                                               const float* __restrict__ w2,
                                               float* __restrict__ gk) {
  int m = blockIdx.x, t = threadIdx.x;
  __shared__ float hrow[D];
  *(fv4*)&hrow[4*t] = *(const fv4*)(h + (size_t)m * D + 4*t);
  __syncthreads();
  int o = t & 63, seg = t >> 6;
  const float* wr = w1 + (size_t)o * D + seg * 256;
  const float* hr = hrow + seg * 256;
  float acc = 0.f;
  for (int j = 0; j < 256; j += 4) {
    fv4 wv = *(const fv4*)(wr + j);
    acc += wv[0]*hr[j] + wv[1]*hr[j+1] + wv[2]*hr[j+2] + wv[3]*hr[j+3];
  }
  __shared__ float part[4][64];
  part[seg][o] = acc;
  __syncthreads();
  if (t < 64) {
    float dot = part[0][t] + part[1][t] + part[2][t] + part[3][t];
    float sv = dot / (1.f + expf(-dot));
    float val = sv * w2[t];
#pragma unroll
    for (int off = 32; off > 0; off >>= 1) val += __shfl_down(val, off);
    if (t == 0) gk[m] = 1.f / (1.f + expf(-val));
  }
}

// ======================================================================
// cumsum: wave-scan (3 barriers)
// ======================================================================
__global__ __launch_bounds__(1024) void k_cumsum(const float* __restrict__ gk,
                                                 float* __restrict__ nrm) {
  int b = blockIdx.x, t = threadIdx.x;
  int lane = t & 63, wv = t >> 6;
  float s = gk[b*S + t];
#pragma unroll
  for (int off = 1; off < 64; off <<= 1) {
    float y = __shfl_up(s, off, 64);
    if (lane >= off) s += y;
  }
  __shared__ float wsum[16];
  if (lane == 63) wsum[wv] = s;
  __syncthreads();
  if (t < 16) {
    float v = wsum[t];
    float sv = v;
#pragma unroll
    for (int off = 1; off < 16; off <<= 1) {
      float y = __shfl_up(sv, off, 16);
      if (t >= off) sv += y;
    }
    wsum[t] = sv - v;   // exclusive prefix of waves
  }
  __syncthreads();
  nrm[b*S + t] = (float)NP + s + wsum[wv];
}

// ======================================================================
// FUSED omega-memory + flash attention, MFMA bf16, fixed-offset softmax.
// grid (16, 32) swizzled so each XCD owns 4 bh (K/V L2-resident).
// ======================================================================
#define SM_OFF 24.0f
__global__ __launch_bounds__(256) void k_matt(const us* __restrict__ qb,
                                              const us* __restrict__ kb,
                                              const us* __restrict__ kbT,
                                              const us* __restrict__ vbT,
                                              const float* __restrict__ MpB,
                                              const float* __restrict__ gk,
                                              const float* __restrict__ nrm,
                                              const float* __restrict__ mg, int layer,
                                              us* __restrict__ ob) {
  // swizzle: flat y-major -> XCD-chunked (nwg=512, 64 per XCD = 4 bh x 16 qt)
  int nf = xcd_remap(blockIdx.y * 16 + blockIdx.x, 512);
  int xx = nf & 15, bh = nf >> 4;
  int qt = (xx & 1) ? 15 - (xx >> 1) : (xx >> 1);
  int b = bh >> 4, hh = bh & 15;
  int t = threadIdx.x, lane = t & 63, w = t >> 6;
  int l16 = lane & 15, lg = lane >> 4;

  __shared__ __attribute__((aligned(16))) us Qs[64*72];
  __shared__ __attribute__((aligned(16))) us Ks[64*72];
  __shared__ __attribute__((aligned(16))) us Ts[64*72];
  __shared__ __attribute__((aligned(16))) us Ps[64*72];
  __shared__ float gks_[64], nrms[64];

  float gate = 1.f / (1.f + expf(-mg[layer]));

  // ---- stage Q tile + Mp ----
  {
    const us* src = qb + ((size_t)bh * S + qt*64) * 64;
#pragma unroll
    for (int p = 0; p < 2; p++) {
      int idx = t + p*256;
      int r = idx >> 3, c = (idx & 7) * 8;
      *(bf16x8*)&Qs[r*72 + c] = *(const bf16x8*)&src[(size_t)idx*8];
    }
    const float* mp = MpB + (size_t)hh * 4096;
#pragma unroll
    for (int p = 0; p < 4; p++) {
      int e = (t + p*256) * 4;
      int r = e >> 6, c = e & 63;
      fv4 v = *(const fv4*)&mp[e];
      us4 o; o[0]=f2bf(v[0]); o[1]=f2bf(v[1]); o[2]=f2bf(v[2]); o[3]=f2bf(v[3]);
      *(us4*)&Ts[r*72 + c] = o;
    }
    if (t < 64) nrms[t] = nrm[b*S + qt*64 + t];
  }
  __syncthreads();

  bf16x8 aq0 = *(const bf16x8*)&Qs[(16*w + l16)*72 + lg*8];
  bf16x8 aq1 = *(const bf16x8*)&Qs[(16*w + l16)*72 + 32 + lg*8];

  // ---- acc_mem init = Mp q (Mp symmetric) ----
  fv4 am[4];
#pragma unroll
  for (int j = 0; j < 4; j++) {
    bf16x8 b0 = *(const bf16x8*)&Ts[(16*j + l16)*72 + lg*8];
    bf16x8 b1 = *(const bf16x8*)&Ts[(16*j + l16)*72 + 32 + lg*8];
    fv4 z = {};
    z = MFMA16(aq0, b0, z, 0, 0, 0);
    z = MFMA16(aq1, b1, z, 0, 0, 0);
    am[j] = z;
  }

  // ================= phase 1: omega memory =================
  for (int kt = 0; kt <= qt; kt++) {
    __syncthreads();
    {
      const us* ksrc = kb + ((size_t)bh * S + kt*64) * 64;
#pragma unroll
      for (int p = 0; p < 2; p++) {
        int idx = t + p*256;
        int r = idx >> 3, c = (idx & 7) * 8;
        *(bf16x8*)&Ks[r*72 + c] = *(const bf16x8*)&ksrc[(size_t)idx*8];
      }
      int d = t >> 2, c0 = (t & 3) * 16;
      const us* tsrc = kbT + ((size_t)bh*64 + d) * S + kt*64 + c0;
      *(bf16x8*)&Ts[d*72 + c0]     = *(const bf16x8*)&tsrc[0];
      *(bf16x8*)&Ts[d*72 + c0 + 8] = *(const bf16x8*)&tsrc[8];
      if (t < 64) gks_[t] = gk[b*S + kt*64 + t];
    }
    __syncthreads();
    fv4 sc[4];
#pragma unroll
    for (int j = 0; j < 4; j++) {
      bf16x8 b0 = *(const bf16x8*)&Ks[(16*j + l16)*72 + lg*8];
      bf16x8 b1 = *(const bf16x8*)&Ks[(16*j + l16)*72 + 32 + lg*8];
      fv4 z = {};
      z = MFMA16(aq0, b0, z, 0, 0, 0);
      z = MFMA16(aq1, b1, z, 0, 0, 0);
      sc[j] = z;
    }
    if (kt < qt) {
#pragma unroll
      for (int j = 0; j < 4; j++) {
        float g = gks_[16*j + l16];
#pragma unroll
        for (int r = 0; r < 4; r++)
          Ps[(16*w + lg*4 + r)*72 + 16*j + l16] = f2bf(sc[j][r] * g);
      }
    } else {
#pragma unroll
      for (int j = 0; j < 4; j++) {
        int kj = 16*j + l16;
        float g = gks_[kj];
#pragma unroll
        for (int r = 0; r < 4; r++) {
          int qi = 16*w + lg*4 + r;
          Ps[qi*72 + kj] = (kj > qi) ? (us)0 : f2bf(sc[j][r] * g);
        }
      }
    }
    __syncthreads();
    bf16x8 ap0 = *(const bf16x8*)&Ps[(16*w + l16)*72 + lg*8];
    bf16x8 ap1 = *(const bf16x8*)&Ps[(16*w + l16)*72 + 32 + lg*8];
#pragma unroll
    for (int j = 0; j < 4; j++) {
      bf16x8 b0 = *(const bf16x8*)&Ts[(16*j + l16)*72 + lg*8];
      bf16x8 b1 = *(const bf16x8*)&Ts[(16*j + l16)*72 + 32 + lg*8];
      am[j] = MFMA16(ap0, b0, am[j], 0, 0, 0);
      am[j] = MFMA16(ap1, b1, am[j], 0, 0, 0);
    }
  }

  // ---- q' = (1-gate) q + gate * acc/norm ----
  __syncthreads();
#pragma unroll
  for (int j = 0; j < 4; j++)
#pragma unroll
    for (int r = 0; r < 4; r++) {
      int qi = 16*w + lg*4 + r, dj = 16*j + l16;
      float qold = bf2f(Qs[qi*72 + dj]);
      float qn = (1.f - gate) * qold + gate * (am[j][r] / nrms[qi]);
      Qs[qi*72 + dj] = f2bf(qn);
    }
  __syncthreads();
  aq0 = *(const bf16x8*)&Qs[(16*w + l16)*72 + lg*8];
  aq1 = *(const bf16x8*)&Qs[(16*w + l16)*72 + 32 + lg*8];

  // ================= phase 2: flash attention, fixed-offset exp ========
  float lsum[4] = {};
  fv4 ao[4] = {};
  for (int kt = 0; kt <= qt; kt++) {
    __syncthreads();
    {
      const us* ksrc = kb + ((size_t)bh * S + kt*64) * 64;
#pragma unroll
      for (int p = 0; p < 2; p++) {
        int idx = t + p*256;
        int r = idx >> 3, c = (idx & 7) * 8;
        *(bf16x8*)&Ks[r*72 + c] = *(const bf16x8*)&ksrc[(size_t)idx*8];
      }
      int d = t >> 2, c0 = (t & 3) * 16;
      const us* tsrc = vbT + ((size_t)bh*64 + d) * S + kt*64 + c0;
      *(bf16x8*)&Ts[d*72 + c0]     = *(const bf16x8*)&tsrc[0];
      *(bf16x8*)&Ts[d*72 + c0 + 8] = *(const bf16x8*)&tsrc[8];
    }
    __syncthreads();
    fv4 sc[4];
#pragma unroll
    for (int j = 0; j < 4; j++) {
      bf16x8 b0 = *(const bf16x8*)&Ks[(16*j + l16)*72 + lg*8];
      bf16x8 b1 = *(const bf16x8*)&Ks[(16*j + l16)*72 + 32 + lg*8];
      fv4 z = {};
      z = MFMA16(aq0, b0, z, 0, 0, 0);
      z = MFMA16(aq1, b1, z, 0, 0, 0);
      sc[j] = z;
    }
    if (kt < qt) {
#pragma unroll
      for (int j = 0; j < 4; j++)
#pragma unroll
        for (int r = 0; r < 4; r++) {
          float p = __expf(fmaf(sc[j][r], 0.125f, -SM_OFF));
          lsum[r] += p;
          Ps[(16*w + lg*4 + r)*72 + 16*j + l16] = f2bf(p);
        }
    } else {
#pragma unroll
      for (int j = 0; j < 4; j++) {
        int kj = 16*j + l16;
#pragma unroll
        for (int r = 0; r < 4; r++) {
          int qi = 16*w + lg*4 + r;
          float p = (kj > qi) ? 0.f : __expf(fmaf(sc[j][r], 0.125f, -SM_OFF));
          lsum[r] += p;
          Ps[qi*72 + kj] = f2bf(p);
        }
      }
    }
    __syncthreads();
    bf16x8 ap0 = *(const bf16x8*)&Ps[(16*w + l16)*72 + lg*8];
    bf16x8 ap1 = *(const bf16x8*)&Ps[(16*w + l16)*72 + 32 + lg*8];
#pragma unroll
    for (int j = 0; j < 4; j++) {
      bf16x8 b0 = *(const bf16x8*)&Ts[(16*j + l16)*72 + lg*8];
      bf16x8 b1 = *(const bf16x8*)&Ts[(16*j + l16)*72 + 32 + lg*8];
      ao[j] = MFMA16(ap0, b0, ao[j], 0, 0, 0);
      ao[j] = MFMA16(ap1, b1, ao[j], 0, 0, 0);
    }
  }

  // ---- deferred l reduce (over the 16-lane k group) + epilogue ----
#pragma unroll
  for (int r = 0; r < 4; r++) {
    float l = lsum[r];
    l += __shfl_xor(l, 1);
    l += __shfl_xor(l, 2);
    l += __shfl_xor(l, 4);
    l += __shfl_xor(l, 8);
    lsum[r] = l;
  }
#pragma unroll
  for (int j = 0; j < 4; j++)
#pragma unroll
    for (int r = 0; r < 4; r++) {
      int qi = 16*w + lg*4 + r;
      ob[((size_t)b*S + qt*64 + qi) * D + hh*64 + 16*j + l16] = f2bf(ao[j][r] / lsum[r]);
    }
}

// ======================================================================
// launcher
// ======================================================================
extern "C" void kernel_launch(void* const* d_in, const int* in_sizes, int n_in,
                              void* d_out, int out_size, void* d_ws, size_t ws_size,
                              hipStream_t stream) {
  const int*   ids      = (const int*)d_in[0];
  const float* tok_emb  = (const float*)d_in[1];
  const float* w_init   = (const float*)d_in[2];
  const float* persist  = (const float*)d_in[3];
  const float* norm1_w  = (const float*)d_in[4];
  const float* norm2_w  = (const float*)d_in[5];
  const float* norm_f_w = (const float*)d_in[6];
  const float* qkv_w    = (const float*)d_in[7];
  const float* q_norm_w = (const float*)d_in[8];
  const float* k_norm_w = (const float*)d_in[9];
  const float* gamma_w1 = (const float*)d_in[10];
  const float* gamma_w2 = (const float*)d_in[11];
  const float* mem_gate = (const float*)d_in[12];
  const float* w_o      = (const float*)d_in[13];
  const float* ffn_w1   = (const float*)d_in[14];
  const float* ffn_w2   = (const float*)d_in[15];
  const float* ffn_w3   = (const float*)d_in[16];
  float* out = (float*)d_out;

  // ---- workspace layout ----
  float* ws   = (float*)d_ws;
  float* x    = ws;                          // 2097152 f32
  us*    hbf  = (us*)(x + 2097152);          // 2097152 us
  float* gk   = x + 2097152 + 1048576;
  float* nrm  = gk + 2048;
  float* cosT = nrm + 2048;
  float* sinT = cosT + 32768;
  float* MpB  = sinT + 32768;                // 65536
  float* h    = MpB + 65536;                 // 2097152
  float* qkv  = h + 2097152;                 // 6291456
  us*    obf  = (us*)(qkv + 6291456);        // 2097152 us
  us*    qb   = obf + 2097152;
  us*    kb   = qb + 2097152;
  us*    vb   = kb + 2097152;
  us*    kbT  = vb + 2097152;
  us*    vbT  = kbT + 2097152;
  us*    f1bf = vbT + 2097152;               // M*FFP = 5636096 us
  us*    wq   = f1bf + (size_t)M*FFP;        // 3145728
  us*    wo   = wq + 3145728;                // 1048576
  us*    w1c  = wo + 1048576;                // 2795520
  us*    w2c  = w1c + 2795520;               // 2795520
  us*    w3c  = w2c + 2795520;               // 2818048
  us*    temb = (us*)h;                      // aliases dead h..f1bf span

  k_embed<<<M, 256, 0, stream>>>(ids, tok_emb, w_init, x);
  k_rope_tables<<<(S*32 + 255)/256, 256, 0, stream>>>(cosT, sinT);
  k_mp<<<H, 256, 0, stream>>>(persist, MpB);

  for (int l = 0; l < NL; l++) {
    k_cvtw<<<2048, 256, 0, stream>>>(qkv_w + (size_t)l*3*D*D, w_o + (size_t)l*D*D,
                                     ffn_w1 + (size_t)l*FF*D, ffn_w2 + (size_t)l*FF*D,
                                     ffn_w3 + (size_t)l*D*FF,
                                     wq, wo, w1c, w2c, w3c);
    k_rms<<<M, 256, 0, stream>>>(x, norm1_w + (size_t)l * D, h, hbf);
    k_bgemm<0,64,128><<<dim3(M/64, 3*D/128), 256, 0, stream>>>(hbf, wq, qkv, 3*D, D);
    k_qkvpost<<<M, 256, 0, stream>>>(qkv, q_norm_w + (size_t)l*DH, k_norm_w + (size_t)l*DH,
                                     cosT, sinT, qb, kb, vb);
    k_tr2<<<dim3(S/64, B*H, 2), 256, 0, stream>>>(kb, vb, kbT, vbT);
    k_gamma<<<M, 256, 0, stream>>>(h, gamma_w1 + (size_t)l*GH*D, gamma_w2 + (size_t)l*GH, gk);
    k_cumsum<<<B, S, 0, stream>>>(gk, nrm);
    k_matt<<<dim3(16, B*H), 256, 0, stream>>>(qb, kb, kbT, vbT, MpB, gk, nrm, mem_gate, l, obf);
    k_bgemm<2,64,64><<<dim3(M/64, D/64), 256, 0, stream>>>(obf, wo, x, D, D);
    k_rms<<<M, 256, 0, stream>>>(x, norm2_w + (size_t)l * D, h, hbf);
    k_ffn12<<<dim3(M/64, (FF+63)/64), 256, 0, stream>>>(hbf, w1c, w2c, f1bf, FF, D);
    k_bgemm<2,64,64><<<dim3(M/64, D/64), 256, 0, stream>>>(f1bf, w3c, x, D, FFP);
  }

  k_rms<<<M, 256, 0, stream>>>(x, norm_f_w, h, hbf);
  k_cvt<<<2048, 256, 0, stream>>>(tok_emb, temb, V*D);
  k_bgemm<0,128,128><<<dim3(M/128, V/128), 256, 0, stream>>>(hbf, temb, out, V, D);
}

// Round 6
// 1899.102 us; speedup vs baseline: 13.6799x; 1.0318x over previous
//
#include <hip/hip_runtime.h>
#include <hip/hip_bf16.h>
#include <math.h>

// ---------------- problem constants ----------------
#define B 2
#define S 1024
#define D 1024
#define H 16
#define DH 64
#define NL 6
#define GH 64
#define NP 16
#define V 32000
#define FF 2730
#define FFP 2752   // FF padded to multiple of 64
#define M (B*S)    // 2048 rows

typedef float fv4 __attribute__((ext_vector_type(4)));
typedef short bf16x8 __attribute__((ext_vector_type(8)));       // 8 bf16 = 4 VGPRs
typedef unsigned short us4 __attribute__((ext_vector_type(4))); // 4 bf16 = 8 bytes
typedef unsigned short us;

#define MFMA16 __builtin_amdgcn_mfma_f32_16x16x32_bf16
#define G2L16(g, l) __builtin_amdgcn_global_load_lds( \
    (const __attribute__((address_space(1))) void*)(g), \
    (__attribute__((address_space(3))) void*)(l), 16, 0, 0)

__device__ __forceinline__ us f2bf(float f) {
  union { float f; unsigned u; } v; v.f = f;
  unsigned r = v.u + 0x7FFFu + ((v.u >> 16) & 1u);   // RNE
  return (us)(r >> 16);
}
__device__ __forceinline__ float bf2f(us h) {
  union { unsigned u; float f; } v; v.u = ((unsigned)h) << 16;
  return v.f;
}

// m204 bijective XCD swizzle
__device__ __forceinline__ int xcd_remap(int flat, int nwg) {
  int q = nwg >> 3, r = nwg & 7;
  int xcd = flat & 7, idx = flat >> 3;
  return (xcd < r) ? (xcd * (q + 1) + idx) : (r * (q + 1) + (xcd - r) * q + idx);
}

// ======================================================================
// embed
// ======================================================================
__global__ __launch_bounds__(256) void k_embed(const int* __restrict__ ids,
                                               const float* __restrict__ emb,
                                               const float* __restrict__ winit,
                                               float* __restrict__ x) {
  int m = blockIdx.x, t = threadIdx.x;
  int id = ids[m];
  fv4 a = *(const fv4*)(emb + (size_t)id * D + 4*t);
  fv4 w = *(const fv4*)(winit + 4*t);
  *(fv4*)(x + (size_t)m * D + 4*t) = a + w;
}

// ======================================================================
// rope tables
// ======================================================================
__global__ void k_rope_tables(float* __restrict__ cosT, float* __restrict__ sinT) {
  int idx = blockIdx.x * blockDim.x + threadIdx.x;
  if (idx >= S * 32) return;
  int s = idx >> 5, f = idx & 31;
  float inv = powf(10000.0f, -2.0f * (float)f / (float)DH);
  float ang = (float)s * inv;
  cosT[idx] = cosf(ang);
  sinT[idx] = sinf(ang);
}

// ======================================================================
// Mp[h][d][e] = sum_n p[n][h][d] * p[n][h][e]   (symmetric)
// ======================================================================
__global__ __launch_bounds__(256) void k_mp(const float* __restrict__ pers,
                                            float* __restrict__ Mp) {
  int h = blockIdx.x, t = threadIdx.x;
  __shared__ float p[NP][DH];
  for (int i = t; i < NP * DH; i += 256) {
    int n = i / DH, dh = i % DH;
    p[n][dh] = pers[(size_t)n * D + h * DH + dh];
  }
  __syncthreads();
  for (int i = t; i < DH * DH; i += 256) {
    int d = i / DH, e = i % DH;
    float s = 0.f;
#pragma unroll
    for (int n = 0; n < NP; n++) s += p[n][d] * p[n][e];
    Mp[(size_t)h * DH * DH + i] = s;
  }
}

// ======================================================================
// rmsnorm rows of D, dual store f32 + bf16
// ======================================================================
__global__ __launch_bounds__(256) void k_rms(const float* __restrict__ in,
                                             const float* __restrict__ w,
                                             float* __restrict__ out,
                                             us* __restrict__ outb) {
  int m = blockIdx.x, t = threadIdx.x;
  fv4 v = *(const fv4*)(in + (size_t)m * D + 4*t);
  float ss = v[0]*v[0] + v[1]*v[1] + v[2]*v[2] + v[3]*v[3];
#pragma unroll
  for (int off = 32; off > 0; off >>= 1) ss += __shfl_down(ss, off);
  __shared__ float buf[4];
  if ((t & 63) == 0) buf[t >> 6] = ss;
  __syncthreads();
  float tot = buf[0] + buf[1] + buf[2] + buf[3];
  float r = rsqrtf(tot * (1.0f / (float)D) + 1e-6f);
  fv4 wv = *(const fv4*)(w + 4*t);
  fv4 res = v * r * wv;
  *(fv4*)(out + (size_t)m * D + 4*t) = res;
  us4 o; o[0]=f2bf(res[0]); o[1]=f2bf(res[1]); o[2]=f2bf(res[2]); o[3]=f2bf(res[3]);
  *(us4*)(outb + (size_t)m * D + 4*t) = o;
}

// ======================================================================
// flat f32 -> bf16 convert (n % 4 == 0)
// ======================================================================
__global__ __launch_bounds__(256) void k_cvt(const float* __restrict__ src,
                                             us* __restrict__ dst, int n) {
  for (size_t i = ((size_t)blockIdx.x * 256 + threadIdx.x) * 4; i < (size_t)n;
       i += (size_t)gridDim.x * 1024) {
    fv4 v = *(const fv4*)(src + i);
    us4 o; o[0]=f2bf(v[0]); o[1]=f2bf(v[1]); o[2]=f2bf(v[2]); o[3]=f2bf(v[3]);
    *(us4*)(dst + i) = o;
  }
}

// ======================================================================
// per-layer weight conversion, single launch
// ======================================================================
#define CVT_N1 786432   // 3*D*D/4
#define CVT_N2 262144   // D*D/4
#define CVT_N3 698880   // FF*D/4
#define CVT_N4 698880
#define CVT_N5 704512   // D * FFP/4
__global__ __launch_bounds__(256) void k_cvtw(const float* __restrict__ s1,
                                              const float* __restrict__ s2,
                                              const float* __restrict__ s3,
                                              const float* __restrict__ s4,
                                              const float* __restrict__ s5,
                                              us* __restrict__ d1, us* __restrict__ d2,
                                              us* __restrict__ d3, us* __restrict__ d4,
                                              us* __restrict__ d5) {
  const int TOT = CVT_N1 + CVT_N2 + CVT_N3 + CVT_N4 + CVT_N5;
  for (int i = blockIdx.x * 256 + threadIdx.x; i < TOT; i += gridDim.x * 256) {
    const float* s; us* d; int j = i;
    if (j < CVT_N1) { s = s1; d = d1; }
    else if ((j -= CVT_N1) < CVT_N2) { s = s2; d = d2; }
    else if ((j -= CVT_N2) < CVT_N3) { s = s3; d = d3; }
    else if ((j -= CVT_N3) < CVT_N4) { s = s4; d = d4; }
    else {
      j -= CVT_N4;
      int r = j / (FFP/4), c = (j % (FFP/4)) * 4;
      us4 o;
#pragma unroll
      for (int q = 0; q < 4; q++) {
        int cc = c + q;
        o[q] = (cc < FF) ? f2bf(s5[(size_t)r * FF + cc]) : (us)0;
      }
      *(us4*)&d5[(size_t)r * FFP + c] = o;
      continue;
    }
    fv4 v = *(const fv4*)(s + (size_t)4 * j);
    us4 o; o[0]=f2bf(v[0]); o[1]=f2bf(v[1]); o[2]=f2bf(v[2]); o[3]=f2bf(v[3]);
    *(us4*)&d[(size_t)4 * j] = o;
  }
}

// ======================================================================
// bf16 MFMA GEMM, m97 structure + XCD swizzle (layer GEMMs).
// ======================================================================
template<int EPI, int BM, int BN>
__global__ __launch_bounds__(256) void k_bgemm(const us* __restrict__ A,
                                               const us* __restrict__ W,
                                               float* __restrict__ C,
                                               int Nn, int Kk) {
  constexpr int FM = BM / 32;
  constexpr int FN = BN / 32;
  constexpr int ACW = BM / 32;
  constexpr int BCW = BN / 32;
  __shared__ __attribute__((aligned(16))) us As[BM * 64];
  __shared__ __attribute__((aligned(16))) us Bs[BN * 64];
  int t = threadIdx.x, lane = t & 63, w = t >> 6;
  int l16 = lane & 15, lkb = lane >> 4;
  int lr = lane >> 3, lc = (lane & 7) * 8;
  int gx = gridDim.x, nwg = gx * gridDim.y;
  int nf = xcd_remap(blockIdx.y * gx + blockIdx.x, nwg);
  int m0 = (nf % gx) * BM, n0 = (nf / gx) * BN;
  int wr = w >> 1, wc = w & 1;

  const us* aB[ACW]; us* aL[ACW];
  const us* bB[BCW]; us* bL[BCW];
#pragma unroll
  for (int i = 0; i < ACW; i++) {
    int chunk = w * ACW + i;
    aB[i] = A + (size_t)(m0 + chunk * 8 + lr) * Kk + lc;
    aL[i] = &As[chunk * 512];
  }
#pragma unroll
  for (int i = 0; i < BCW; i++) {
    int chunk = w * BCW + i;
    int wrow = n0 + chunk * 8 + lr;
    if (wrow >= Nn) wrow = Nn - 1;
    bB[i] = W + (size_t)wrow * Kk + lc;
    bL[i] = &Bs[chunk * 512];
  }

  fv4 acc[FM][FN] = {};
  for (int k0 = 0; k0 < Kk; k0 += 64) {
#pragma unroll
    for (int i = 0; i < ACW; i++) G2L16(aB[i] + k0, aL[i]);
#pragma unroll
    for (int i = 0; i < BCW; i++) G2L16(bB[i] + k0, bL[i]);
    __syncthreads();
#pragma unroll
    for (int kk = 0; kk < 2; kk++) {
      bf16x8 af[FM], bfh[FN];
#pragma unroll
      for (int i = 0; i < FM; i++)
        af[i] = *(const bf16x8*)&As[(wr*(BM/2) + i*16 + l16)*64 + kk*32 + lkb*8];
#pragma unroll
      for (int j = 0; j < FN; j++)
        bfh[j] = *(const bf16x8*)&Bs[(wc*(BN/2) + j*16 + l16)*64 + kk*32 + lkb*8];
#pragma unroll
      for (int i = 0; i < FM; i++)
#pragma unroll
        for (int j = 0; j < FN; j++)
          acc[i][j] = MFMA16(af[i], bfh[j], acc[i][j], 0, 0, 0);
    }
    __syncthreads();
  }

#pragma unroll
  for (int i = 0; i < FM; i++) {
    int gr0 = m0 + wr*(BM/2) + i*16 + lkb*4;
#pragma unroll
    for (int j = 0; j < FN; j++) {
      int gc = n0 + wc*(BN/2) + j*16 + l16;
      if (gc < Nn) {
#pragma unroll
        for (int r = 0; r < 4; r++) {
          size_t idx = (size_t)(gr0 + r) * Nn + gc;
          float val = acc[i][j][r];
          if (EPI == 0) C[idx] = val;
          else if (EPI == 1) C[idx] = val / (1.f + expf(-val));
          else if (EPI == 2) C[idx] += val;
          else C[idx] *= val;
        }
      }
    }
  }
}

// ======================================================================
// 256x256 8-wave deep-pipelined bf16 GEMM (T2 swizzle + T3/T4 counted
// vmcnt + T5 setprio). Requires Mm%256==0, Nn%256==0, Kk%64==0.
// 512 threads = 8 waves (2M x 4N); per-wave 128x64; BK=64 double-buffered.
// Half-tile = 128 rows x 64 cols of one operand (2 global_load_lds).
// Issue queue: 7 halves in prologue, 4 per tile; vmcnt(8) per tile
// (vmcnt(0) only at the last tile). LDS swizzle: LDS[r][sl] holds
// G[r][sl ^ (r&7)] (16B slots), applied via per-lane global source perm.
// ======================================================================
struct G8 { const us* A; const us* W; int K; int m0; int n0; };

__device__ __forceinline__ void g8_issue(const G8& g, us* lds8, int q, int t) {
  int tile = q >> 2, h = q & 3;
  us* buf = lds8 + (size_t)(tile & 1) * 32768;
  const us* Gp = (h < 2) ? g.A : g.W;
  int rbase = ((h < 2) ? g.m0 : g.n0) + (h & 1) * 128;
  us* part = buf + (h >> 1) * 16384 + (h & 1) * 8192;
  int r8 = t >> 3;                               // 0..63
  int sl = (((t & 7) ^ (r8 & 7)) * 8);           // swizzled global 16B slot
#pragma unroll
  for (int c = 0; c < 2; c++) {
    const us* src = Gp + (size_t)(rbase + c * 64 + r8) * g.K + tile * 64 + sl;
    us* dst = part + c * 4096 + t * 8;           // linear: base + lane*16B
    G2L16(src, dst);
  }
}

__global__ __launch_bounds__(512, 2) void k_gemm8(const us* __restrict__ A,
                                                  const us* __restrict__ W,
                                                  float* __restrict__ C,
                                                  int Nn, int Kk) {
  __shared__ __attribute__((aligned(16))) us lds8[65536];   // 128 KB
  int t = threadIdx.x, lane = t & 63, w = t >> 6;
  int wm = w >> 2, wn = w & 3;
  int l16 = lane & 15, lkb = lane >> 4;
  int gx = gridDim.x, nwg = gx * gridDim.y;
  int nf = xcd_remap(blockIdx.y * gx + blockIdx.x, nwg);
  int m0 = (nf % gx) * 256, n0 = (nf / gx) * 256;
  G8 g{A, W, Kk, m0, n0};
  int NK = Kk >> 6, QMAX = NK * 4;

  int q = 0;
  for (; q < 7 && q < QMAX; ++q) g8_issue(g, lds8, q, t);

  fv4 acc[8][4] = {};
  int arow = wm * 128 + l16;
  int brow = wn * 64 + l16;
  int sw = l16 & 7;

  for (int T = 0; T < NK; ++T) {
    if (q < QMAX) { g8_issue(g, lds8, q, t); q++; }   // tile T+1, h3 -> other buf
    if (T == NK - 1) asm volatile("s_waitcnt vmcnt(0)" ::: "memory");
    else             asm volatile("s_waitcnt vmcnt(8)" ::: "memory");
    __builtin_amdgcn_s_barrier();                      // tile T resident
    const us* buf = lds8 + (size_t)(T & 1) * 32768;
    bf16x8 a0[8], a1[8], b0[4], b1[4];
#pragma unroll
    for (int i = 0; i < 8; i++) {
      a0[i] = *(const bf16x8*)&buf[(arow + i*16)*64 + ((lkb     ) ^ sw)*8];
      a1[i] = *(const bf16x8*)&buf[(arow + i*16)*64 + ((lkb +  4) ^ sw)*8];
    }
#pragma unroll
    for (int j = 0; j < 4; j++) {
      b0[j] = *(const bf16x8*)&buf[16384 + (brow + j*16)*64 + ((lkb    ) ^ sw)*8];
      b1[j] = *(const bf16x8*)&buf[16384 + (brow + j*16)*64 + ((lkb + 4) ^ sw)*8];
    }
    __builtin_amdgcn_s_barrier();                      // all waves' reads issued
    __builtin_amdgcn_s_setprio(1);
#pragma unroll
    for (int i = 0; i < 8; i++)
#pragma unroll
      for (int j = 0; j < 4; j++)
        acc[i][j] = MFMA16(a0[i], b0[j], acc[i][j], 0, 0, 0);
    __builtin_amdgcn_s_setprio(0);
    if (q < QMAX) { g8_issue(g, lds8, q, t); q++; }    // tile T+2 h0..2 -> cur buf
    if (q < QMAX) { g8_issue(g, lds8, q, t); q++; }    // (safe: after barrier 2)
    if (q < QMAX) { g8_issue(g, lds8, q, t); q++; }
    __builtin_amdgcn_s_setprio(1);
#pragma unroll
    for (int i = 0; i < 8; i++)
#pragma unroll
      for (int j = 0; j < 4; j++)
        acc[i][j] = MFMA16(a1[i], b1[j], acc[i][j], 0, 0, 0);
    __builtin_amdgcn_s_setprio(0);
  }

#pragma unroll
  for (int i = 0; i < 8; i++) {
    int gr0 = m0 + wm*128 + i*16 + lkb*4;
#pragma unroll
    for (int j = 0; j < 4; j++) {
      int gc = n0 + wn*64 + j*16 + l16;
#pragma unroll
      for (int r = 0; r < 4; r++)
        C[(size_t)(gr0 + r) * Nn + gc] = acc[i][j][r];
    }
  }
}

// ======================================================================
// fused FFN w1/w2 GEMM
// ======================================================================
__global__ __launch_bounds__(256) void k_ffn12(const us* __restrict__ A,
                                               const us* __restrict__ W1,
                                               const us* __restrict__ W2,
                                               us* __restrict__ Cb,
                                               int Nn, int Kk) {
  __shared__ __attribute__((aligned(16))) us As[64 * 64];
  __shared__ __attribute__((aligned(16))) us B1s[64 * 64];
  __shared__ __attribute__((aligned(16))) us B2s[64 * 64];
  int t = threadIdx.x, lane = t & 63, w = t >> 6;
  int l16 = lane & 15, lkb = lane >> 4;
  int lr = lane >> 3, lc = (lane & 7) * 8;
  int gx = gridDim.x, nwg = gx * gridDim.y;
  int nf = xcd_remap(blockIdx.y * gx + blockIdx.x, nwg);
  int m0 = (nf % gx) * 64, n0 = (nf / gx) * 64;
  int wr = w >> 1, wc = w & 1;

  const us* aB[2]; us* aL[2];
  const us* b1B[2]; us* b1L[2];
  const us* b2B[2]; us* b2L[2];
#pragma unroll
  for (int i = 0; i < 2; i++) {
    int chunk = w * 2 + i;
    aB[i] = A + (size_t)(m0 + chunk * 8 + lr) * Kk + lc;
    aL[i] = &As[chunk * 512];
    int wrow = n0 + chunk * 8 + lr;
    if (wrow >= Nn) wrow = Nn - 1;
    b1B[i] = W1 + (size_t)wrow * Kk + lc;
    b1L[i] = &B1s[chunk * 512];
    b2B[i] = W2 + (size_t)wrow * Kk + lc;
    b2L[i] = &B2s[chunk * 512];
  }

  fv4 acc1[2][2] = {}, acc2[2][2] = {};
  for (int k0 = 0; k0 < Kk; k0 += 64) {
#pragma unroll
    for (int i = 0; i < 2; i++) {
      G2L16(aB[i] + k0, aL[i]);
      G2L16(b1B[i] + k0, b1L[i]);
      G2L16(b2B[i] + k0, b2L[i]);
    }
    __syncthreads();
#pragma unroll
    for (int kk = 0; kk < 2; kk++) {
      bf16x8 af[2], b1f[2], b2f[2];
#pragma unroll
      for (int i = 0; i < 2; i++)
        af[i] = *(const bf16x8*)&As[(wr*32 + i*16 + l16)*64 + kk*32 + lkb*8];
#pragma unroll
      for (int j = 0; j < 2; j++) {
        b1f[j] = *(const bf16x8*)&B1s[(wc*32 + j*16 + l16)*64 + kk*32 + lkb*8];
        b2f[j] = *(const bf16x8*)&B2s[(wc*32 + j*16 + l16)*64 + kk*32 + lkb*8];
      }
#pragma unroll
      for (int i = 0; i < 2; i++)
#pragma unroll
        for (int j = 0; j < 2; j++) {
          acc1[i][j] = MFMA16(af[i], b1f[j], acc1[i][j], 0, 0, 0);
          acc2[i][j] = MFMA16(af[i], b2f[j], acc2[i][j], 0, 0, 0);
        }
    }
    __syncthreads();
  }

#pragma unroll
  for (int i = 0; i < 2; i++) {
    int gr0 = m0 + wr*32 + i*16 + lkb*4;
#pragma unroll
    for (int j = 0; j < 2; j++) {
      int gc = n0 + wc*32 + j*16 + l16;
      if (gc < Nn) {
#pragma unroll
        for (int r = 0; r < 4; r++) {
          float v1 = acc1[i][j][r], v2 = acc2[i][j][r];
          float sv = v1 / (1.f + expf(-v1));
          Cb[(size_t)(gr0 + r) * FFP + gc] = f2bf(sv * v2);
        }
      }
    }
  }
}

// ======================================================================
// qkv post
// ======================================================================
__global__ __launch_bounds__(256) void k_qkvpost(const float* __restrict__ qkv,
                                                 const float* __restrict__ qnw,
                                                 const float* __restrict__ knw,
                                                 const float* __restrict__ cosT,
                                                 const float* __restrict__ sinT,
                                                 us* __restrict__ q,
                                                 us* __restrict__ k,
                                                 us* __restrict__ v) {
  int m = blockIdx.x;
  int b = m / S, s = m % S;
  int t = threadIdx.x;
  __shared__ float buf[D];
  __shared__ float cs[32], sn[32];
  if (t < 32) { cs[t] = cosT[s*32 + t]; sn[t] = sinT[s*32 + t]; }
  const float* row = qkv + (size_t)m * 3 * D;
  int lane16 = t & 15;
  int e = 4 * t, eh = e >> 6, rdh = e & 63;

  for (int part = 0; part < 2; part++) {
    fv4 val = *(const fv4*)(row + part * D + 4*t);
    float ss = val[0]*val[0] + val[1]*val[1] + val[2]*val[2] + val[3]*val[3];
    ss += __shfl_xor(ss, 8); ss += __shfl_xor(ss, 4);
    ss += __shfl_xor(ss, 2); ss += __shfl_xor(ss, 1);
    float r = rsqrtf(ss * (1.0f / (float)DH) + 1e-6f);
    fv4 w4 = *(const fv4*)((part == 0 ? qnw : knw) + 4*lane16);
    *(fv4*)&buf[4*t] = val * r * w4;
    __syncthreads();
    fv4 out;
#pragma unroll
    for (int j = 0; j < 4; j++) {
      int rr = rdh + j;
      if (rr < 32) {
        float x1 = buf[eh*64 + rr], x2 = buf[eh*64 + rr + 32];
        out[j] = x1 * cs[rr] - x2 * sn[rr];
      } else {
        int f = rr - 32;
        float x1 = buf[eh*64 + f], x2 = buf[eh*64 + rr];
        out[j] = x2 * cs[f] + x1 * sn[f];
      }
    }
    us* dst = (part == 0 ? q : k);
    us4 o; o[0]=f2bf(out[0]); o[1]=f2bf(out[1]); o[2]=f2bf(out[2]); o[3]=f2bf(out[3]);
    *(us4*)&dst[(((size_t)(b*H + eh)) * S + s) * DH + rdh] = o;
    __syncthreads();
  }
  fv4 vv = *(const fv4*)(row + 2 * D + 4*t);
  us4 o; o[0]=f2bf(vv[0]); o[1]=f2bf(vv[1]); o[2]=f2bf(vv[2]); o[3]=f2bf(vv[3]);
  *(us4*)&v[(((size_t)(b*H + eh)) * S + s) * DH + rdh] = o;
}

// ======================================================================
// 64x64 bf16 transpose: (bh, s, dh) -> (bh, dh, s); grid.z selects k or v
// ======================================================================
__global__ __launch_bounds__(256) void k_tr2(const us* __restrict__ ksrc,
                                             const us* __restrict__ vsrc,
                                             us* __restrict__ kdst,
                                             us* __restrict__ vdst) {
  __shared__ __attribute__((aligned(16))) us tile[64*72];
  int st = blockIdx.x, bh = blockIdx.y, t = threadIdx.x;
  const us* src = blockIdx.z ? vsrc : ksrc;
  us* dst = blockIdx.z ? vdst : kdst;
  const us* sp = src + ((size_t)bh * S + st*64) * 64;
#pragma unroll
  for (int p = 0; p < 2; p++) {
    int idx = t + p*256;
    int r = idx >> 3, c = (idx & 7)*8;
    *(bf16x8*)&tile[r*72 + c] = *(const bf16x8*)&sp[(size_t)idx*8];
  }
  __syncthreads();
  int d = t >> 2;
#pragma unroll
  for (int cc = 0; cc < 16; cc += 8) {
    int s0 = (t & 3)*16 + cc;
    bf16x8 vv;
#pragma unroll
    for (int j2 = 0; j2 < 8; j2++) vv[j2] = (short)tile[(s0+j2)*72 + d];
    *(bf16x8*)&dst[((size_t)bh*64 + d)*S + st*64 + s0] = vv;
  }
}

// ======================================================================
// gamma gate
// ======================================================================
__global__ __launch_bounds__(256) void k_gamma(const float* __restrict__ h,
                                               const float* __restrict__ w1,
                                               const float* __restrict__ w2,
                                               float* __restrict__ gk) {
  int m = blockIdx.x, t = threadIdx.x;
  __shared__ float hrow[D];
  *(fv4*)&hrow[4*t] = *(const fv4*)(h + (size_t)m * D + 4*t);
  __syncthreads();
  int o = t & 63, seg = t >> 6;
  const float* wr = w1 + (size_t)o * D + seg * 256;
  const float* hr = hrow + seg * 256;
  float acc = 0.f;
  for (int j = 0; j < 256; j += 4) {
    fv4 wv = *(const fv4*)(wr + j);
    acc += wv[0]*hr[j] + wv[1]*hr[j+1] + wv[2]*hr[j+2] + wv[3]*hr[j+3];
  }
  __shared__ float part[4][64];
  part[seg][o] = acc;
  __syncthreads();
  if (t < 64) {
    float dot = part[0][t] + part[1][t] + part[2][t] + part[3][t];
    float sv = dot / (1.f + expf(-dot));
    float val = sv * w2[t];
#pragma unroll
    for (int off = 32; off > 0; off >>= 1) val += __shfl_down(val, off);
    if (t == 0) gk[m] = 1.f / (1.f + expf(-val));
  }
}

// ======================================================================
// cumsum: wave-scan
// ======================================================================
__global__ __launch_bounds__(1024) void k_cumsum(const float* __restrict__ gk,
                                                 float* __restrict__ nrm) {
  int b = blockIdx.x, t = threadIdx.x;
  int lane = t & 63, wv = t >> 6;
  float s = gk[b*S + t];
#pragma unroll
  for (int off = 1; off < 64; off <<= 1) {
    float y = __shfl_up(s, off, 64);
    if (lane >= off) s += y;
  }
  __shared__ float wsum[16];
  if (lane == 63) wsum[wv] = s;
  __syncthreads();
  if (t < 16) {
    float v = wsum[t];
    float sv = v;
#pragma unroll
    for (int off = 1; off < 16; off <<= 1) {
      float y = __shfl_up(sv, off, 16);
      if (t >= off) sv += y;
    }
    wsum[t] = sv - v;
  }
  __syncthreads();
  nrm[b*S + t] = (float)NP + s + wsum[wv];
}

// ======================================================================
// FUSED omega-memory + flash attention, MFMA bf16, fixed-offset softmax.
// ======================================================================
#define SM_OFF 24.0f
__global__ __launch_bounds__(256) void k_matt(const us* __restrict__ qb,
                                              const us* __restrict__ kb,
                                              const us* __restrict__ kbT,
                                              const us* __restrict__ vbT,
                                              const float* __restrict__ MpB,
                                              const float* __restrict__ gk,
                                              const float* __restrict__ nrm,
                                              const float* __restrict__ mg, int layer,
                                              us* __restrict__ ob) {
  int nf = xcd_remap(blockIdx.y * 16 + blockIdx.x, 512);
  int xx = nf & 15, bh = nf >> 4;
  int qt = (xx & 1) ? 15 - (xx >> 1) : (xx >> 1);
  int b = bh >> 4, hh = bh & 15;
  int t = threadIdx.x, lane = t & 63, w = t >> 6;
  int l16 = lane & 15, lg = lane >> 4;

  __shared__ __attribute__((aligned(16))) us Qs[64*72];
  __shared__ __attribute__((aligned(16))) us Ks[64*72];
  __shared__ __attribute__((aligned(16))) us Ts[64*72];
  __shared__ __attribute__((aligned(16))) us Ps[64*72];
  __shared__ float gks_[64], nrms[64];

  float gate = 1.f / (1.f + expf(-mg[layer]));

  {
    const us* src = qb + ((size_t)bh * S + qt*64) * 64;
#pragma unroll
    for (int p = 0; p < 2; p++) {
      int idx = t + p*256;
      int r = idx >> 3, c = (idx & 7) * 8;
      *(bf16x8*)&Qs[r*72 + c] = *(const bf16x8*)&src[(size_t)idx*8];
    }
    const float* mp = MpB + (size_t)hh * 4096;
#pragma unroll
    for (int p = 0; p < 4; p++) {
      int e = (t + p*256) * 4;
      int r = e >> 6, c = e & 63;
      fv4 v = *(const fv4*)&mp[e];
      us4 o; o[0]=f2bf(v[0]); o[1]=f2bf(v[1]); o[2]=f2bf(v[2]); o[3]=f2bf(v[3]);
      *(us4*)&Ts[r*72 + c] = o;
    }
    if (t < 64) nrms[t] = nrm[b*S + qt*64 + t];
  }
  __syncthreads();

  bf16x8 aq0 = *(const bf16x8*)&Qs[(16*w + l16)*72 + lg*8];
  bf16x8 aq1 = *(const bf16x8*)&Qs[(16*w + l16)*72 + 32 + lg*8];

  fv4 am[4];
#pragma unroll
  for (int j = 0; j < 4; j++) {
    bf16x8 b0 = *(const bf16x8*)&Ts[(16*j + l16)*72 + lg*8];
    bf16x8 b1 = *(const bf16x8*)&Ts[(16*j + l16)*72 + 32 + lg*8];
    fv4 z = {};
    z = MFMA16(aq0, b0, z, 0, 0, 0);
    z = MFMA16(aq1, b1, z, 0, 0, 0);
    am[j] = z;
  }

  // ================= phase 1: omega memory =================
  for (int kt = 0; kt <= qt; kt++) {
    __syncthreads();
    {
      const us* ksrc = kb + ((size_t)bh * S + kt*64) * 64;
#pragma unroll
      for (int p = 0; p < 2; p++) {
        int idx = t + p*256;
        int r = idx >> 3, c = (idx & 7) * 8;
        *(bf16x8*)&Ks[r*72 + c] = *(const bf16x8*)&ksrc[(size_t)idx*8];
      }
      int d = t >> 2, c0 = (t & 3) * 16;
      const us* tsrc = kbT + ((size_t)bh*64 + d) * S + kt*64 + c0;
      *(bf16x8*)&Ts[d*72 + c0]     = *(const bf16x8*)&tsrc[0];
      *(bf16x8*)&Ts[d*72 + c0 + 8] = *(const bf16x8*)&tsrc[8];
      if (t < 64) gks_[t] = gk[b*S + kt*64 + t];
    }
    __syncthreads();
    fv4 sc[4];
#pragma unroll
    for (int j = 0; j < 4; j++) {
      bf16x8 b0 = *(const bf16x8*)&Ks[(16*j + l16)*72 + lg*8];
      bf16x8 b1 = *(const bf16x8*)&Ks[(16*j + l16)*72 + 32 + lg*8];
      fv4 z = {};
      z = MFMA16(aq0, b0, z, 0, 0, 0);
      z = MFMA16(aq1, b1, z, 0, 0, 0);
      sc[j] = z;
    }
    if (kt < qt) {
#pragma unroll
      for (int j = 0; j < 4; j++) {
        float g = gks_[16*j + l16];
#pragma unroll
        for (int r = 0; r < 4; r++)
          Ps[(16*w + lg*4 + r)*72 + 16*j + l16] = f2bf(sc[j][r] * g);
      }
    } else {
#pragma unroll
      for (int j = 0; j < 4; j++) {
        int kj = 16*j + l16;
        float g = gks_[kj];
#pragma unroll
        for (int r = 0; r < 4; r++) {
          int qi = 16*w + lg*4 + r;
          Ps[qi*72 + kj] = (kj > qi) ? (us)0 : f2bf(sc[j][r] * g);
        }
      }
    }
    __syncthreads();
    bf16x8 ap0 = *(const bf16x8*)&Ps[(16*w + l16)*72 + lg*8];
    bf16x8 ap1 = *(const bf16x8*)&Ps[(16*w + l16)*72 + 32 + lg*8];
#pragma unroll
    for (int j = 0; j < 4; j++) {
      bf16x8 b0 = *(const bf16x8*)&Ts[(16*j + l16)*72 + lg*8];
      bf16x8 b1 = *(const bf16x8*)&Ts[(16*j + l16)*72 + 32 + lg*8];
      am[j] = MFMA16(ap0, b0, am[j], 0, 0, 0);
      am[j] = MFMA16(ap1, b1, am[j], 0, 0, 0);
    }
  }

  __syncthreads();
#pragma unroll
  for (int j = 0; j < 4; j++)
#pragma unroll
    for (int r = 0; r < 4; r++) {
      int qi = 16*w + lg*4 + r, dj = 16*j + l16;
      float qold = bf2f(Qs[qi*72 + dj]);
      float qn = (1.f - gate) * qold + gate * (am[j][r] / nrms[qi]);
      Qs[qi*72 + dj] = f2bf(qn);
    }
  __syncthreads();
  aq0 = *(const bf16x8*)&Qs[(16*w + l16)*72 + lg*8];
  aq1 = *(const bf16x8*)&Qs[(16*w + l16)*72 + 32 + lg*8];

  // ================= phase 2: flash attention =================
  float lsum[4] = {};
  fv4 ao[4] = {};
  for (int kt = 0; kt <= qt; kt++) {
    __syncthreads();
    {
      const us* ksrc = kb + ((size_t)bh * S + kt*64) * 64;
#pragma unroll
      for (int p = 0; p < 2; p++) {
        int idx = t + p*256;
        int r = idx >> 3, c = (idx & 7) * 8;
        *(bf16x8*)&Ks[r*72 + c] = *(const bf16x8*)&ksrc[(size_t)idx*8];
      }
      int d = t >> 2, c0 = (t & 3) * 16;
      const us* tsrc = vbT + ((size_t)bh*64 + d) * S + kt*64 + c0;
      *(bf16x8*)&Ts[d*72 + c0]     = *(const bf16x8*)&tsrc[0];
      *(bf16x8*)&Ts[d*72 + c0 + 8] = *(const bf16x8*)&tsrc[8];
    }
    __syncthreads();
    fv4 sc[4];
#pragma unroll
    for (int j = 0; j < 4; j++) {
      bf16x8 b0 = *(const bf16x8*)&Ks[(16*j + l16)*72 + lg*8];
      bf16x8 b1 = *(const bf16x8*)&Ks[(16*j + l16)*72 + 32 + lg*8];
      fv4 z = {};
      z = MFMA16(aq0, b0, z, 0, 0, 0);
      z = MFMA16(aq1, b1, z, 0, 0, 0);
      sc[j] = z;
    }
    if (kt < qt) {
#pragma unroll
      for (int j = 0; j < 4; j++)
#pragma unroll
        for (int r = 0; r < 4; r++) {
          float p = __expf(fmaf(sc[j][r], 0.125f, -SM_OFF));
          lsum[r] += p;
          Ps[(16*w + lg*4 + r)*72 + 16*j + l16] = f2bf(p);
        }
    } else {
#pragma unroll
      for (int j = 0; j < 4; j++) {
        int kj = 16*j + l16;
#pragma unroll
        for (int r = 0; r < 4; r++) {
          int qi = 16*w + lg*4 + r;
          float p = (kj > qi) ? 0.f : __expf(fmaf(sc[j][r], 0.125f, -SM_OFF));
          lsum[r] += p;
          Ps[qi*72 + kj] = f2bf(p);
        }
      }
    }
    __syncthreads();
    bf16x8 ap0 = *(const bf16x8*)&Ps[(16*w + l16)*72 + lg*8];
    bf16x8 ap1 = *(const bf16x8*)&Ps[(16*w + l16)*72 + 32 + lg*8];
#pragma unroll
    for (int j = 0; j < 4; j++) {
      bf16x8 b0 = *(const bf16x8*)&Ts[(16*j + l16)*72 + lg*8];
      bf16x8 b1 = *(const bf16x8*)&Ts[(16*j + l16)*72 + 32 + lg*8];
      ao[j] = MFMA16(ap0, b0, ao[j], 0, 0, 0);
      ao[j] = MFMA16(ap1, b1, ao[j], 0, 0, 0);
    }
  }

#pragma unroll
  for (int r = 0; r < 4; r++) {
    float l = lsum[r];
    l += __shfl_xor(l, 1);
    l += __shfl_xor(l, 2);
    l += __shfl_xor(l, 4);
    l += __shfl_xor(l, 8);
    lsum[r] = l;
  }
#pragma unroll
  for (int j = 0; j < 4; j++)
#pragma unroll
    for (int r = 0; r < 4; r++) {
      int qi = 16*w + lg*4 + r;
      ob[((size_t)b*S + qt*64 + qi) * D + hh*64 + 16*j + l16] = f2bf(ao[j][r] / lsum[r]);
    }
}

// ======================================================================
// launcher
// ======================================================================
extern "C" void kernel_launch(void* const* d_in, const int* in_sizes, int n_in,
                              void* d_out, int out_size, void* d_ws, size_t ws_size,
                              hipStream_t stream) {
  const int*   ids      = (const int*)d_in[0];
  const float* tok_emb  = (const float*)d_in[1];
  const float* w_init   = (const float*)d_in[2];
  const float* persist  = (const float*)d_in[3];
  const float* norm1_w  = (const float*)d_in[4];
  const float* norm2_w  = (const float*)d_in[5];
  const float* norm_f_w = (const float*)d_in[6];
  const float* qkv_w    = (const float*)d_in[7];
  const float* q_norm_w = (const float*)d_in[8];
  const float* k_norm_w = (const float*)d_in[9];
  const float* gamma_w1 = (const float*)d_in[10];
  const float* gamma_w2 = (const float*)d_in[11];
  const float* mem_gate = (const float*)d_in[12];
  const float* w_o      = (const float*)d_in[13];
  const float* ffn_w1   = (const float*)d_in[14];
  const float* ffn_w2   = (const float*)d_in[15];
  const float* ffn_w3   = (const float*)d_in[16];
  float* out = (float*)d_out;

  // ---- workspace layout ----
  float* ws   = (float*)d_ws;
  float* x    = ws;                          // 2097152 f32
  us*    hbf  = (us*)(x + 2097152);          // 2097152 us
  float* gk   = x + 2097152 + 1048576;
  float* nrm  = gk + 2048;
  float* cosT = nrm + 2048;
  float* sinT = cosT + 32768;
  float* MpB  = sinT + 32768;                // 65536
  float* h    = MpB + 65536;                 // 2097152
  float* qkv  = h + 2097152;                 // 6291456
  us*    obf  = (us*)(qkv + 6291456);        // 2097152 us
  us*    qb   = obf + 2097152;
  us*    kb   = qb + 2097152;
  us*    vb   = kb + 2097152;
  us*    kbT  = vb + 2097152;
  us*    vbT  = kbT + 2097152;
  us*    f1bf = vbT + 2097152;               // M*FFP = 5636096 us
  us*    wq   = f1bf + (size_t)M*FFP;        // 3145728
  us*    wo   = wq + 3145728;                // 1048576
  us*    w1c  = wo + 1048576;                // 2795520
  us*    w2c  = w1c + 2795520;               // 2795520
  us*    w3c  = w2c + 2795520;               // 2818048
  us*    temb = (us*)h;                      // aliases dead h..f1bf span

  k_embed<<<M, 256, 0, stream>>>(ids, tok_emb, w_init, x);
  k_rope_tables<<<(S*32 + 255)/256, 256, 0, stream>>>(cosT, sinT);
  k_mp<<<H, 256, 0, stream>>>(persist, MpB);

  for (int l = 0; l < NL; l++) {
    k_cvtw<<<2048, 256, 0, stream>>>(qkv_w + (size_t)l*3*D*D, w_o + (size_t)l*D*D,
                                     ffn_w1 + (size_t)l*FF*D, ffn_w2 + (size_t)l*FF*D,
                                     ffn_w3 + (size_t)l*D*FF,
                                     wq, wo, w1c, w2c, w3c);
    k_rms<<<M, 256, 0, stream>>>(x, norm1_w + (size_t)l * D, h, hbf);
    k_bgemm<0,64,128><<<dim3(M/64, 3*D/128), 256, 0, stream>>>(hbf, wq, qkv, 3*D, D);
    k_qkvpost<<<M, 256, 0, stream>>>(qkv, q_norm_w + (size_t)l*DH, k_norm_w + (size_t)l*DH,
                                     cosT, sinT, qb, kb, vb);
    k_tr2<<<dim3(S/64, B*H, 2), 256, 0, stream>>>(kb, vb, kbT, vbT);
    k_gamma<<<M, 256, 0, stream>>>(h, gamma_w1 + (size_t)l*GH*D, gamma_w2 + (size_t)l*GH, gk);
    k_cumsum<<<B, S, 0, stream>>>(gk, nrm);
    k_matt<<<dim3(16, B*H), 256, 0, stream>>>(qb, kb, kbT, vbT, MpB, gk, nrm, mem_gate, l, obf);
    k_bgemm<2,64,64><<<dim3(M/64, D/64), 256, 0, stream>>>(obf, wo, x, D, D);
    k_rms<<<M, 256, 0, stream>>>(x, norm2_w + (size_t)l * D, h, hbf);
    k_ffn12<<<dim3(M/64, (FF+63)/64), 256, 0, stream>>>(hbf, w1c, w2c, f1bf, FF, D);
    k_bgemm<2,64,64><<<dim3(M/64, D/64), 256, 0, stream>>>(f1bf, w3c, x, D, FFP);
  }

  k_rms<<<M, 256, 0, stream>>>(x, norm_f_w, h, hbf);
  k_cvt<<<2048, 256, 0, stream>>>(tok_emb, temb, V*D);
  k_gemm8<<<dim3(8, V/256), 512, 0, stream>>>(hbf, temb, out, V, D);
}

// Round 7
// 1828.833 us; speedup vs baseline: 14.2055x; 1.0384x over previous
//
#include <hip/hip_runtime.h>
#include <hip/hip_bf16.h>
#include <math.h>

// ---------------- problem constants ----------------
#define B 2
#define S 1024
#define D 1024
#define H 16
#define DH 64
#define NL 6
#define GH 64
#define NP 16
#define V 32000
#define FF 2730
#define FFP 2752   // FF padded to multiple of 64
#define M (B*S)    // 2048 rows

typedef float fv4 __attribute__((ext_vector_type(4)));
typedef short bf16x8 __attribute__((ext_vector_type(8)));       // 8 bf16 = 4 VGPRs
typedef unsigned short us4 __attribute__((ext_vector_type(4))); // 4 bf16 = 8 bytes
typedef unsigned short us;

#define MFMA16 __builtin_amdgcn_mfma_f32_16x16x32_bf16
#define G2L16(g, l) __builtin_amdgcn_global_load_lds( \
    (const __attribute__((address_space(1))) void*)(g), \
    (__attribute__((address_space(3))) void*)(l), 16, 0, 0)

__device__ __forceinline__ us f2bf(float f) {
  union { float f; unsigned u; } v; v.f = f;
  unsigned r = v.u + 0x7FFFu + ((v.u >> 16) & 1u);   // RNE
  return (us)(r >> 16);
}
__device__ __forceinline__ float bf2f(us h) {
  union { unsigned u; float f; } v; v.u = ((unsigned)h) << 16;
  return v.f;
}

// m204 bijective XCD swizzle
__device__ __forceinline__ int xcd_remap(int flat, int nwg) {
  int q = nwg >> 3, r = nwg & 7;
  int xcd = flat & 7, idx = flat >> 3;
  return (xcd < r) ? (xcd * (q + 1) + idx) : (r * (q + 1) + (xcd - r) * q + idx);
}

// ======================================================================
// embed
// ======================================================================
__global__ __launch_bounds__(256) void k_embed(const int* __restrict__ ids,
                                               const float* __restrict__ emb,
                                               const float* __restrict__ winit,
                                               float* __restrict__ x) {
  int m = blockIdx.x, t = threadIdx.x;
  int id = ids[m];
  fv4 a = *(const fv4*)(emb + (size_t)id * D + 4*t);
  fv4 w = *(const fv4*)(winit + 4*t);
  *(fv4*)(x + (size_t)m * D + 4*t) = a + w;
}

// ======================================================================
// rope tables
// ======================================================================
__global__ void k_rope_tables(float* __restrict__ cosT, float* __restrict__ sinT) {
  int idx = blockIdx.x * blockDim.x + threadIdx.x;
  if (idx >= S * 32) return;
  int s = idx >> 5, f = idx & 31;
  float inv = powf(10000.0f, -2.0f * (float)f / (float)DH);
  float ang = (float)s * inv;
  cosT[idx] = cosf(ang);
  sinT[idx] = sinf(ang);
}

// ======================================================================
// Mp[h][d][e] = sum_n p[n][h][d] * p[n][h][e]   (symmetric)
// ======================================================================
__global__ __launch_bounds__(256) void k_mp(const float* __restrict__ pers,
                                            float* __restrict__ Mp) {
  int h = blockIdx.x, t = threadIdx.x;
  __shared__ float p[NP][DH];
  for (int i = t; i < NP * DH; i += 256) {
    int n = i / DH, dh = i % DH;
    p[n][dh] = pers[(size_t)n * D + h * DH + dh];
  }
  __syncthreads();
  for (int i = t; i < DH * DH; i += 256) {
    int d = i / DH, e = i % DH;
    float s = 0.f;
#pragma unroll
    for (int n = 0; n < NP; n++) s += p[n][d] * p[n][e];
    Mp[(size_t)h * DH * DH + i] = s;
  }
}

// ======================================================================
// rmsnorm rows of D, dual store f32 + bf16
// ======================================================================
__global__ __launch_bounds__(256) void k_rms(const float* __restrict__ in,
                                             const float* __restrict__ w,
                                             float* __restrict__ out,
                                             us* __restrict__ outb) {
  int m = blockIdx.x, t = threadIdx.x;
  fv4 v = *(const fv4*)(in + (size_t)m * D + 4*t);
  float ss = v[0]*v[0] + v[1]*v[1] + v[2]*v[2] + v[3]*v[3];
#pragma unroll
  for (int off = 32; off > 0; off >>= 1) ss += __shfl_down(ss, off);
  __shared__ float buf[4];
  if ((t & 63) == 0) buf[t >> 6] = ss;
  __syncthreads();
  float tot = buf[0] + buf[1] + buf[2] + buf[3];
  float r = rsqrtf(tot * (1.0f / (float)D) + 1e-6f);
  fv4 wv = *(const fv4*)(w + 4*t);
  fv4 res = v * r * wv;
  *(fv4*)(out + (size_t)m * D + 4*t) = res;
  us4 o; o[0]=f2bf(res[0]); o[1]=f2bf(res[1]); o[2]=f2bf(res[2]); o[3]=f2bf(res[3]);
  *(us4*)(outb + (size_t)m * D + 4*t) = o;
}

// ======================================================================
// flat f32 -> bf16 convert (n % 4 == 0)
// ======================================================================
__global__ __launch_bounds__(256) void k_cvt(const float* __restrict__ src,
                                             us* __restrict__ dst, int n) {
  for (size_t i = ((size_t)blockIdx.x * 256 + threadIdx.x) * 4; i < (size_t)n;
       i += (size_t)gridDim.x * 1024) {
    fv4 v = *(const fv4*)(src + i);
    us4 o; o[0]=f2bf(v[0]); o[1]=f2bf(v[1]); o[2]=f2bf(v[2]); o[3]=f2bf(v[3]);
    *(us4*)(dst + i) = o;
  }
}

// ======================================================================
// per-layer weight conversion, single launch
// ======================================================================
#define CVT_N1 786432   // 3*D*D/4
#define CVT_N2 262144   // D*D/4
#define CVT_N3 698880   // FF*D/4
#define CVT_N4 698880
#define CVT_N5 704512   // D * FFP/4
__global__ __launch_bounds__(256) void k_cvtw(const float* __restrict__ s1,
                                              const float* __restrict__ s2,
                                              const float* __restrict__ s3,
                                              const float* __restrict__ s4,
                                              const float* __restrict__ s5,
                                              us* __restrict__ d1, us* __restrict__ d2,
                                              us* __restrict__ d3, us* __restrict__ d4,
                                              us* __restrict__ d5) {
  const int TOT = CVT_N1 + CVT_N2 + CVT_N3 + CVT_N4 + CVT_N5;
  for (int i = blockIdx.x * 256 + threadIdx.x; i < TOT; i += gridDim.x * 256) {
    const float* s; us* d; int j = i;
    if (j < CVT_N1) { s = s1; d = d1; }
    else if ((j -= CVT_N1) < CVT_N2) { s = s2; d = d2; }
    else if ((j -= CVT_N2) < CVT_N3) { s = s3; d = d3; }
    else if ((j -= CVT_N3) < CVT_N4) { s = s4; d = d4; }
    else {
      j -= CVT_N4;
      int r = j / (FFP/4), c = (j % (FFP/4)) * 4;
      us4 o;
#pragma unroll
      for (int q = 0; q < 4; q++) {
        int cc = c + q;
        o[q] = (cc < FF) ? f2bf(s5[(size_t)r * FF + cc]) : (us)0;
      }
      *(us4*)&d5[(size_t)r * FFP + c] = o;
      continue;
    }
    fv4 v = *(const fv4*)(s + (size_t)4 * j);
    us4 o; o[0]=f2bf(v[0]); o[1]=f2bf(v[1]); o[2]=f2bf(v[2]); o[3]=f2bf(v[3]);
    *(us4*)&d[(size_t)4 * j] = o;
  }
}

// ======================================================================
// bf16 MFMA GEMM, m97 structure + XCD swizzle (layer GEMMs).
// ======================================================================
template<int EPI, int BM, int BN>
__global__ __launch_bounds__(256) void k_bgemm(const us* __restrict__ A,
                                               const us* __restrict__ W,
                                               float* __restrict__ C,
                                               int Nn, int Kk) {
  constexpr int FM = BM / 32;
  constexpr int FN = BN / 32;
  constexpr int ACW = BM / 32;
  constexpr int BCW = BN / 32;
  __shared__ __attribute__((aligned(16))) us As[BM * 64];
  __shared__ __attribute__((aligned(16))) us Bs[BN * 64];
  int t = threadIdx.x, lane = t & 63, w = t >> 6;
  int l16 = lane & 15, lkb = lane >> 4;
  int lr = lane >> 3, lc = (lane & 7) * 8;
  int gx = gridDim.x, nwg = gx * gridDim.y;
  int nf = xcd_remap(blockIdx.y * gx + blockIdx.x, nwg);
  int m0 = (nf % gx) * BM, n0 = (nf / gx) * BN;
  int wr = w >> 1, wc = w & 1;

  const us* aB[ACW]; us* aL[ACW];
  const us* bB[BCW]; us* bL[BCW];
#pragma unroll
  for (int i = 0; i < ACW; i++) {
    int chunk = w * ACW + i;
    aB[i] = A + (size_t)(m0 + chunk * 8 + lr) * Kk + lc;
    aL[i] = &As[chunk * 512];
  }
#pragma unroll
  for (int i = 0; i < BCW; i++) {
    int chunk = w * BCW + i;
    int wrow = n0 + chunk * 8 + lr;
    if (wrow >= Nn) wrow = Nn - 1;
    bB[i] = W + (size_t)wrow * Kk + lc;
    bL[i] = &Bs[chunk * 512];
  }

  fv4 acc[FM][FN] = {};
  for (int k0 = 0; k0 < Kk; k0 += 64) {
#pragma unroll
    for (int i = 0; i < ACW; i++) G2L16(aB[i] + k0, aL[i]);
#pragma unroll
    for (int i = 0; i < BCW; i++) G2L16(bB[i] + k0, bL[i]);
    __syncthreads();
#pragma unroll
    for (int kk = 0; kk < 2; kk++) {
      bf16x8 af[FM], bfh[FN];
#pragma unroll
      for (int i = 0; i < FM; i++)
        af[i] = *(const bf16x8*)&As[(wr*(BM/2) + i*16 + l16)*64 + kk*32 + lkb*8];
#pragma unroll
      for (int j = 0; j < FN; j++)
        bfh[j] = *(const bf16x8*)&Bs[(wc*(BN/2) + j*16 + l16)*64 + kk*32 + lkb*8];
#pragma unroll
      for (int i = 0; i < FM; i++)
#pragma unroll
        for (int j = 0; j < FN; j++)
          acc[i][j] = MFMA16(af[i], bfh[j], acc[i][j], 0, 0, 0);
    }
    __syncthreads();
  }

#pragma unroll
  for (int i = 0; i < FM; i++) {
    int gr0 = m0 + wr*(BM/2) + i*16 + lkb*4;
#pragma unroll
    for (int j = 0; j < FN; j++) {
      int gc = n0 + wc*(BN/2) + j*16 + l16;
      if (gc < Nn) {
#pragma unroll
        for (int r = 0; r < 4; r++) {
          size_t idx = (size_t)(gr0 + r) * Nn + gc;
          float val = acc[i][j][r];
          if (EPI == 0) C[idx] = val;
          else if (EPI == 1) C[idx] = val / (1.f + expf(-val));
          else if (EPI == 2) C[idx] += val;
          else C[idx] *= val;
        }
      }
    }
  }
}

// ======================================================================
// 256x256 8-wave deep-pipelined bf16 GEMM (T2+T3/T4+T5) — lm_head.
// ======================================================================
struct G8 { const us* A; const us* W; int K; int m0; int n0; };

__device__ __forceinline__ void g8_issue(const G8& g, us* lds8, int q, int t) {
  int tile = q >> 2, h = q & 3;
  us* buf = lds8 + (size_t)(tile & 1) * 32768;
  const us* Gp = (h < 2) ? g.A : g.W;
  int rbase = ((h < 2) ? g.m0 : g.n0) + (h & 1) * 128;
  us* part = buf + (h >> 1) * 16384 + (h & 1) * 8192;
  int r8 = t >> 3;                               // 0..63
  int sl = (((t & 7) ^ (r8 & 7)) * 8);           // swizzled global 16B slot
#pragma unroll
  for (int c = 0; c < 2; c++) {
    const us* src = Gp + (size_t)(rbase + c * 64 + r8) * g.K + tile * 64 + sl;
    us* dst = part + c * 4096 + t * 8;           // linear: base + lane*16B
    G2L16(src, dst);
  }
}

__global__ __launch_bounds__(512, 2) void k_gemm8(const us* __restrict__ A,
                                                  const us* __restrict__ W,
                                                  float* __restrict__ C,
                                                  int Nn, int Kk) {
  __shared__ __attribute__((aligned(16))) us lds8[65536];   // 128 KB
  int t = threadIdx.x, lane = t & 63, w = t >> 6;
  int wm = w >> 2, wn = w & 3;
  int l16 = lane & 15, lkb = lane >> 4;
  int gx = gridDim.x, nwg = gx * gridDim.y;
  int nf = xcd_remap(blockIdx.y * gx + blockIdx.x, nwg);
  int m0 = (nf % gx) * 256, n0 = (nf / gx) * 256;
  G8 g{A, W, Kk, m0, n0};
  int NK = Kk >> 6, QMAX = NK * 4;

  int q = 0;
  for (; q < 7 && q < QMAX; ++q) g8_issue(g, lds8, q, t);

  fv4 acc[8][4] = {};
  int arow = wm * 128 + l16;
  int brow = wn * 64 + l16;
  int sw = l16 & 7;

  for (int T = 0; T < NK; ++T) {
    if (q < QMAX) { g8_issue(g, lds8, q, t); q++; }   // tile T+1, h3 -> other buf
    if (T == NK - 1) asm volatile("s_waitcnt vmcnt(0)" ::: "memory");
    else             asm volatile("s_waitcnt vmcnt(8)" ::: "memory");
    __builtin_amdgcn_s_barrier();                      // tile T resident
    const us* buf = lds8 + (size_t)(T & 1) * 32768;
    bf16x8 a0[8], a1[8], b0[4], b1[4];
#pragma unroll
    for (int i = 0; i < 8; i++) {
      a0[i] = *(const bf16x8*)&buf[(arow + i*16)*64 + ((lkb     ) ^ sw)*8];
      a1[i] = *(const bf16x8*)&buf[(arow + i*16)*64 + ((lkb +  4) ^ sw)*8];
    }
#pragma unroll
    for (int j = 0; j < 4; j++) {
      b0[j] = *(const bf16x8*)&buf[16384 + (brow + j*16)*64 + ((lkb    ) ^ sw)*8];
      b1[j] = *(const bf16x8*)&buf[16384 + (brow + j*16)*64 + ((lkb + 4) ^ sw)*8];
    }
    __builtin_amdgcn_s_barrier();                      // all waves' reads issued
    __builtin_amdgcn_s_setprio(1);
#pragma unroll
    for (int i = 0; i < 8; i++)
#pragma unroll
      for (int j = 0; j < 4; j++)
        acc[i][j] = MFMA16(a0[i], b0[j], acc[i][j], 0, 0, 0);
    __builtin_amdgcn_s_setprio(0);
    if (q < QMAX) { g8_issue(g, lds8, q, t); q++; }    // tile T+2 h0..2 -> cur buf
    if (q < QMAX) { g8_issue(g, lds8, q, t); q++; }    // (safe: after barrier 2)
    if (q < QMAX) { g8_issue(g, lds8, q, t); q++; }
    __builtin_amdgcn_s_setprio(1);
#pragma unroll
    for (int i = 0; i < 8; i++)
#pragma unroll
      for (int j = 0; j < 4; j++)
        acc[i][j] = MFMA16(a1[i], b1[j], acc[i][j], 0, 0, 0);
    __builtin_amdgcn_s_setprio(0);
  }

#pragma unroll
  for (int i = 0; i < 8; i++) {
    int gr0 = m0 + wm*128 + i*16 + lkb*4;
#pragma unroll
    for (int j = 0; j < 4; j++) {
      int gc = n0 + wn*64 + j*16 + l16;
#pragma unroll
      for (int r = 0; r < 4; r++)
        C[(size_t)(gr0 + r) * Nn + gc] = acc[i][j][r];
    }
  }
}

// ======================================================================
// fused FFN w1/w2 GEMM: Cb = f2bf(silu(A@W1^T) * (A@W2^T)), stride FFP.
// 128x64 tile: FM=4, FN=2, 32 MFMAs per barrier pair, 8 G2L16/wave.
// ======================================================================
__global__ __launch_bounds__(256) void k_ffn12(const us* __restrict__ A,
                                               const us* __restrict__ W1,
                                               const us* __restrict__ W2,
                                               us* __restrict__ Cb,
                                               int Nn, int Kk) {
  __shared__ __attribute__((aligned(16))) us As[128 * 64];
  __shared__ __attribute__((aligned(16))) us B1s[64 * 64];
  __shared__ __attribute__((aligned(16))) us B2s[64 * 64];
  int t = threadIdx.x, lane = t & 63, w = t >> 6;
  int l16 = lane & 15, lkb = lane >> 4;
  int lr = lane >> 3, lc = (lane & 7) * 8;
  int gx = gridDim.x, nwg = gx * gridDim.y;
  int nf = xcd_remap(blockIdx.y * gx + blockIdx.x, nwg);
  int m0 = (nf % gx) * 128, n0 = (nf / gx) * 64;
  int wr = w >> 1, wc = w & 1;

  const us* aB[4]; us* aL[4];
  const us* b1B[2]; us* b1L[2];
  const us* b2B[2]; us* b2L[2];
#pragma unroll
  for (int i = 0; i < 4; i++) {
    int chunk = w * 4 + i;
    aB[i] = A + (size_t)(m0 + chunk * 8 + lr) * Kk + lc;
    aL[i] = &As[chunk * 512];
  }
#pragma unroll
  for (int i = 0; i < 2; i++) {
    int chunk = w * 2 + i;
    int wrow = n0 + chunk * 8 + lr;
    if (wrow >= Nn) wrow = Nn - 1;
    b1B[i] = W1 + (size_t)wrow * Kk + lc;
    b1L[i] = &B1s[chunk * 512];
    b2B[i] = W2 + (size_t)wrow * Kk + lc;
    b2L[i] = &B2s[chunk * 512];
  }

  fv4 acc1[4][2] = {}, acc2[4][2] = {};
  for (int k0 = 0; k0 < Kk; k0 += 64) {
#pragma unroll
    for (int i = 0; i < 4; i++) G2L16(aB[i] + k0, aL[i]);
#pragma unroll
    for (int i = 0; i < 2; i++) {
      G2L16(b1B[i] + k0, b1L[i]);
      G2L16(b2B[i] + k0, b2L[i]);
    }
    __syncthreads();
#pragma unroll
    for (int kk = 0; kk < 2; kk++) {
      bf16x8 af[4], b1f[2], b2f[2];
#pragma unroll
      for (int i = 0; i < 4; i++)
        af[i] = *(const bf16x8*)&As[(wr*64 + i*16 + l16)*64 + kk*32 + lkb*8];
#pragma unroll
      for (int j = 0; j < 2; j++) {
        b1f[j] = *(const bf16x8*)&B1s[(wc*32 + j*16 + l16)*64 + kk*32 + lkb*8];
        b2f[j] = *(const bf16x8*)&B2s[(wc*32 + j*16 + l16)*64 + kk*32 + lkb*8];
      }
#pragma unroll
      for (int i = 0; i < 4; i++)
#pragma unroll
        for (int j = 0; j < 2; j++) {
          acc1[i][j] = MFMA16(af[i], b1f[j], acc1[i][j], 0, 0, 0);
          acc2[i][j] = MFMA16(af[i], b2f[j], acc2[i][j], 0, 0, 0);
        }
    }
    __syncthreads();
  }

#pragma unroll
  for (int i = 0; i < 4; i++) {
    int gr0 = m0 + wr*64 + i*16 + lkb*4;
#pragma unroll
    for (int j = 0; j < 2; j++) {
      int gc = n0 + wc*32 + j*16 + l16;
      if (gc < Nn) {
#pragma unroll
        for (int r = 0; r < 4; r++) {
          float v1 = acc1[i][j][r], v2 = acc2[i][j][r];
          float sv = v1 / (1.f + expf(-v1));
          Cb[(size_t)(gr0 + r) * FFP + gc] = f2bf(sv * v2);
        }
      }
    }
  }
}

// ======================================================================
// qkv post
// ======================================================================
__global__ __launch_bounds__(256) void k_qkvpost(const float* __restrict__ qkv,
                                                 const float* __restrict__ qnw,
                                                 const float* __restrict__ knw,
                                                 const float* __restrict__ cosT,
                                                 const float* __restrict__ sinT,
                                                 us* __restrict__ q,
                                                 us* __restrict__ k,
                                                 us* __restrict__ v) {
  int m = blockIdx.x;
  int b = m / S, s = m % S;
  int t = threadIdx.x;
  __shared__ float buf[D];
  __shared__ float cs[32], sn[32];
  if (t < 32) { cs[t] = cosT[s*32 + t]; sn[t] = sinT[s*32 + t]; }
  const float* row = qkv + (size_t)m * 3 * D;
  int lane16 = t & 15;
  int e = 4 * t, eh = e >> 6, rdh = e & 63;

  for (int part = 0; part < 2; part++) {
    fv4 val = *(const fv4*)(row + part * D + 4*t);
    float ss = val[0]*val[0] + val[1]*val[1] + val[2]*val[2] + val[3]*val[3];
    ss += __shfl_xor(ss, 8); ss += __shfl_xor(ss, 4);
    ss += __shfl_xor(ss, 2); ss += __shfl_xor(ss, 1);
    float r = rsqrtf(ss * (1.0f / (float)DH) + 1e-6f);
    fv4 w4 = *(const fv4*)((part == 0 ? qnw : knw) + 4*lane16);
    *(fv4*)&buf[4*t] = val * r * w4;
    __syncthreads();
    fv4 out;
#pragma unroll
    for (int j = 0; j < 4; j++) {
      int rr = rdh + j;
      if (rr < 32) {
        float x1 = buf[eh*64 + rr], x2 = buf[eh*64 + rr + 32];
        out[j] = x1 * cs[rr] - x2 * sn[rr];
      } else {
        int f = rr - 32;
        float x1 = buf[eh*64 + f], x2 = buf[eh*64 + rr];
        out[j] = x2 * cs[f] + x1 * sn[f];
      }
    }
    us* dst = (part == 0 ? q : k);
    us4 o; o[0]=f2bf(out[0]); o[1]=f2bf(out[1]); o[2]=f2bf(out[2]); o[3]=f2bf(out[3]);
    *(us4*)&dst[(((size_t)(b*H + eh)) * S + s) * DH + rdh] = o;
    __syncthreads();
  }
  fv4 vv = *(const fv4*)(row + 2 * D + 4*t);
  us4 o; o[0]=f2bf(vv[0]); o[1]=f2bf(vv[1]); o[2]=f2bf(vv[2]); o[3]=f2bf(vv[3]);
  *(us4*)&v[(((size_t)(b*H + eh)) * S + s) * DH + rdh] = o;
}

// ======================================================================
// 64x64 bf16 transpose: (bh, s, dh) -> (bh, dh, s); grid.z selects k or v
// ======================================================================
__global__ __launch_bounds__(256) void k_tr2(const us* __restrict__ ksrc,
                                             const us* __restrict__ vsrc,
                                             us* __restrict__ kdst,
                                             us* __restrict__ vdst) {
  __shared__ __attribute__((aligned(16))) us tile[64*72];
  int st = blockIdx.x, bh = blockIdx.y, t = threadIdx.x;
  const us* src = blockIdx.z ? vsrc : ksrc;
  us* dst = blockIdx.z ? vdst : kdst;
  const us* sp = src + ((size_t)bh * S + st*64) * 64;
#pragma unroll
  for (int p = 0; p < 2; p++) {
    int idx = t + p*256;
    int r = idx >> 3, c = (idx & 7)*8;
    *(bf16x8*)&tile[r*72 + c] = *(const bf16x8*)&sp[(size_t)idx*8];
  }
  __syncthreads();
  int d = t >> 2;
#pragma unroll
  for (int cc = 0; cc < 16; cc += 8) {
    int s0 = (t & 3)*16 + cc;
    bf16x8 vv;
#pragma unroll
    for (int j2 = 0; j2 < 8; j2++) vv[j2] = (short)tile[(s0+j2)*72 + d];
    *(bf16x8*)&dst[((size_t)bh*64 + d)*S + st*64 + s0] = vv;
  }
}

// ======================================================================
// gamma gate
// ======================================================================
__global__ __launch_bounds__(256) void k_gamma(const float* __restrict__ h,
                                               const float* __restrict__ w1,
                                               const float* __restrict__ w2,
                                               float* __restrict__ gk) {
  int m = blockIdx.x, t = threadIdx.x;
  __shared__ float hrow[D];
  *(fv4*)&hrow[4*t] = *(const fv4*)(h + (size_t)m * D + 4*t);
  __syncthreads();
  int o = t & 63, seg = t >> 6;
  const float* wr = w1 + (size_t)o * D + seg * 256;
  const float* hr = hrow + seg * 256;
  float acc = 0.f;
  for (int j = 0; j < 256; j += 4) {
    fv4 wv = *(const fv4*)(wr + j);
    acc += wv[0]*hr[j] + wv[1]*hr[j+1] + wv[2]*hr[j+2] + wv[3]*hr[j+3];
  }
  __shared__ float part[4][64];
  part[seg][o] = acc;
  __syncthreads();
  if (t < 64) {
    float dot = part[0][t] + part[1][t] + part[2][t] + part[3][t];
    float sv = dot / (1.f + expf(-dot));
    float val = sv * w2[t];
#pragma unroll
    for (int off = 32; off > 0; off >>= 1) val += __shfl_down(val, off);
    if (t == 0) gk[m] = 1.f / (1.f + expf(-val));
  }
}

// ======================================================================
// cumsum: wave-scan
// ======================================================================
__global__ __launch_bounds__(1024) void k_cumsum(const float* __restrict__ gk,
                                                 float* __restrict__ nrm) {
  int b = blockIdx.x, t = threadIdx.x;
  int lane = t & 63, wv = t >> 6;
  float s = gk[b*S + t];
#pragma unroll
  for (int off = 1; off < 64; off <<= 1) {
    float y = __shfl_up(s, off, 64);
    if (lane >= off) s += y;
  }
  __shared__ float wsum[16];
  if (lane == 63) wsum[wv] = s;
  __syncthreads();
  if (t < 16) {
    float v = wsum[t];
    float sv = v;
#pragma unroll
    for (int off = 1; off < 16; off <<= 1) {
      float y = __shfl_up(sv, off, 16);
      if (t >= off) sv += y;
    }
    wsum[t] = sv - v;
  }
  __syncthreads();
  nrm[b*S + t] = (float)NP + s + wsum[wv];
}

// ======================================================================
// FUSED omega-memory + flash attention, MFMA bf16, fixed-offset softmax.
// Barrier discipline: Ks/Ts are read cross-wave (B-fragments span all 64
// rows) -> staging needs the 2 per-iter barriers. Ps and Qs are WAVE-
// PRIVATE (wave w only writes/reads rows [16w,16w+16) as A-fragments) ->
// no barrier needed between Ps write and Ps read, nor around q' update.
// ======================================================================
#define SM_OFF 24.0f
__global__ __launch_bounds__(256) void k_matt(const us* __restrict__ qb,
                                              const us* __restrict__ kb,
                                              const us* __restrict__ kbT,
                                              const us* __restrict__ vbT,
                                              const float* __restrict__ MpB,
                                              const float* __restrict__ gk,
                                              const float* __restrict__ nrm,
                                              const float* __restrict__ mg, int layer,
                                              us* __restrict__ ob) {
  int nf = xcd_remap(blockIdx.y * 16 + blockIdx.x, 512);
  int xx = nf & 15, bh = nf >> 4;
  int qt = (xx & 1) ? 15 - (xx >> 1) : (xx >> 1);
  int b = bh >> 4, hh = bh & 15;
  int t = threadIdx.x, lane = t & 63, w = t >> 6;
  int l16 = lane & 15, lg = lane >> 4;

  __shared__ __attribute__((aligned(16))) us Qs[64*72];
  __shared__ __attribute__((aligned(16))) us Ks[64*72];
  __shared__ __attribute__((aligned(16))) us Ts[64*72];
  __shared__ __attribute__((aligned(16))) us Ps[64*72];
  __shared__ float gks_[64], nrms[64];

  float gate = 1.f / (1.f + expf(-mg[layer]));

  {
    const us* src = qb + ((size_t)bh * S + qt*64) * 64;
#pragma unroll
    for (int p = 0; p < 2; p++) {
      int idx = t + p*256;
      int r = idx >> 3, c = (idx & 7) * 8;
      *(bf16x8*)&Qs[r*72 + c] = *(const bf16x8*)&src[(size_t)idx*8];
    }
    const float* mp = MpB + (size_t)hh * 4096;
#pragma unroll
    for (int p = 0; p < 4; p++) {
      int e = (t + p*256) * 4;
      int r = e >> 6, c = e & 63;
      fv4 v = *(const fv4*)&mp[e];
      us4 o; o[0]=f2bf(v[0]); o[1]=f2bf(v[1]); o[2]=f2bf(v[2]); o[3]=f2bf(v[3]);
      *(us4*)&Ts[r*72 + c] = o;
    }
    if (t < 64) nrms[t] = nrm[b*S + qt*64 + t];
  }
  __syncthreads();

  bf16x8 aq0 = *(const bf16x8*)&Qs[(16*w + l16)*72 + lg*8];
  bf16x8 aq1 = *(const bf16x8*)&Qs[(16*w + l16)*72 + 32 + lg*8];

  fv4 am[4];
#pragma unroll
  for (int j = 0; j < 4; j++) {
    bf16x8 b0 = *(const bf16x8*)&Ts[(16*j + l16)*72 + lg*8];
    bf16x8 b1 = *(const bf16x8*)&Ts[(16*j + l16)*72 + 32 + lg*8];
    fv4 z = {};
    z = MFMA16(aq0, b0, z, 0, 0, 0);
    z = MFMA16(aq1, b1, z, 0, 0, 0);
    am[j] = z;
  }

  // ================= phase 1: omega memory =================
  for (int kt = 0; kt <= qt; kt++) {
    __syncthreads();
    {
      const us* ksrc = kb + ((size_t)bh * S + kt*64) * 64;
#pragma unroll
      for (int p = 0; p < 2; p++) {
        int idx = t + p*256;
        int r = idx >> 3, c = (idx & 7) * 8;
        *(bf16x8*)&Ks[r*72 + c] = *(const bf16x8*)&ksrc[(size_t)idx*8];
      }
      int d = t >> 2, c0 = (t & 3) * 16;
      const us* tsrc = kbT + ((size_t)bh*64 + d) * S + kt*64 + c0;
      *(bf16x8*)&Ts[d*72 + c0]     = *(const bf16x8*)&tsrc[0];
      *(bf16x8*)&Ts[d*72 + c0 + 8] = *(const bf16x8*)&tsrc[8];
      if (t < 64) gks_[t] = gk[b*S + kt*64 + t];
    }
    __syncthreads();
    fv4 sc[4];
#pragma unroll
    for (int j = 0; j < 4; j++) {
      bf16x8 b0 = *(const bf16x8*)&Ks[(16*j + l16)*72 + lg*8];
      bf16x8 b1 = *(const bf16x8*)&Ks[(16*j + l16)*72 + 32 + lg*8];
      fv4 z = {};
      z = MFMA16(aq0, b0, z, 0, 0, 0);
      z = MFMA16(aq1, b1, z, 0, 0, 0);
      sc[j] = z;
    }
    if (kt < qt) {
#pragma unroll
      for (int j = 0; j < 4; j++) {
        float g = gks_[16*j + l16];
#pragma unroll
        for (int r = 0; r < 4; r++)
          Ps[(16*w + lg*4 + r)*72 + 16*j + l16] = f2bf(sc[j][r] * g);
      }
    } else {
#pragma unroll
      for (int j = 0; j < 4; j++) {
        int kj = 16*j + l16;
        float g = gks_[kj];
#pragma unroll
        for (int r = 0; r < 4; r++) {
          int qi = 16*w + lg*4 + r;
          Ps[qi*72 + kj] = (kj > qi) ? (us)0 : f2bf(sc[j][r] * g);
        }
      }
    }
    // no barrier: Ps rows [16w,16w+16) are wave-private (write then A-read)
    bf16x8 ap0 = *(const bf16x8*)&Ps[(16*w + l16)*72 + lg*8];
    bf16x8 ap1 = *(const bf16x8*)&Ps[(16*w + l16)*72 + 32 + lg*8];
#pragma unroll
    for (int j = 0; j < 4; j++) {
      bf16x8 b0 = *(const bf16x8*)&Ts[(16*j + l16)*72 + lg*8];
      bf16x8 b1 = *(const bf16x8*)&Ts[(16*j + l16)*72 + 32 + lg*8];
      am[j] = MFMA16(ap0, b0, am[j], 0, 0, 0);
      am[j] = MFMA16(ap1, b1, am[j], 0, 0, 0);
    }
  }

  // q' update: Qs rows [16w,16w+16) wave-private -> no barriers needed
#pragma unroll
  for (int j = 0; j < 4; j++)
#pragma unroll
    for (int r = 0; r < 4; r++) {
      int qi = 16*w + lg*4 + r, dj = 16*j + l16;
      float qold = bf2f(Qs[qi*72 + dj]);
      float qn = (1.f - gate) * qold + gate * (am[j][r] / nrms[qi]);
      Qs[qi*72 + dj] = f2bf(qn);
    }
  aq0 = *(const bf16x8*)&Qs[(16*w + l16)*72 + lg*8];
  aq1 = *(const bf16x8*)&Qs[(16*w + l16)*72 + 32 + lg*8];

  // ================= phase 2: flash attention =================
  float lsum[4] = {};
  fv4 ao[4] = {};
  for (int kt = 0; kt <= qt; kt++) {
    __syncthreads();
    {
      const us* ksrc = kb + ((size_t)bh * S + kt*64) * 64;
#pragma unroll
      for (int p = 0; p < 2; p++) {
        int idx = t + p*256;
        int r = idx >> 3, c = (idx & 7) * 8;
        *(bf16x8*)&Ks[r*72 + c] = *(const bf16x8*)&ksrc[(size_t)idx*8];
      }
      int d = t >> 2, c0 = (t & 3) * 16;
      const us* tsrc = vbT + ((size_t)bh*64 + d) * S + kt*64 + c0;
      *(bf16x8*)&Ts[d*72 + c0]     = *(const bf16x8*)&tsrc[0];
      *(bf16x8*)&Ts[d*72 + c0 + 8] = *(const bf16x8*)&tsrc[8];
    }
    __syncthreads();
    fv4 sc[4];
#pragma unroll
    for (int j = 0; j < 4; j++) {
      bf16x8 b0 = *(const bf16x8*)&Ks[(16*j + l16)*72 + lg*8];
      bf16x8 b1 = *(const bf16x8*)&Ks[(16*j + l16)*72 + 32 + lg*8];
      fv4 z = {};
      z = MFMA16(aq0, b0, z, 0, 0, 0);
      z = MFMA16(aq1, b1, z, 0, 0, 0);
      sc[j] = z;
    }
    if (kt < qt) {
#pragma unroll
      for (int j = 0; j < 4; j++)
#pragma unroll
        for (int r = 0; r < 4; r++) {
          float p = __expf(fmaf(sc[j][r], 0.125f, -SM_OFF));
          lsum[r] += p;
          Ps[(16*w + lg*4 + r)*72 + 16*j + l16] = f2bf(p);
        }
    } else {
#pragma unroll
      for (int j = 0; j < 4; j++) {
        int kj = 16*j + l16;
#pragma unroll
        for (int r = 0; r < 4; r++) {
          int qi = 16*w + lg*4 + r;
          float p = (kj > qi) ? 0.f : __expf(fmaf(sc[j][r], 0.125f, -SM_OFF));
          lsum[r] += p;
          Ps[qi*72 + kj] = f2bf(p);
        }
      }
    }
    // no barrier: Ps wave-private
    bf16x8 ap0 = *(const bf16x8*)&Ps[(16*w + l16)*72 + lg*8];
    bf16x8 ap1 = *(const bf16x8*)&Ps[(16*w + l16)*72 + 32 + lg*8];
#pragma unroll
    for (int j = 0; j < 4; j++) {
      bf16x8 b0 = *(const bf16x8*)&Ts[(16*j + l16)*72 + lg*8];
      bf16x8 b1 = *(const bf16x8*)&Ts[(16*j + l16)*72 + 32 + lg*8];
      ao[j] = MFMA16(ap0, b0, ao[j], 0, 0, 0);
      ao[j] = MFMA16(ap1, b1, ao[j], 0, 0, 0);
    }
  }

#pragma unroll
  for (int r = 0; r < 4; r++) {
    float l = lsum[r];
    l += __shfl_xor(l, 1);
    l += __shfl_xor(l, 2);
    l += __shfl_xor(l, 4);
    l += __shfl_xor(l, 8);
    lsum[r] = l;
  }
#pragma unroll
  for (int j = 0; j < 4; j++)
#pragma unroll
    for (int r = 0; r < 4; r++) {
      int qi = 16*w + lg*4 + r;
      ob[((size_t)b*S + qt*64 + qi) * D + hh*64 + 16*j + l16] = f2bf(ao[j][r] / lsum[r]);
    }
}

// ======================================================================
// launcher
// ======================================================================
extern "C" void kernel_launch(void* const* d_in, const int* in_sizes, int n_in,
                              void* d_out, int out_size, void* d_ws, size_t ws_size,
                              hipStream_t stream) {
  const int*   ids      = (const int*)d_in[0];
  const float* tok_emb  = (const float*)d_in[1];
  const float* w_init   = (const float*)d_in[2];
  const float* persist  = (const float*)d_in[3];
  const float* norm1_w  = (const float*)d_in[4];
  const float* norm2_w  = (const float*)d_in[5];
  const float* norm_f_w = (const float*)d_in[6];
  const float* qkv_w    = (const float*)d_in[7];
  const float* q_norm_w = (const float*)d_in[8];
  const float* k_norm_w = (const float*)d_in[9];
  const float* gamma_w1 = (const float*)d_in[10];
  const float* gamma_w2 = (const float*)d_in[11];
  const float* mem_gate = (const float*)d_in[12];
  const float* w_o      = (const float*)d_in[13];
  const float* ffn_w1   = (const float*)d_in[14];
  const float* ffn_w2   = (const float*)d_in[15];
  const float* ffn_w3   = (const float*)d_in[16];
  float* out = (float*)d_out;

  // ---- workspace layout ----
  float* ws   = (float*)d_ws;
  float* x    = ws;                          // 2097152 f32
  us*    hbf  = (us*)(x + 2097152);          // 2097152 us
  float* gk   = x + 2097152 + 1048576;
  float* nrm  = gk + 2048;
  float* cosT = nrm + 2048;
  float* sinT = cosT + 32768;
  float* MpB  = sinT + 32768;                // 65536
  float* h    = MpB + 65536;                 // 2097152
  float* qkv  = h + 2097152;                 // 6291456
  us*    obf  = (us*)(qkv + 6291456);        // 2097152 us
  us*    qb   = obf + 2097152;
  us*    kb   = qb + 2097152;
  us*    vb   = kb + 2097152;
  us*    kbT  = vb + 2097152;
  us*    vbT  = kbT + 2097152;
  us*    f1bf = vbT + 2097152;               // M*FFP = 5636096 us
  us*    wq   = f1bf + (size_t)M*FFP;        // 3145728
  us*    wo   = wq + 3145728;                // 1048576
  us*    w1c  = wo + 1048576;                // 2795520
  us*    w2c  = w1c + 2795520;               // 2795520
  us*    w3c  = w2c + 2795520;               // 2818048
  us*    temb = (us*)h;                      // aliases dead h..f1bf span

  k_embed<<<M, 256, 0, stream>>>(ids, tok_emb, w_init, x);
  k_rope_tables<<<(S*32 + 255)/256, 256, 0, stream>>>(cosT, sinT);
  k_mp<<<H, 256, 0, stream>>>(persist, MpB);

  for (int l = 0; l < NL; l++) {
    k_cvtw<<<2048, 256, 0, stream>>>(qkv_w + (size_t)l*3*D*D, w_o + (size_t)l*D*D,
                                     ffn_w1 + (size_t)l*FF*D, ffn_w2 + (size_t)l*FF*D,
                                     ffn_w3 + (size_t)l*D*FF,
                                     wq, wo, w1c, w2c, w3c);
    k_rms<<<M, 256, 0, stream>>>(x, norm1_w + (size_t)l * D, h, hbf);
    k_bgemm<0,128,128><<<dim3(M/128, 3*D/128), 256, 0, stream>>>(hbf, wq, qkv, 3*D, D);
    k_qkvpost<<<M, 256, 0, stream>>>(qkv, q_norm_w + (size_t)l*DH, k_norm_w + (size_t)l*DH,
                                     cosT, sinT, qb, kb, vb);
    k_tr2<<<dim3(S/64, B*H, 2), 256, 0, stream>>>(kb, vb, kbT, vbT);
    k_gamma<<<M, 256, 0, stream>>>(h, gamma_w1 + (size_t)l*GH*D, gamma_w2 + (size_t)l*GH, gk);
    k_cumsum<<<B, S, 0, stream>>>(gk, nrm);
    k_matt<<<dim3(16, B*H), 256, 0, stream>>>(qb, kb, kbT, vbT, MpB, gk, nrm, mem_gate, l, obf);
    k_bgemm<2,64,64><<<dim3(M/64, D/64), 256, 0, stream>>>(obf, wo, x, D, D);
    k_rms<<<M, 256, 0, stream>>>(x, norm2_w + (size_t)l * D, h, hbf);
    k_ffn12<<<dim3(M/128, (FF+63)/64), 256, 0, stream>>>(hbf, w1c, w2c, f1bf, FF, D);
    k_bgemm<2,64,64><<<dim3(M/64, D/64), 256, 0, stream>>>(f1bf, w3c, x, D, FFP);
  }

  k_rms<<<M, 256, 0, stream>>>(x, norm_f_w, h, hbf);
  k_cvt<<<2048, 256, 0, stream>>>(tok_emb, temb, V*D);
  k_gemm8<<<dim3(8, V/256), 512, 0, stream>>>(hbf, temb, out, V, D);
}